// Round 1
// baseline (10508.244 us; speedup 1.0000x reference)
//
#include <hip/hip_runtime.h>
#include <hip/hip_bf16.h>

#define D_MODEL 1024
#define N_HEADS 16
#define DH 64
#define D_FF   4096
#define SEQ    1024
#define BATCH  4
#define TOK    (BATCH*SEQ)
#define EPS    1e-5f
#define SCALE  0.125f   // 1/sqrt(64)

// ---------------------------------------------------------------------------
// Generic fp32 GEMM: C[M,N] = A[M,K] @ B[K,N] (+bias[N]) (+relu)
// 64x64 tile, BK=16, 256 threads, 4x4 microtile per thread.
// ---------------------------------------------------------------------------
#define BM 64
#define BN 64
#define BK 16

__global__ __launch_bounds__(256) void gemm_kernel(
    const float* __restrict__ A, const float* __restrict__ B,
    float* __restrict__ C, int M, int N, int K,
    const float* __restrict__ bias, int relu)
{
    __shared__ float As[BK][BM + 1];   // +1 pad: conflict-free k-major reads
    __shared__ float Bs[BK][BN];       // unpadded: aligned float4 rows

    const int tid = threadIdx.x;
    const int tx  = tid & 15;          // output col group (0..15)
    const int ty  = tid >> 4;          // output row group (0..15)
    const int m0  = blockIdx.y * BM;
    const int n0  = blockIdx.x * BN;

    // global load indices
    const int a_m  = tid >> 2;         // 0..63 (row within A tile)
    const int a_k4 = (tid & 3) * 4;    // 0,4,8,12 (k float4 start)
    const int b_k  = tid >> 4;         // 0..15 (row within B tile)
    const int b_n4 = (tid & 15) * 4;   // col float4 start

    float acc[4][4] = {};

    for (int k0 = 0; k0 < K; k0 += BK) {
        float4 av = *reinterpret_cast<const float4*>(
            &A[(size_t)(m0 + a_m) * K + k0 + a_k4]);
        float4 bv = *reinterpret_cast<const float4*>(
            &B[(size_t)(k0 + b_k) * N + n0 + b_n4]);

        As[a_k4 + 0][a_m] = av.x;
        As[a_k4 + 1][a_m] = av.y;
        As[a_k4 + 2][a_m] = av.z;
        As[a_k4 + 3][a_m] = av.w;
        *reinterpret_cast<float4*>(&Bs[b_k][b_n4]) = bv;
        __syncthreads();

#pragma unroll
        for (int kk = 0; kk < BK; ++kk) {
            float a0 = As[kk][ty * 4 + 0];
            float a1 = As[kk][ty * 4 + 1];
            float a2 = As[kk][ty * 4 + 2];
            float a3 = As[kk][ty * 4 + 3];
            float4 bq = *reinterpret_cast<const float4*>(&Bs[kk][tx * 4]);
            acc[0][0] += a0 * bq.x; acc[0][1] += a0 * bq.y; acc[0][2] += a0 * bq.z; acc[0][3] += a0 * bq.w;
            acc[1][0] += a1 * bq.x; acc[1][1] += a1 * bq.y; acc[1][2] += a1 * bq.z; acc[1][3] += a1 * bq.w;
            acc[2][0] += a2 * bq.x; acc[2][1] += a2 * bq.y; acc[2][2] += a2 * bq.z; acc[2][3] += a2 * bq.w;
            acc[3][0] += a3 * bq.x; acc[3][1] += a3 * bq.y; acc[3][2] += a3 * bq.z; acc[3][3] += a3 * bq.w;
        }
        __syncthreads();
    }

    // epilogue: bias + relu, float4 stores
    float4 bcol = make_float4(0.f, 0.f, 0.f, 0.f);
    if (bias) bcol = *reinterpret_cast<const float4*>(&bias[n0 + tx * 4]);
#pragma unroll
    for (int i = 0; i < 4; ++i) {
        float4 o;
        o.x = acc[i][0] + bcol.x;
        o.y = acc[i][1] + bcol.y;
        o.z = acc[i][2] + bcol.z;
        o.w = acc[i][3] + bcol.w;
        if (relu) {
            o.x = fmaxf(o.x, 0.f); o.y = fmaxf(o.y, 0.f);
            o.z = fmaxf(o.z, 0.f); o.w = fmaxf(o.w, 0.f);
        }
        *reinterpret_cast<float4*>(
            &C[(size_t)(m0 + ty * 4 + i) * N + n0 + tx * 4]) = o;
    }
}

// ---------------------------------------------------------------------------
// Attention: one block (256 thr) per (b, h, q). Q/K/V are [TOK, D] with head
// slice at col h*64. Scores row staged in LDS, block-reduce softmax, PV.
// ---------------------------------------------------------------------------
__global__ __launch_bounds__(256) void attn_kernel(
    const float* __restrict__ Q, const float* __restrict__ K,
    const float* __restrict__ V, float* __restrict__ O, int causal)
{
    __shared__ float qs[DH];
    __shared__ float sc[SEQ];
    __shared__ float red[256];
    __shared__ float s_max, s_inv;

    const int tid = threadIdx.x;
    const int bid = blockIdx.x;
    const int qi  = bid & (SEQ - 1);
    const int h   = (bid >> 10) & (N_HEADS - 1);
    const int b   = bid >> 14;

    const size_t base = (size_t)b * SEQ * D_MODEL + (size_t)h * DH;

    if (tid < DH) qs[tid] = Q[base + (size_t)qi * D_MODEL + tid];
    __syncthreads();

    // phase 1: scores
    const float4* q4 = reinterpret_cast<const float4*>(qs);
    for (int j = tid; j < SEQ; j += 256) {
        const float4* k4 = reinterpret_cast<const float4*>(K + base + (size_t)j * D_MODEL);
        float s = 0.f;
#pragma unroll
        for (int d = 0; d < DH / 4; ++d) {
            float4 kk = k4[d];
            float4 qq = q4[d];
            s += qq.x * kk.x + qq.y * kk.y + qq.z * kk.z + qq.w * kk.w;
        }
        s *= SCALE;
        if (causal && j > qi) s = -1e30f;
        sc[j] = s;
    }
    __syncthreads();

    // softmax: max
    float m = -1e30f;
    for (int j = tid; j < SEQ; j += 256) m = fmaxf(m, sc[j]);
    red[tid] = m;
    __syncthreads();
    for (int s = 128; s > 0; s >>= 1) {
        if (tid < s) red[tid] = fmaxf(red[tid], red[tid + s]);
        __syncthreads();
    }
    if (tid == 0) s_max = red[0];
    __syncthreads();
    const float mx = s_max;

    // softmax: exp + sum
    float sum = 0.f;
    for (int j = tid; j < SEQ; j += 256) {
        float e = __expf(sc[j] - mx);
        sc[j] = e;
        sum += e;
    }
    __syncthreads();
    red[tid] = sum;
    __syncthreads();
    for (int s = 128; s > 0; s >>= 1) {
        if (tid < s) red[tid] += red[tid + s];
        __syncthreads();
    }
    if (tid == 0) s_inv = 1.f / red[0];
    __syncthreads();
    const float inv = s_inv;

    // phase 2: PV. thread = (chunk c of j, dim d); coalesced V reads.
    const int d = tid & 63;
    const int c = tid >> 6;
    float acc = 0.f;
    const float* vb = V + base + d;
    for (int j = c * 256; j < c * 256 + 256; ++j)
        acc += sc[j] * vb[(size_t)j * D_MODEL];
    __syncthreads();
    red[tid] = acc;
    __syncthreads();
    if (tid < DH) {
        float o = (red[tid] + red[tid + 64] + red[tid + 128] + red[tid + 192]) * inv;
        O[base + (size_t)qi * D_MODEL + tid] = o;
    }
}

// ---------------------------------------------------------------------------
// out[row] = res[row] + LayerNorm(x[row]) * g + b   (row = token, D=1024)
// ---------------------------------------------------------------------------
__global__ __launch_bounds__(256) void ln_res_kernel(
    const float* __restrict__ x, const float* __restrict__ res,
    const float* __restrict__ g, const float* __restrict__ bta,
    float* __restrict__ out)
{
    __shared__ float red[256];
    __shared__ float s_mu, s_rstd;

    const int row = blockIdx.x;
    const int tid = threadIdx.x;
    const float4* x4 = reinterpret_cast<const float4*>(x + (size_t)row * D_MODEL);
    float4 v = x4[tid];

    float sum = v.x + v.y + v.z + v.w;
    red[tid] = sum;
    __syncthreads();
    for (int s = 128; s > 0; s >>= 1) {
        if (tid < s) red[tid] += red[tid + s];
        __syncthreads();
    }
    if (tid == 0) s_mu = red[0] * (1.f / D_MODEL);
    __syncthreads();
    const float mu = s_mu;

    float dx = v.x - mu, dy = v.y - mu, dz = v.z - mu, dw = v.w - mu;
    red[tid] = dx * dx + dy * dy + dz * dz + dw * dw;
    __syncthreads();
    for (int s = 128; s > 0; s >>= 1) {
        if (tid < s) red[tid] += red[tid + s];
        __syncthreads();
    }
    if (tid == 0) s_rstd = rsqrtf(red[0] * (1.f / D_MODEL) + EPS);
    __syncthreads();
    const float rstd = s_rstd;

    float4 rv = reinterpret_cast<const float4*>(res + (size_t)row * D_MODEL)[tid];
    float4 gv = reinterpret_cast<const float4*>(g)[tid];
    float4 bv = reinterpret_cast<const float4*>(bta)[tid];

    float4 o;
    o.x = rv.x + dx * rstd * gv.x + bv.x;
    o.y = rv.y + dy * rstd * gv.y + bv.y;
    o.z = rv.z + dz * rstd * gv.z + bv.z;
    o.w = rv.w + dw * rstd * gv.w + bv.w;
    reinterpret_cast<float4*>(out + (size_t)row * D_MODEL)[tid] = o;
}

// ---------------------------------------------------------------------------
extern "C" void kernel_launch(void* const* d_in, const int* in_sizes, int n_in,
                              void* d_out, int out_size, void* d_ws, size_t ws_size,
                              hipStream_t stream)
{
    const float* X    = (const float*)d_in[0];
    const float* Wq1  = (const float*)d_in[1];
    const float* Wk1  = (const float*)d_in[2];
    const float* Wv1  = (const float*)d_in[3];
    const float* Wo1  = (const float*)d_in[4];
    const float* Wq2  = (const float*)d_in[5];
    const float* Wk2  = (const float*)d_in[6];
    const float* Wv2  = (const float*)d_in[7];
    const float* Wo2  = (const float*)d_in[8];
    const float* ln_g = (const float*)d_in[9];
    const float* ln_b = (const float*)d_in[10];
    const float* W1   = (const float*)d_in[11];
    const float* b1   = (const float*)d_in[12];
    const float* W2   = (const float*)d_in[13];
    const float* b2   = (const float*)d_in[14];

    float* ws = (float*)d_ws;
    const size_t CH = (size_t)TOK * D_MODEL;   // 4,194,304 floats
    float* q  = ws + 0 * CH;
    float* k  = ws + 1 * CH;
    float* v  = ws + 2 * CH;
    float* t0 = ws + 3 * CH;
    float* t1 = ws + 4 * CH;
    float* t2 = ws + 5 * CH;
    float* hb = ws;   // FFN hidden [TOK, D_FF] overlays q..t0 (dead by then)

    auto gemm = [&](const float* A, const float* B, float* C,
                    int M, int N, int K, const float* bias, int relu) {
        dim3 grid(N / BN, M / BM);
        gemm_kernel<<<grid, 256, 0, stream>>>(A, B, C, M, N, K, bias, relu);
    };

    // ---- MHA 1 (causal) ----
    gemm(X, Wq1, q, TOK, D_MODEL, D_MODEL, nullptr, 0);
    gemm(X, Wk1, k, TOK, D_MODEL, D_MODEL, nullptr, 0);
    gemm(X, Wv1, v, TOK, D_MODEL, D_MODEL, nullptr, 0);
    attn_kernel<<<dim3(BATCH * N_HEADS * SEQ), 256, 0, stream>>>(q, k, v, t0, 1);
    gemm(t0, Wo1, t1, TOK, D_MODEL, D_MODEL, nullptr, 0);          // masked
    ln_res_kernel<<<dim3(TOK), 256, 0, stream>>>(t1, X, ln_g, ln_b, t2); // norm_masked

    // ---- MHA 2 (full) ----
    gemm(t2, Wq2, q, TOK, D_MODEL, D_MODEL, nullptr, 0);
    gemm(t2, Wk2, k, TOK, D_MODEL, D_MODEL, nullptr, 0);
    gemm(t2, Wv2, v, TOK, D_MODEL, D_MODEL, nullptr, 0);
    attn_kernel<<<dim3(BATCH * N_HEADS * SEQ), 256, 0, stream>>>(q, k, v, t0, 0);
    gemm(t0, Wo2, t1, TOK, D_MODEL, D_MODEL, nullptr, 0);          // attn2
    ln_res_kernel<<<dim3(TOK), 256, 0, stream>>>(t1, t1, ln_g, ln_b, t2); // norm_attn2

    // ---- FFN ----
    gemm(t2, W1, hb, TOK, D_FF, D_MODEL, b1, 1);                   // relu(x@W1+b1)
    gemm(hb, W2, t1, TOK, D_MODEL, D_FF, b2, 0);                   // ff
    ln_res_kernel<<<dim3(TOK), 256, 0, stream>>>(t1, t2, ln_g, ln_b, (float*)d_out);
}

// Round 2
// 2922.890 us; speedup vs baseline: 3.5952x; 3.5952x over previous
//
#include <hip/hip_runtime.h>
#include <hip/hip_bf16.h>

#define D_MODEL 1024
#define N_HEADS 16
#define DH 64
#define D_FF   4096
#define SEQ    1024
#define BATCH  4
#define TOK    (BATCH*SEQ)
#define EPS    1e-5f
#define SCALE  0.125f   // 1/sqrt(64)

// ---------------------------------------------------------------------------
// Generic fp32 GEMM: C[M,N] = A[M,K] @ B[K,N] (+bias[N]) (+relu)
// 64x64 tile, BK=16, 256 threads, 4x4 microtile per thread.
// ---------------------------------------------------------------------------
#define BM 64
#define BN 64
#define BK 16

__global__ __launch_bounds__(256) void gemm_kernel(
    const float* __restrict__ A, const float* __restrict__ B,
    float* __restrict__ C, int M, int N, int K,
    const float* __restrict__ bias, int relu)
{
    __shared__ float As[BK][BM + 1];
    __shared__ float Bs[BK][BN];

    const int tid = threadIdx.x;
    const int tx  = tid & 15;
    const int ty  = tid >> 4;
    const int m0  = blockIdx.y * BM;
    const int n0  = blockIdx.x * BN;

    const int a_m  = tid >> 2;
    const int a_k4 = (tid & 3) * 4;
    const int b_k  = tid >> 4;
    const int b_n4 = (tid & 15) * 4;

    float acc[4][4] = {};

    for (int k0 = 0; k0 < K; k0 += BK) {
        float4 av = *reinterpret_cast<const float4*>(
            &A[(size_t)(m0 + a_m) * K + k0 + a_k4]);
        float4 bv = *reinterpret_cast<const float4*>(
            &B[(size_t)(k0 + b_k) * N + n0 + b_n4]);

        As[a_k4 + 0][a_m] = av.x;
        As[a_k4 + 1][a_m] = av.y;
        As[a_k4 + 2][a_m] = av.z;
        As[a_k4 + 3][a_m] = av.w;
        *reinterpret_cast<float4*>(&Bs[b_k][b_n4]) = bv;
        __syncthreads();

#pragma unroll
        for (int kk = 0; kk < BK; ++kk) {
            float a0 = As[kk][ty * 4 + 0];
            float a1 = As[kk][ty * 4 + 1];
            float a2 = As[kk][ty * 4 + 2];
            float a3 = As[kk][ty * 4 + 3];
            float4 bq = *reinterpret_cast<const float4*>(&Bs[kk][tx * 4]);
            acc[0][0] += a0 * bq.x; acc[0][1] += a0 * bq.y; acc[0][2] += a0 * bq.z; acc[0][3] += a0 * bq.w;
            acc[1][0] += a1 * bq.x; acc[1][1] += a1 * bq.y; acc[1][2] += a1 * bq.z; acc[1][3] += a1 * bq.w;
            acc[2][0] += a2 * bq.x; acc[2][1] += a2 * bq.y; acc[2][2] += a2 * bq.z; acc[2][3] += a2 * bq.w;
            acc[3][0] += a3 * bq.x; acc[3][1] += a3 * bq.y; acc[3][2] += a3 * bq.z; acc[3][3] += a3 * bq.w;
        }
        __syncthreads();
    }

    float4 bcol = make_float4(0.f, 0.f, 0.f, 0.f);
    if (bias) bcol = *reinterpret_cast<const float4*>(&bias[n0 + tx * 4]);
#pragma unroll
    for (int i = 0; i < 4; ++i) {
        float4 o;
        o.x = acc[i][0] + bcol.x;
        o.y = acc[i][1] + bcol.y;
        o.z = acc[i][2] + bcol.z;
        o.w = acc[i][3] + bcol.w;
        if (relu) {
            o.x = fmaxf(o.x, 0.f); o.y = fmaxf(o.y, 0.f);
            o.z = fmaxf(o.z, 0.f); o.w = fmaxf(o.w, 0.f);
        }
        *reinterpret_cast<float4*>(
            &C[(size_t)(m0 + ty * 4 + i) * N + n0 + tx * 4]) = o;
    }
}

// ---------------------------------------------------------------------------
// Tiled flash-style attention.
// Block = (b, h, 64 q-rows). 256 threads = 16x16 (ty=q-group, tx=j/d-group),
// each thread owns a 4x4 microtile. K/V tiles of 64 rows staged in LDS and
// reused across all 64 q-rows. Online softmax in registers (m/l replicated
// across the 16 tx-lanes of a q-row via shfl_xor reduction).
// LDS layouts chosen for <=2-way bank conflicts on all hot loops:
//   Qt/Kt [d][q|j] pad 65 (transposed staging writes + inner reads free)
//   Vs    [j][d]   pad 64 (natural row-major, col-indexed -> free)
//   Ps    [q][j]   pad 65 (reads free; 16 scalar writes/tile 8-way, ~7% of tile)
// ---------------------------------------------------------------------------
__global__ __launch_bounds__(256) void attn_tile_kernel(
    const float* __restrict__ Q, const float* __restrict__ K,
    const float* __restrict__ V, float* __restrict__ O, int causal)
{
    __shared__ float Qt[DH][65];
    __shared__ float Kt[DH][65];
    __shared__ float Vs[64][64];
    __shared__ float Ps[64][65];

    const int tid = threadIdx.x;
    const int tx = tid & 15;
    const int ty = tid >> 4;
    const int qt = blockIdx.x;                 // q-tile index
    const int bh = blockIdx.y;                 // b*H + h
    const int h  = bh & (N_HEADS - 1);
    const int b  = bh >> 4;
    const size_t base = (size_t)b * SEQ * D_MODEL + (size_t)h * DH;
    const int q0 = qt * 64;

    const int srow = tid >> 4;                 // 0..15 staging row
    const int d4   = (tid & 15) * 4;           // staging col (float4)

    // stage Q tile transposed: Qt[d][q]
#pragma unroll
    for (int r = 0; r < 4; ++r) {
        int q = srow + 16 * r;
        float4 v4 = *reinterpret_cast<const float4*>(
            &Q[base + (size_t)(q0 + q) * D_MODEL + d4]);
        Qt[d4 + 0][q] = v4.x; Qt[d4 + 1][q] = v4.y;
        Qt[d4 + 2][q] = v4.z; Qt[d4 + 3][q] = v4.w;
    }

    float m[4], l[4], acc_o[4][4];
#pragma unroll
    for (int i = 0; i < 4; ++i) {
        m[i] = -1e30f; l[i] = 0.f;
#pragma unroll
        for (int j = 0; j < 4; ++j) acc_o[i][j] = 0.f;
    }

    const int ntile = causal ? (qt + 1) : (SEQ / 64);
    for (int kt = 0; kt < ntile; ++kt) {
        const int j0 = kt * 64;
        __syncthreads();   // prev tile's PV done before overwriting Kt/Vs
#pragma unroll
        for (int r = 0; r < 4; ++r) {
            int j = srow + 16 * r;
            float4 kv = *reinterpret_cast<const float4*>(
                &K[base + (size_t)(j0 + j) * D_MODEL + d4]);
            Kt[d4 + 0][j] = kv.x; Kt[d4 + 1][j] = kv.y;
            Kt[d4 + 2][j] = kv.z; Kt[d4 + 3][j] = kv.w;
            float4 vv = *reinterpret_cast<const float4*>(
                &V[base + (size_t)(j0 + j) * D_MODEL + d4]);
            Vs[j][d4 + 0] = vv.x; Vs[j][d4 + 1] = vv.y;
            Vs[j][d4 + 2] = vv.z; Vs[j][d4 + 3] = vv.w;
        }
        __syncthreads();

        // scores: 4x4 outer-product microtile over d
        float s[4][4] = {};
        for (int kk = 0; kk < DH; ++kk) {
            float qv0 = Qt[kk][4 * ty + 0];
            float qv1 = Qt[kk][4 * ty + 1];
            float qv2 = Qt[kk][4 * ty + 2];
            float qv3 = Qt[kk][4 * ty + 3];
            float kv0 = Kt[kk][4 * tx + 0];
            float kv1 = Kt[kk][4 * tx + 1];
            float kv2 = Kt[kk][4 * tx + 2];
            float kv3 = Kt[kk][4 * tx + 3];
            s[0][0] += qv0 * kv0; s[0][1] += qv0 * kv1; s[0][2] += qv0 * kv2; s[0][3] += qv0 * kv3;
            s[1][0] += qv1 * kv0; s[1][1] += qv1 * kv1; s[1][2] += qv1 * kv2; s[1][3] += qv1 * kv3;
            s[2][0] += qv2 * kv0; s[2][1] += qv2 * kv1; s[2][2] += qv2 * kv2; s[2][3] += qv2 * kv3;
            s[3][0] += qv3 * kv0; s[3][1] += qv3 * kv1; s[3][2] += qv3 * kv2; s[3][3] += qv3 * kv3;
        }
#pragma unroll
        for (int i = 0; i < 4; ++i)
#pragma unroll
            for (int j = 0; j < 4; ++j) s[i][j] *= SCALE;

        if (causal && kt == qt) {
#pragma unroll
            for (int i = 0; i < 4; ++i)
#pragma unroll
                for (int j = 0; j < 4; ++j)
                    if (4 * tx + j > 4 * ty + i) s[i][j] = -1e30f;
        }

        // online softmax (per q-row; state replicated across tx lanes)
        float tmax[4], rs[4];
#pragma unroll
        for (int i = 0; i < 4; ++i)
            tmax[i] = fmaxf(fmaxf(s[i][0], s[i][1]), fmaxf(s[i][2], s[i][3]));
#pragma unroll
        for (int d = 1; d < 16; d <<= 1)
#pragma unroll
            for (int i = 0; i < 4; ++i)
                tmax[i] = fmaxf(tmax[i], __shfl_xor(tmax[i], d));

#pragma unroll
        for (int i = 0; i < 4; ++i) {
            float mn = fmaxf(m[i], tmax[i]);
            float sc = __expf(m[i] - mn);
            float sum = 0.f;
#pragma unroll
            for (int j = 0; j < 4; ++j) {
                float p = __expf(s[i][j] - mn);
                s[i][j] = p;
                sum += p;
            }
            rs[i] = sum;
            m[i] = mn;
            l[i] *= sc;
#pragma unroll
            for (int j = 0; j < 4; ++j) acc_o[i][j] *= sc;
        }
#pragma unroll
        for (int d = 1; d < 16; d <<= 1)
#pragma unroll
            for (int i = 0; i < 4; ++i) rs[i] += __shfl_xor(rs[i], d);
#pragma unroll
        for (int i = 0; i < 4; ++i) l[i] += rs[i];

        // P -> LDS for the PV transpose
#pragma unroll
        for (int i = 0; i < 4; ++i)
#pragma unroll
            for (int j = 0; j < 4; ++j)
                Ps[4 * ty + i][4 * tx + j] = s[i][j];
        __syncthreads();

        // PV: acc_o[q][d] += sum_j P[q][j] * V[j][d]
        for (int jj = 0; jj < 64; ++jj) {
            float p0 = Ps[4 * ty + 0][jj];
            float p1 = Ps[4 * ty + 1][jj];
            float p2 = Ps[4 * ty + 2][jj];
            float p3 = Ps[4 * ty + 3][jj];
            float v0 = Vs[jj][4 * tx + 0];
            float v1 = Vs[jj][4 * tx + 1];
            float v2 = Vs[jj][4 * tx + 2];
            float v3 = Vs[jj][4 * tx + 3];
            acc_o[0][0] += p0 * v0; acc_o[0][1] += p0 * v1; acc_o[0][2] += p0 * v2; acc_o[0][3] += p0 * v3;
            acc_o[1][0] += p1 * v0; acc_o[1][1] += p1 * v1; acc_o[1][2] += p1 * v2; acc_o[1][3] += p1 * v3;
            acc_o[2][0] += p2 * v0; acc_o[2][1] += p2 * v1; acc_o[2][2] += p2 * v2; acc_o[2][3] += p2 * v3;
            acc_o[3][0] += p3 * v0; acc_o[3][1] += p3 * v1; acc_o[3][2] += p3 * v2; acc_o[3][3] += p3 * v3;
        }
    }

    // epilogue: O = acc_o / l
#pragma unroll
    for (int i = 0; i < 4; ++i) {
        float inv = 1.f / l[i];
        float4 o;
        o.x = acc_o[i][0] * inv;
        o.y = acc_o[i][1] * inv;
        o.z = acc_o[i][2] * inv;
        o.w = acc_o[i][3] * inv;
        *reinterpret_cast<float4*>(
            &O[base + (size_t)(q0 + 4 * ty + i) * D_MODEL + 4 * tx]) = o;
    }
}

// ---------------------------------------------------------------------------
// out[row] = res[row] + LayerNorm(x[row]) * g + b
// ---------------------------------------------------------------------------
__global__ __launch_bounds__(256) void ln_res_kernel(
    const float* __restrict__ x, const float* __restrict__ res,
    const float* __restrict__ g, const float* __restrict__ bta,
    float* __restrict__ out)
{
    __shared__ float red[256];
    __shared__ float s_mu, s_rstd;

    const int row = blockIdx.x;
    const int tid = threadIdx.x;
    const float4* x4 = reinterpret_cast<const float4*>(x + (size_t)row * D_MODEL);
    float4 v = x4[tid];

    float sum = v.x + v.y + v.z + v.w;
    red[tid] = sum;
    __syncthreads();
    for (int s = 128; s > 0; s >>= 1) {
        if (tid < s) red[tid] += red[tid + s];
        __syncthreads();
    }
    if (tid == 0) s_mu = red[0] * (1.f / D_MODEL);
    __syncthreads();
    const float mu = s_mu;

    float dx = v.x - mu, dy = v.y - mu, dz = v.z - mu, dw = v.w - mu;
    red[tid] = dx * dx + dy * dy + dz * dz + dw * dw;
    __syncthreads();
    for (int s = 128; s > 0; s >>= 1) {
        if (tid < s) red[tid] += red[tid + s];
        __syncthreads();
    }
    if (tid == 0) s_rstd = rsqrtf(red[0] * (1.f / D_MODEL) + EPS);
    __syncthreads();
    const float rstd = s_rstd;

    float4 rv = reinterpret_cast<const float4*>(res + (size_t)row * D_MODEL)[tid];
    float4 gv = reinterpret_cast<const float4*>(g)[tid];
    float4 bv = reinterpret_cast<const float4*>(bta)[tid];

    float4 o;
    o.x = rv.x + dx * rstd * gv.x + bv.x;
    o.y = rv.y + dy * rstd * gv.y + bv.y;
    o.z = rv.z + dz * rstd * gv.z + bv.z;
    o.w = rv.w + dw * rstd * gv.w + bv.w;
    reinterpret_cast<float4*>(out + (size_t)row * D_MODEL)[tid] = o;
}

// ---------------------------------------------------------------------------
extern "C" void kernel_launch(void* const* d_in, const int* in_sizes, int n_in,
                              void* d_out, int out_size, void* d_ws, size_t ws_size,
                              hipStream_t stream)
{
    const float* X    = (const float*)d_in[0];
    const float* Wq1  = (const float*)d_in[1];
    const float* Wk1  = (const float*)d_in[2];
    const float* Wv1  = (const float*)d_in[3];
    const float* Wo1  = (const float*)d_in[4];
    const float* Wq2  = (const float*)d_in[5];
    const float* Wk2  = (const float*)d_in[6];
    const float* Wv2  = (const float*)d_in[7];
    const float* Wo2  = (const float*)d_in[8];
    const float* ln_g = (const float*)d_in[9];
    const float* ln_b = (const float*)d_in[10];
    const float* W1   = (const float*)d_in[11];
    const float* b1   = (const float*)d_in[12];
    const float* W2   = (const float*)d_in[13];
    const float* b2   = (const float*)d_in[14];

    float* ws = (float*)d_ws;
    const size_t CH = (size_t)TOK * D_MODEL;
    float* q  = ws + 0 * CH;
    float* k  = ws + 1 * CH;
    float* v  = ws + 2 * CH;
    float* t0 = ws + 3 * CH;
    float* t1 = ws + 4 * CH;
    float* t2 = ws + 5 * CH;
    float* hb = ws;   // FFN hidden [TOK, D_FF] overlays q..t0 (dead by then)

    auto gemm = [&](const float* A, const float* B, float* C,
                    int M, int N, int K, const float* bias, int relu) {
        dim3 grid(N / BN, M / BM);
        gemm_kernel<<<grid, 256, 0, stream>>>(A, B, C, M, N, K, bias, relu);
    };

    dim3 agrid(SEQ / 64, BATCH * N_HEADS);

    // ---- MHA 1 (causal) ----
    gemm(X, Wq1, q, TOK, D_MODEL, D_MODEL, nullptr, 0);
    gemm(X, Wk1, k, TOK, D_MODEL, D_MODEL, nullptr, 0);
    gemm(X, Wv1, v, TOK, D_MODEL, D_MODEL, nullptr, 0);
    attn_tile_kernel<<<agrid, 256, 0, stream>>>(q, k, v, t0, 1);
    gemm(t0, Wo1, t1, TOK, D_MODEL, D_MODEL, nullptr, 0);
    ln_res_kernel<<<dim3(TOK), 256, 0, stream>>>(t1, X, ln_g, ln_b, t2);

    // ---- MHA 2 (full) ----
    gemm(t2, Wq2, q, TOK, D_MODEL, D_MODEL, nullptr, 0);
    gemm(t2, Wk2, k, TOK, D_MODEL, D_MODEL, nullptr, 0);
    gemm(t2, Wv2, v, TOK, D_MODEL, D_MODEL, nullptr, 0);
    attn_tile_kernel<<<agrid, 256, 0, stream>>>(q, k, v, t0, 0);
    gemm(t0, Wo2, t1, TOK, D_MODEL, D_MODEL, nullptr, 0);
    ln_res_kernel<<<dim3(TOK), 256, 0, stream>>>(t1, t1, ln_g, ln_b, t2);

    // ---- FFN ----
    gemm(t2, W1, hb, TOK, D_FF, D_MODEL, b1, 1);
    gemm(hb, W2, t1, TOK, D_MODEL, D_FF, b2, 0);
    ln_res_kernel<<<dim3(TOK), 256, 0, stream>>>(t1, t2, ln_g, ln_b, (float*)d_out);
}

// Round 3
// 1108.528 us; speedup vs baseline: 9.4795x; 2.6367x over previous
//
#include <hip/hip_runtime.h>
#include <hip/hip_bf16.h>

#define D_MODEL 1024
#define N_HEADS 16
#define DH 64
#define D_FF   4096
#define SEQ    1024
#define BATCH  4
#define TOK    (BATCH*SEQ)
#define EPS    1e-5f
#define SCALE  0.125f   // 1/sqrt(64)

typedef __attribute__((ext_vector_type(8))) short short8v;
typedef __attribute__((ext_vector_type(4))) float f32x4;

__device__ __forceinline__ unsigned short f2bf(float f) {
    unsigned int u; __builtin_memcpy(&u, &f, 4);
    u += 0x7fffu + ((u >> 16) & 1u);          // RNE
    return (unsigned short)(u >> 16);
}
__device__ __forceinline__ float bf2f(unsigned short s) {
    unsigned int u = ((unsigned int)s) << 16;
    float f; __builtin_memcpy(&f, &u, 4);
    return f;
}

// ---------------------------------------------------------------------------
// bf16 MFMA GEMM (m97 structure): C[M,N] = A[M,K] @ Bt[N,K]^T
// 128x128 tile, BK=32, 4 waves (each 64x64), mfma_f32_16x16x32_bf16.
// LDS filled via global_load_lds width=16 (linear dest = wave base + lane*16;
// per-lane global source chooses the row-major [128][32] tile layout).
// 64B LDS rows -> frag ds_read_b128 is 2-way bank aliasing (free, m136).
// Epilogue: +bias, relu, writes fp32 (Cf) and/or bf16 (Cb).
// ---------------------------------------------------------------------------
__global__ __launch_bounds__(256) void gemm_bf16_kernel(
    const unsigned short* __restrict__ A,    // [M][K] bf16
    const unsigned short* __restrict__ Bt,   // [N][K] bf16
    float* __restrict__ Cf, unsigned short* __restrict__ Cb,
    int M, int N, int K, const float* __restrict__ bias, int relu)
{
    __shared__ unsigned short As[128 * 32];
    __shared__ unsigned short Bs[128 * 32];

    const int tid = threadIdx.x;
    const int l   = tid & 63;
    const int w   = tid >> 6;
    const int wr  = w >> 1, wc = w & 1;
    const int m0  = blockIdx.y * 128, n0 = blockIdx.x * 128;

    // staging: 512 16B-units per matrix; thread covers units u = p*256 + w*64 + l
    const int u0 = w * 64 + l;
    const int r0 = u0 >> 2, c0 = (u0 & 3) * 8;
    const int u1 = 256 + u0;
    const int r1 = u1 >> 2, c1 = (u1 & 3) * 8;

    const unsigned short* a0 = A  + (size_t)(m0 + r0) * K + c0;
    const unsigned short* a1 = A  + (size_t)(m0 + r1) * K + c1;
    const unsigned short* b0 = Bt + (size_t)(n0 + r0) * K + c0;
    const unsigned short* b1 = Bt + (size_t)(n0 + r1) * K + c1;
    unsigned short* lda0 = &As[(w * 64) * 8];
    unsigned short* lda1 = &As[(256 + w * 64) * 8];
    unsigned short* ldb0 = &Bs[(w * 64) * 8];
    unsigned short* ldb1 = &Bs[(256 + w * 64) * 8];

    f32x4 acc[4][4];
#pragma unroll
    for (int i = 0; i < 4; ++i)
#pragma unroll
        for (int j = 0; j < 4; ++j) acc[i][j] = (f32x4){0.f, 0.f, 0.f, 0.f};

    const int lr = l & 15;
    const int lk = (l >> 4) * 8;

    for (int k0 = 0; k0 < K; k0 += 32) {
        __builtin_amdgcn_global_load_lds(
            (const __attribute__((address_space(1))) void*)(a0 + k0),
            (__attribute__((address_space(3))) void*)lda0, 16, 0, 0);
        __builtin_amdgcn_global_load_lds(
            (const __attribute__((address_space(1))) void*)(a1 + k0),
            (__attribute__((address_space(3))) void*)lda1, 16, 0, 0);
        __builtin_amdgcn_global_load_lds(
            (const __attribute__((address_space(1))) void*)(b0 + k0),
            (__attribute__((address_space(3))) void*)ldb0, 16, 0, 0);
        __builtin_amdgcn_global_load_lds(
            (const __attribute__((address_space(1))) void*)(b1 + k0),
            (__attribute__((address_space(3))) void*)ldb1, 16, 0, 0);
        __syncthreads();   // drains vmcnt -> LDS tiles ready

        short8v af[4], bfr[4];
#pragma unroll
        for (int mi = 0; mi < 4; ++mi)
            af[mi] = *reinterpret_cast<const short8v*>(
                &As[(wr * 64 + mi * 16 + lr) * 32 + lk]);
#pragma unroll
        for (int ni = 0; ni < 4; ++ni)
            bfr[ni] = *reinterpret_cast<const short8v*>(
                &Bs[(wc * 64 + ni * 16 + lr) * 32 + lk]);
#pragma unroll
        for (int mi = 0; mi < 4; ++mi)
#pragma unroll
            for (int ni = 0; ni < 4; ++ni)
                acc[mi][ni] = __builtin_amdgcn_mfma_f32_16x16x32_bf16(
                    af[mi], bfr[ni], acc[mi][ni], 0, 0, 0);
        __syncthreads();   // all waves done reading before next stage
    }

    // epilogue: C/D layout col = lane&15, row = (lane>>4)*4 + reg  [m89/m91]
#pragma unroll
    for (int mi = 0; mi < 4; ++mi) {
        const int row = m0 + wr * 64 + mi * 16 + (l >> 4) * 4;
#pragma unroll
        for (int ni = 0; ni < 4; ++ni) {
            const int col = n0 + wc * 64 + ni * 16 + lr;
            const float bv = bias ? bias[col] : 0.f;
#pragma unroll
            for (int j = 0; j < 4; ++j) {
                float v = acc[mi][ni][j] + bv;
                if (relu) v = fmaxf(v, 0.f);
                const size_t idx = (size_t)(row + j) * N + col;
                if (Cf) Cf[idx] = v;
                if (Cb) Cb[idx] = f2bf(v);
            }
        }
    }
}

// ---------------------------------------------------------------------------
// Weight convert+transpose: W fp32 [K][N] -> Wt bf16 [N][K]. 64x64 LDS tiles.
// ---------------------------------------------------------------------------
__global__ __launch_bounds__(256) void tcvt_kernel(
    const float* __restrict__ W, unsigned short* __restrict__ Wt, int K, int N)
{
    __shared__ unsigned short L[64][65];
    const int tid = threadIdx.x;
    const int tx = tid & 15, ty = tid >> 4;
    const int n0 = blockIdx.x * 64, k0 = blockIdx.y * 64;
#pragma unroll
    for (int r = 0; r < 4; ++r) {
        int kr = ty + 16 * r;
        float4 v = *reinterpret_cast<const float4*>(
            &W[(size_t)(k0 + kr) * N + n0 + tx * 4]);
        L[tx * 4 + 0][kr] = f2bf(v.x);
        L[tx * 4 + 1][kr] = f2bf(v.y);
        L[tx * 4 + 2][kr] = f2bf(v.z);
        L[tx * 4 + 3][kr] = f2bf(v.w);
    }
    __syncthreads();
#pragma unroll
    for (int r = 0; r < 4; ++r) {
        int nr = ty + 16 * r;
        ushort4 o = make_ushort4(L[nr][tx * 4 + 0], L[nr][tx * 4 + 1],
                                 L[nr][tx * 4 + 2], L[nr][tx * 4 + 3]);
        *reinterpret_cast<ushort4*>(&Wt[(size_t)(n0 + nr) * K + k0 + tx * 4]) = o;
    }
}

// fp32 -> bf16 elementwise (n4 = count/4)
__global__ __launch_bounds__(256) void f2b_kernel(
    const float* __restrict__ in, unsigned short* __restrict__ out, int n4)
{
    int i = blockIdx.x * 256 + threadIdx.x;
    if (i < n4) {
        float4 v = reinterpret_cast<const float4*>(in)[i];
        reinterpret_cast<ushort4*>(out)[i] =
            make_ushort4(f2bf(v.x), f2bf(v.y), f2bf(v.z), f2bf(v.w));
    }
}

// ---------------------------------------------------------------------------
// Tiled flash-style attention, bf16 in/out, fp32 math (structure from R1).
// ---------------------------------------------------------------------------
__global__ __launch_bounds__(256) void attn_tile_kernel(
    const unsigned short* __restrict__ Q, const unsigned short* __restrict__ K,
    const unsigned short* __restrict__ V, unsigned short* __restrict__ O, int causal)
{
    __shared__ float Qt[DH][65];
    __shared__ float Kt[DH][65];
    __shared__ float Vs[64][64];
    __shared__ float Ps[64][65];

    const int tid = threadIdx.x;
    const int tx = tid & 15;
    const int ty = tid >> 4;
    const int qt = blockIdx.x;
    const int bh = blockIdx.y;
    const int h  = bh & (N_HEADS - 1);
    const int b  = bh >> 4;
    const size_t base = (size_t)b * SEQ * D_MODEL + (size_t)h * DH;
    const int q0 = qt * 64;

    const int srow = tid >> 4;
    const int d4   = (tid & 15) * 4;

#pragma unroll
    for (int r = 0; r < 4; ++r) {
        int q = srow + 16 * r;
        ushort4 v4 = *reinterpret_cast<const ushort4*>(
            &Q[base + (size_t)(q0 + q) * D_MODEL + d4]);
        Qt[d4 + 0][q] = bf2f(v4.x); Qt[d4 + 1][q] = bf2f(v4.y);
        Qt[d4 + 2][q] = bf2f(v4.z); Qt[d4 + 3][q] = bf2f(v4.w);
    }

    float m[4], lsum[4], acc_o[4][4];
#pragma unroll
    for (int i = 0; i < 4; ++i) {
        m[i] = -1e30f; lsum[i] = 0.f;
#pragma unroll
        for (int j = 0; j < 4; ++j) acc_o[i][j] = 0.f;
    }

    const int ntile = causal ? (qt + 1) : (SEQ / 64);
    for (int kt = 0; kt < ntile; ++kt) {
        const int j0 = kt * 64;
        __syncthreads();
#pragma unroll
        for (int r = 0; r < 4; ++r) {
            int j = srow + 16 * r;
            ushort4 kv = *reinterpret_cast<const ushort4*>(
                &K[base + (size_t)(j0 + j) * D_MODEL + d4]);
            Kt[d4 + 0][j] = bf2f(kv.x); Kt[d4 + 1][j] = bf2f(kv.y);
            Kt[d4 + 2][j] = bf2f(kv.z); Kt[d4 + 3][j] = bf2f(kv.w);
            ushort4 vv = *reinterpret_cast<const ushort4*>(
                &V[base + (size_t)(j0 + j) * D_MODEL + d4]);
            Vs[j][d4 + 0] = bf2f(vv.x); Vs[j][d4 + 1] = bf2f(vv.y);
            Vs[j][d4 + 2] = bf2f(vv.z); Vs[j][d4 + 3] = bf2f(vv.w);
        }
        __syncthreads();

        float s[4][4] = {};
        for (int kk = 0; kk < DH; ++kk) {
            float qv0 = Qt[kk][4 * ty + 0];
            float qv1 = Qt[kk][4 * ty + 1];
            float qv2 = Qt[kk][4 * ty + 2];
            float qv3 = Qt[kk][4 * ty + 3];
            float kv0 = Kt[kk][4 * tx + 0];
            float kv1 = Kt[kk][4 * tx + 1];
            float kv2 = Kt[kk][4 * tx + 2];
            float kv3 = Kt[kk][4 * tx + 3];
            s[0][0] += qv0 * kv0; s[0][1] += qv0 * kv1; s[0][2] += qv0 * kv2; s[0][3] += qv0 * kv3;
            s[1][0] += qv1 * kv0; s[1][1] += qv1 * kv1; s[1][2] += qv1 * kv2; s[1][3] += qv1 * kv3;
            s[2][0] += qv2 * kv0; s[2][1] += qv2 * kv1; s[2][2] += qv2 * kv2; s[2][3] += qv2 * kv3;
            s[3][0] += qv3 * kv0; s[3][1] += qv3 * kv1; s[3][2] += qv3 * kv2; s[3][3] += qv3 * kv3;
        }
#pragma unroll
        for (int i = 0; i < 4; ++i)
#pragma unroll
            for (int j = 0; j < 4; ++j) s[i][j] *= SCALE;

        if (causal && kt == qt) {
#pragma unroll
            for (int i = 0; i < 4; ++i)
#pragma unroll
                for (int j = 0; j < 4; ++j)
                    if (4 * tx + j > 4 * ty + i) s[i][j] = -1e30f;
        }

        float tmax[4], rs[4];
#pragma unroll
        for (int i = 0; i < 4; ++i)
            tmax[i] = fmaxf(fmaxf(s[i][0], s[i][1]), fmaxf(s[i][2], s[i][3]));
#pragma unroll
        for (int d = 1; d < 16; d <<= 1)
#pragma unroll
            for (int i = 0; i < 4; ++i)
                tmax[i] = fmaxf(tmax[i], __shfl_xor(tmax[i], d));

#pragma unroll
        for (int i = 0; i < 4; ++i) {
            float mn = fmaxf(m[i], tmax[i]);
            float sc = __expf(m[i] - mn);
            float sum = 0.f;
#pragma unroll
            for (int j = 0; j < 4; ++j) {
                float p = __expf(s[i][j] - mn);
                s[i][j] = p;
                sum += p;
            }
            rs[i] = sum;
            m[i] = mn;
            lsum[i] *= sc;
#pragma unroll
            for (int j = 0; j < 4; ++j) acc_o[i][j] *= sc;
        }
#pragma unroll
        for (int d = 1; d < 16; d <<= 1)
#pragma unroll
            for (int i = 0; i < 4; ++i) rs[i] += __shfl_xor(rs[i], d);
#pragma unroll
        for (int i = 0; i < 4; ++i) lsum[i] += rs[i];

#pragma unroll
        for (int i = 0; i < 4; ++i)
#pragma unroll
            for (int j = 0; j < 4; ++j)
                Ps[4 * ty + i][4 * tx + j] = s[i][j];
        __syncthreads();

        for (int jj = 0; jj < 64; ++jj) {
            float p0 = Ps[4 * ty + 0][jj];
            float p1 = Ps[4 * ty + 1][jj];
            float p2 = Ps[4 * ty + 2][jj];
            float p3 = Ps[4 * ty + 3][jj];
            float v0 = Vs[jj][4 * tx + 0];
            float v1 = Vs[jj][4 * tx + 1];
            float v2 = Vs[jj][4 * tx + 2];
            float v3 = Vs[jj][4 * tx + 3];
            acc_o[0][0] += p0 * v0; acc_o[0][1] += p0 * v1; acc_o[0][2] += p0 * v2; acc_o[0][3] += p0 * v3;
            acc_o[1][0] += p1 * v0; acc_o[1][1] += p1 * v1; acc_o[1][2] += p1 * v2; acc_o[1][3] += p1 * v3;
            acc_o[2][0] += p2 * v0; acc_o[2][1] += p2 * v1; acc_o[2][2] += p2 * v2; acc_o[2][3] += p2 * v3;
            acc_o[3][0] += p3 * v0; acc_o[3][1] += p3 * v1; acc_o[3][2] += p3 * v2; acc_o[3][3] += p3 * v3;
        }
    }

#pragma unroll
    for (int i = 0; i < 4; ++i) {
        float inv = 1.f / lsum[i];
        ushort4 o = make_ushort4(f2bf(acc_o[i][0] * inv), f2bf(acc_o[i][1] * inv),
                                 f2bf(acc_o[i][2] * inv), f2bf(acc_o[i][3] * inv));
        *reinterpret_cast<ushort4*>(
            &O[base + (size_t)(q0 + 4 * ty + i) * D_MODEL + 4 * tx]) = o;
    }
}

// ---------------------------------------------------------------------------
// out = res + LayerNorm(x)*g + b ; optional bf16 side-copy
// ---------------------------------------------------------------------------
__global__ __launch_bounds__(256) void ln_res_kernel(
    const float* __restrict__ x, const float* __restrict__ res,
    const float* __restrict__ g, const float* __restrict__ bta,
    float* __restrict__ out, unsigned short* __restrict__ outb)
{
    __shared__ float red[256];
    __shared__ float s_mu, s_rstd;

    const int row = blockIdx.x;
    const int tid = threadIdx.x;
    const float4* x4 = reinterpret_cast<const float4*>(x + (size_t)row * D_MODEL);
    float4 v = x4[tid];

    float sum = v.x + v.y + v.z + v.w;
    red[tid] = sum;
    __syncthreads();
    for (int s = 128; s > 0; s >>= 1) {
        if (tid < s) red[tid] += red[tid + s];
        __syncthreads();
    }
    if (tid == 0) s_mu = red[0] * (1.f / D_MODEL);
    __syncthreads();
    const float mu = s_mu;

    float dx = v.x - mu, dy = v.y - mu, dz = v.z - mu, dw = v.w - mu;
    red[tid] = dx * dx + dy * dy + dz * dz + dw * dw;
    __syncthreads();
    for (int s = 128; s > 0; s >>= 1) {
        if (tid < s) red[tid] += red[tid + s];
        __syncthreads();
    }
    if (tid == 0) s_rstd = rsqrtf(red[0] * (1.f / D_MODEL) + EPS);
    __syncthreads();
    const float rstd = s_rstd;

    float4 rv = reinterpret_cast<const float4*>(res + (size_t)row * D_MODEL)[tid];
    float4 gv = reinterpret_cast<const float4*>(g)[tid];
    float4 bv = reinterpret_cast<const float4*>(bta)[tid];

    float4 o;
    o.x = rv.x + dx * rstd * gv.x + bv.x;
    o.y = rv.y + dy * rstd * gv.y + bv.y;
    o.z = rv.z + dz * rstd * gv.z + bv.z;
    o.w = rv.w + dw * rstd * gv.w + bv.w;
    reinterpret_cast<float4*>(out + (size_t)row * D_MODEL)[tid] = o;
    if (outb)
        reinterpret_cast<ushort4*>(outb + (size_t)row * D_MODEL)[tid] =
            make_ushort4(f2bf(o.x), f2bf(o.y), f2bf(o.z), f2bf(o.w));
}

// ---------------------------------------------------------------------------
extern "C" void kernel_launch(void* const* d_in, const int* in_sizes, int n_in,
                              void* d_out, int out_size, void* d_ws, size_t ws_size,
                              hipStream_t stream)
{
    const float* X    = (const float*)d_in[0];
    const float* Wq1  = (const float*)d_in[1];
    const float* Wk1  = (const float*)d_in[2];
    const float* Wv1  = (const float*)d_in[3];
    const float* Wo1  = (const float*)d_in[4];
    const float* Wq2  = (const float*)d_in[5];
    const float* Wk2  = (const float*)d_in[6];
    const float* Wv2  = (const float*)d_in[7];
    const float* Wo2  = (const float*)d_in[8];
    const float* ln_g = (const float*)d_in[9];
    const float* ln_b = (const float*)d_in[10];
    const float* W1   = (const float*)d_in[11];
    const float* b1   = (const float*)d_in[12];
    const float* W2   = (const float*)d_in[13];
    const float* b2   = (const float*)d_in[14];

    // ws layout (bf16 units; total 88 MB < proven-safe 100.7 MB):
    //  [0,4Mi)   WtA (4 weight-transpose slots; reused per phase; W1t in FFN)
    //  [4,8Mi)   Xb (bf16 X); later W2t
    //  [8,24Mi)  qb,kb,vb,t0b (4x4Mi); FFN hidden hb overlays all 16Mi
    //  [24,28Mi) t2b
    //  then fp32: t1 (4Mi floats), t2 (4Mi floats)
    const size_t MI = 1024 * 1024;
    unsigned short* ws16 = (unsigned short*)d_ws;
    unsigned short* WtA = ws16;
    unsigned short* Xb  = ws16 + 4 * MI;   // also W2t in FFN phase
    unsigned short* qb  = ws16 + 8 * MI;
    unsigned short* kb  = ws16 + 12 * MI;
    unsigned short* vb  = ws16 + 16 * MI;
    unsigned short* t0b = ws16 + 20 * MI;
    unsigned short* hb  = qb;              // [TOK][D_FF] bf16 = 16Mi
    unsigned short* t2b = ws16 + 24 * MI;
    float* t1 = (float*)(ws16 + 28 * MI);
    float* t2 = t1 + 4 * MI;

    auto gemm = [&](const unsigned short* A, const unsigned short* Bt,
                    float* Cf, unsigned short* Cb, int M, int N, int K,
                    const float* bias, int relu) {
        gemm_bf16_kernel<<<dim3(N / 128, M / 128), 256, 0, stream>>>(
            A, Bt, Cf, Cb, M, N, K, bias, relu);
    };
    auto tcvt = [&](const float* W, unsigned short* Wt, int K, int N) {
        tcvt_kernel<<<dim3(N / 64, K / 64), 256, 0, stream>>>(W, Wt, K, N);
    };

    dim3 agrid(SEQ / 64, BATCH * N_HEADS);

    // ---- prologue: weights(MHA1) + X -> bf16 ----
    tcvt(Wq1, WtA + 0 * MI, D_MODEL, D_MODEL);
    tcvt(Wk1, WtA + 1 * MI, D_MODEL, D_MODEL);
    tcvt(Wv1, WtA + 2 * MI, D_MODEL, D_MODEL);
    tcvt(Wo1, WtA + 3 * MI, D_MODEL, D_MODEL);
    f2b_kernel<<<dim3(4096), 256, 0, stream>>>(X, Xb, TOK * D_MODEL / 4);

    // ---- MHA 1 (causal) ----
    gemm(Xb, WtA + 0 * MI, nullptr, qb, TOK, D_MODEL, D_MODEL, nullptr, 0);
    gemm(Xb, WtA + 1 * MI, nullptr, kb, TOK, D_MODEL, D_MODEL, nullptr, 0);
    gemm(Xb, WtA + 2 * MI, nullptr, vb, TOK, D_MODEL, D_MODEL, nullptr, 0);
    attn_tile_kernel<<<agrid, 256, 0, stream>>>(qb, kb, vb, t0b, 1);
    gemm(t0b, WtA + 3 * MI, t1, nullptr, TOK, D_MODEL, D_MODEL, nullptr, 0);
    ln_res_kernel<<<dim3(TOK), 256, 0, stream>>>(t1, X, ln_g, ln_b, t2, t2b);

    // ---- MHA 2 (full) ----
    tcvt(Wq2, WtA + 0 * MI, D_MODEL, D_MODEL);
    tcvt(Wk2, WtA + 1 * MI, D_MODEL, D_MODEL);
    tcvt(Wv2, WtA + 2 * MI, D_MODEL, D_MODEL);
    tcvt(Wo2, WtA + 3 * MI, D_MODEL, D_MODEL);
    gemm(t2b, WtA + 0 * MI, nullptr, qb, TOK, D_MODEL, D_MODEL, nullptr, 0);
    gemm(t2b, WtA + 1 * MI, nullptr, kb, TOK, D_MODEL, D_MODEL, nullptr, 0);
    gemm(t2b, WtA + 2 * MI, nullptr, vb, TOK, D_MODEL, D_MODEL, nullptr, 0);
    attn_tile_kernel<<<agrid, 256, 0, stream>>>(qb, kb, vb, t0b, 0);
    gemm(t0b, WtA + 3 * MI, t1, nullptr, TOK, D_MODEL, D_MODEL, nullptr, 0);
    ln_res_kernel<<<dim3(TOK), 256, 0, stream>>>(t1, t1, ln_g, ln_b, t2, t2b);

    // ---- FFN ----
    tcvt(W1, WtA, D_MODEL, D_FF);          // W1t [4096][1024] = 4Mi -> WtA
    tcvt(W2, Xb,  D_FF, D_MODEL);          // W2t [1024][4096] = 4Mi -> Xb slot
    gemm(t2b, WtA, nullptr, hb, TOK, D_FF, D_MODEL, b1, 1);
    gemm(hb, Xb, t1, nullptr, TOK, D_MODEL, D_FF, b2, 0);
    ln_res_kernel<<<dim3(TOK), 256, 0, stream>>>(t1, t2, ln_g, ln_b,
                                                 (float*)d_out, nullptr);
}

// Round 4
// 599.526 us; speedup vs baseline: 17.5276x; 1.8490x over previous
//
#include <hip/hip_runtime.h>
#include <hip/hip_bf16.h>

#define D_MODEL 1024
#define N_HEADS 16
#define DH 64
#define D_FF   4096
#define SEQ    1024
#define BATCH  4
#define TOK    (BATCH*SEQ)
#define EPS    1e-5f
#define SCALE  0.125f   // 1/sqrt(64)

typedef unsigned short USHORT;
typedef __attribute__((ext_vector_type(8))) short short8v;
typedef __attribute__((ext_vector_type(4))) float f32x4;

__device__ __forceinline__ USHORT f2bf(float f) {
    unsigned int u; __builtin_memcpy(&u, &f, 4);
    u += 0x7fffu + ((u >> 16) & 1u);          // RNE
    return (USHORT)(u >> 16);
}
__device__ __forceinline__ float bf2f(USHORT s) {
    unsigned int u = ((unsigned int)s) << 16;
    float f; __builtin_memcpy(&f, &u, 4);
    return f;
}

// swizzled frag read: element (row,c) lives at row*64 + ((c>>3)^(row&7))*8 + (c&7)
__device__ __forceinline__ short8v ld_frag(const USHORT* lds, int row, int c8) {
    return *reinterpret_cast<const short8v*>(
        &lds[row * 64 + (((c8) ^ (row & 7)) << 3)]);
}

// ---------------------------------------------------------------------------
// bf16 MFMA GEMM (m97 structure): C[M,N] = A[M,K] @ Bt[N,K]^T
// Optional extra epilogue: VtOut = C^T in per-head layout [b*16+h][64 d][1024 S]
// (used by the V projection so attention's PV step gets j-contiguous V).
// ---------------------------------------------------------------------------
__global__ __launch_bounds__(256) void gemm_bf16_kernel(
    const USHORT* __restrict__ A,    // [M][K] bf16
    const USHORT* __restrict__ Bt,   // [N][K] bf16
    float* __restrict__ Cf, USHORT* __restrict__ Cb, USHORT* __restrict__ VtOut,
    int M, int N, int K, const float* __restrict__ bias, int relu)
{
    __shared__ USHORT As[128 * 32];
    __shared__ USHORT Bs[128 * 32];

    const int tid = threadIdx.x;
    const int l   = tid & 63;
    const int w   = tid >> 6;
    const int wr  = w >> 1, wc = w & 1;
    const int m0  = blockIdx.y * 128, n0 = blockIdx.x * 128;

    const int u0 = w * 64 + l;
    const int r0 = u0 >> 2, c0 = (u0 & 3) * 8;
    const int u1 = 256 + u0;
    const int r1 = u1 >> 2, c1 = (u1 & 3) * 8;

    const USHORT* a0 = A  + (size_t)(m0 + r0) * K + c0;
    const USHORT* a1 = A  + (size_t)(m0 + r1) * K + c1;
    const USHORT* b0 = Bt + (size_t)(n0 + r0) * K + c0;
    const USHORT* b1 = Bt + (size_t)(n0 + r1) * K + c1;
    USHORT* lda0 = &As[(w * 64) * 8];
    USHORT* lda1 = &As[(256 + w * 64) * 8];
    USHORT* ldb0 = &Bs[(w * 64) * 8];
    USHORT* ldb1 = &Bs[(256 + w * 64) * 8];

    f32x4 acc[4][4];
#pragma unroll
    for (int i = 0; i < 4; ++i)
#pragma unroll
        for (int j = 0; j < 4; ++j) acc[i][j] = (f32x4){0.f, 0.f, 0.f, 0.f};

    const int lr = l & 15;
    const int lk = (l >> 4) * 8;

    for (int k0 = 0; k0 < K; k0 += 32) {
        __builtin_amdgcn_global_load_lds(
            (const __attribute__((address_space(1))) void*)(a0 + k0),
            (__attribute__((address_space(3))) void*)lda0, 16, 0, 0);
        __builtin_amdgcn_global_load_lds(
            (const __attribute__((address_space(1))) void*)(a1 + k0),
            (__attribute__((address_space(3))) void*)lda1, 16, 0, 0);
        __builtin_amdgcn_global_load_lds(
            (const __attribute__((address_space(1))) void*)(b0 + k0),
            (__attribute__((address_space(3))) void*)ldb0, 16, 0, 0);
        __builtin_amdgcn_global_load_lds(
            (const __attribute__((address_space(1))) void*)(b1 + k0),
            (__attribute__((address_space(3))) void*)ldb1, 16, 0, 0);
        __syncthreads();

        short8v af[4], bfr[4];
#pragma unroll
        for (int mi = 0; mi < 4; ++mi)
            af[mi] = *reinterpret_cast<const short8v*>(
                &As[(wr * 64 + mi * 16 + lr) * 32 + lk]);
#pragma unroll
        for (int ni = 0; ni < 4; ++ni)
            bfr[ni] = *reinterpret_cast<const short8v*>(
                &Bs[(wc * 64 + ni * 16 + lr) * 32 + lk]);
#pragma unroll
        for (int mi = 0; mi < 4; ++mi)
#pragma unroll
            for (int ni = 0; ni < 4; ++ni)
                acc[mi][ni] = __builtin_amdgcn_mfma_f32_16x16x32_bf16(
                    af[mi], bfr[ni], acc[mi][ni], 0, 0, 0);
        __syncthreads();
    }

    // epilogue: C/D layout col = lane&15, row = (lane>>4)*4 + reg  [m89/m91]
#pragma unroll
    for (int mi = 0; mi < 4; ++mi) {
        const int row = m0 + wr * 64 + mi * 16 + (l >> 4) * 4;
#pragma unroll
        for (int ni = 0; ni < 4; ++ni) {
            const int col = n0 + wc * 64 + ni * 16 + lr;
            const float bv = bias ? bias[col] : 0.f;
#pragma unroll
            for (int j = 0; j < 4; ++j) {
                float v = acc[mi][ni][j] + bv;
                if (relu) v = fmaxf(v, 0.f);
                const size_t idx = (size_t)(row + j) * N + col;
                if (Cf) Cf[idx] = v;
                if (Cb) Cb[idx] = f2bf(v);
            }
            if (VtOut) {   // Vt[b*16+h][d][S]; the 4 regs are 4 consecutive tokens
                const int bb = row >> 10, jr = row & 1023;
                const int hh = col >> 6, dd = col & 63;
                ushort4 pk = make_ushort4(f2bf(acc[mi][ni][0]), f2bf(acc[mi][ni][1]),
                                          f2bf(acc[mi][ni][2]), f2bf(acc[mi][ni][3]));
                *reinterpret_cast<ushort4*>(
                    &VtOut[((size_t)(bb * 16 + hh) * 64 + dd) * 1024 + jr]) = pk;
            }
        }
    }
}

// ---------------------------------------------------------------------------
// Weight convert+transpose: W fp32 [K][N] -> Wt bf16 [N][K]. 64x64 LDS tiles.
// ---------------------------------------------------------------------------
__global__ __launch_bounds__(256) void tcvt_kernel(
    const float* __restrict__ W, USHORT* __restrict__ Wt, int K, int N)
{
    __shared__ USHORT L[64][65];
    const int tid = threadIdx.x;
    const int tx = tid & 15, ty = tid >> 4;
    const int n0 = blockIdx.x * 64, k0 = blockIdx.y * 64;
#pragma unroll
    for (int r = 0; r < 4; ++r) {
        int kr = ty + 16 * r;
        float4 v = *reinterpret_cast<const float4*>(
            &W[(size_t)(k0 + kr) * N + n0 + tx * 4]);
        L[tx * 4 + 0][kr] = f2bf(v.x);
        L[tx * 4 + 1][kr] = f2bf(v.y);
        L[tx * 4 + 2][kr] = f2bf(v.z);
        L[tx * 4 + 3][kr] = f2bf(v.w);
    }
    __syncthreads();
#pragma unroll
    for (int r = 0; r < 4; ++r) {
        int nr = ty + 16 * r;
        ushort4 o = make_ushort4(L[nr][tx * 4 + 0], L[nr][tx * 4 + 1],
                                 L[nr][tx * 4 + 2], L[nr][tx * 4 + 3]);
        *reinterpret_cast<ushort4*>(&Wt[(size_t)(n0 + nr) * K + k0 + tx * 4]) = o;
    }
}

// fp32 -> bf16 elementwise (n4 = count/4)
__global__ __launch_bounds__(256) void f2b_kernel(
    const float* __restrict__ in, USHORT* __restrict__ out, int n4)
{
    int i = blockIdx.x * 256 + threadIdx.x;
    if (i < n4) {
        float4 v = reinterpret_cast<const float4*>(in)[i];
        reinterpret_cast<ushort4*>(out)[i] =
            make_ushort4(f2bf(v.x), f2bf(v.y), f2bf(v.z), f2bf(v.w));
    }
}

// ---------------------------------------------------------------------------
// MFMA flash attention. Block = (b,h, 64 q-rows), 4 waves; wave owns a 16-row
// q-strip. K-tile (j,d) and Vt-tile (d,j) staged via global_load_lds into
// XOR-swizzled LDS (swizzle applied on the per-lane GLOBAL source, m173).
// S = mfma(Qfrag, Kfrag); online softmax per 16-lane group (shfl_xor);
// P staged per-wave in swizzled LDS; O += mfma(Pfrag, Vtfrag).
// ---------------------------------------------------------------------------
__global__ __launch_bounds__(256) void attn_mfma_kernel(
    const USHORT* __restrict__ Q, const USHORT* __restrict__ K,
    const USHORT* __restrict__ Vt, USHORT* __restrict__ O, int causal)
{
    __shared__ USHORT Qs[64 * 64];
    __shared__ USHORT Ks[64 * 64];
    __shared__ USHORT Vs[64 * 64];
    __shared__ USHORT Ps[4][16 * 64];

    const int tid = threadIdx.x;
    const int l  = tid & 63;
    const int w  = tid >> 6;
    const int lr = l & 15;
    const int lg = l >> 4;
    const int qt = blockIdx.x;
    const int bh = blockIdx.y;
    const int h = bh & 15, b = bh >> 4;
    const int q0 = qt * 64;

    const USHORT* gq  = Q  + (size_t)(b * SEQ + q0) * D_MODEL + h * DH;
    const USHORT* gk0 = K  + (size_t)b * SEQ * D_MODEL + h * DH;
    const USHORT* gv0 = Vt + (size_t)bh * DH * SEQ;

    // staging source offsets (inverse-swizzled): unit u -> row u>>3, block (u&7)^(row&7)
    const int r0s = tid >> 3,         c0s = (tid & 7) ^ (r0s & 7);
    const int r1s = (256 + tid) >> 3, c1s = (tid & 7) ^ (r1s & 7);
    const size_t so0 = (size_t)r0s * 1024 + c0s * 8;   // Q/K/Vt all have row stride 1024
    const size_t so1 = (size_t)r1s * 1024 + c1s * 8;
    const int db0 = (tid & 192) << 3;          // wave-uniform LDS unit base (ushorts)
    const int db1 = (256 << 3) + db0;

#define STAGE(ldsb, gsrc) do {                                                  \
    __builtin_amdgcn_global_load_lds(                                           \
        (const __attribute__((address_space(1))) void*)((gsrc) + so0),          \
        (__attribute__((address_space(3))) void*)((ldsb) + db0), 16, 0, 0);     \
    __builtin_amdgcn_global_load_lds(                                           \
        (const __attribute__((address_space(1))) void*)((gsrc) + so1),          \
        (__attribute__((address_space(3))) void*)((ldsb) + db1), 16, 0, 0);     \
} while (0)

    STAGE(Qs, gq);

    f32x4 oacc[4];
    float m_[4], l_[4];
#pragma unroll
    for (int r = 0; r < 4; ++r) {
        m_[r] = -1e30f; l_[r] = 0.f;
    }
#pragma unroll
    for (int d = 0; d < 4; ++d) oacc[d] = (f32x4){0.f, 0.f, 0.f, 0.f};

    __syncthreads();
    short8v qa0 = ld_frag(Qs, w * 16 + lr, lg);
    short8v qa1 = ld_frag(Qs, w * 16 + lr, 4 + lg);

    const int ntile = causal ? (qt + 1) : (SEQ / 64);
    for (int kt = 0; kt < ntile; ++kt) {
        const int j0 = kt * 64;
        __syncthreads();                       // all waves done with prev K/V
        STAGE(Ks, gk0 + (size_t)j0 * D_MODEL);
        STAGE(Vs, gv0 + j0);
        __syncthreads();                       // staging drained

        f32x4 sa[4];
#pragma unroll
        for (int jb = 0; jb < 4; ++jb) {
            sa[jb] = (f32x4){0.f, 0.f, 0.f, 0.f};
            sa[jb] = __builtin_amdgcn_mfma_f32_16x16x32_bf16(
                qa0, ld_frag(Ks, jb * 16 + lr, lg), sa[jb], 0, 0, 0);
            sa[jb] = __builtin_amdgcn_mfma_f32_16x16x32_bf16(
                qa1, ld_frag(Ks, jb * 16 + lr, 4 + lg), sa[jb], 0, 0, 0);
        }

        // scale + causal mask (diagonal tile only)
#pragma unroll
        for (int jb = 0; jb < 4; ++jb)
#pragma unroll
            for (int r = 0; r < 4; ++r) {
                float s = sa[jb][r] * SCALE;
                if (causal && kt == qt &&
                    (j0 + jb * 16 + lr) > (q0 + w * 16 + lg * 4 + r))
                    s = -1e30f;
                sa[jb][r] = s;
            }

        // online softmax per q-row (state replicated across the 16-lane group)
#pragma unroll
        for (int r = 0; r < 4; ++r) {
            float tm = fmaxf(fmaxf(sa[0][r], sa[1][r]), fmaxf(sa[2][r], sa[3][r]));
            tm = fmaxf(tm, __shfl_xor(tm, 1));
            tm = fmaxf(tm, __shfl_xor(tm, 2));
            tm = fmaxf(tm, __shfl_xor(tm, 4));
            tm = fmaxf(tm, __shfl_xor(tm, 8));
            float mn = fmaxf(m_[r], tm);
            float sc = __expf(m_[r] - mn);
            m_[r] = mn;
            float rs_ = 0.f;
#pragma unroll
            for (int jb = 0; jb < 4; ++jb) {
                float p = __expf(sa[jb][r] - mn);
                sa[jb][r] = p;
                rs_ += p;
            }
            rs_ += __shfl_xor(rs_, 1);
            rs_ += __shfl_xor(rs_, 2);
            rs_ += __shfl_xor(rs_, 4);
            rs_ += __shfl_xor(rs_, 8);
            l_[r] = l_[r] * sc + rs_;
#pragma unroll
            for (int d = 0; d < 4; ++d) oacc[d][r] *= sc;
        }

        // P -> per-wave swizzled LDS (bf16)
        USHORT* PsW = Ps[w];
#pragma unroll
        for (int jb = 0; jb < 4; ++jb) {
            const int c8 = jb * 2 + (lr >> 3), cl = lr & 7;
#pragma unroll
            for (int r = 0; r < 4; ++r) {
                const int row = lg * 4 + r;
                PsW[row * 64 + ((c8 ^ (row & 7)) << 3) + cl] = f2bf(sa[jb][r]);
            }
        }

        // PV
        short8v pa0 = ld_frag(PsW, lr, lg);
        short8v pa1 = ld_frag(PsW, lr, 4 + lg);
#pragma unroll
        for (int d = 0; d < 4; ++d) {
            oacc[d] = __builtin_amdgcn_mfma_f32_16x16x32_bf16(
                pa0, ld_frag(Vs, d * 16 + lr, lg), oacc[d], 0, 0, 0);
            oacc[d] = __builtin_amdgcn_mfma_f32_16x16x32_bf16(
                pa1, ld_frag(Vs, d * 16 + lr, 4 + lg), oacc[d], 0, 0, 0);
        }
    }
#undef STAGE

    USHORT* go = O + (size_t)(b * SEQ + q0 + w * 16) * D_MODEL + h * DH;
#pragma unroll
    for (int r = 0; r < 4; ++r) {
        const float inv = 1.f / l_[r];
        const int qrow = lg * 4 + r;
#pragma unroll
        for (int d = 0; d < 4; ++d)
            go[(size_t)qrow * D_MODEL + d * 16 + lr] = f2bf(oacc[d][r] * inv);
    }
}

// ---------------------------------------------------------------------------
// out = res + LayerNorm(x)*g + b ; optional bf16 side-copy
// ---------------------------------------------------------------------------
__global__ __launch_bounds__(256) void ln_res_kernel(
    const float* __restrict__ x, const float* __restrict__ res,
    const float* __restrict__ g, const float* __restrict__ bta,
    float* __restrict__ out, USHORT* __restrict__ outb)
{
    __shared__ float red[256];
    __shared__ float s_mu, s_rstd;

    const int row = blockIdx.x;
    const int tid = threadIdx.x;
    const float4* x4 = reinterpret_cast<const float4*>(x + (size_t)row * D_MODEL);
    float4 v = x4[tid];

    float sum = v.x + v.y + v.z + v.w;
    red[tid] = sum;
    __syncthreads();
    for (int s = 128; s > 0; s >>= 1) {
        if (tid < s) red[tid] += red[tid + s];
        __syncthreads();
    }
    if (tid == 0) s_mu = red[0] * (1.f / D_MODEL);
    __syncthreads();
    const float mu = s_mu;

    float dx = v.x - mu, dy = v.y - mu, dz = v.z - mu, dw = v.w - mu;
    red[tid] = dx * dx + dy * dy + dz * dz + dw * dw;
    __syncthreads();
    for (int s = 128; s > 0; s >>= 1) {
        if (tid < s) red[tid] += red[tid + s];
        __syncthreads();
    }
    if (tid == 0) s_rstd = rsqrtf(red[0] * (1.f / D_MODEL) + EPS);
    __syncthreads();
    const float rstd = s_rstd;

    float4 rv = reinterpret_cast<const float4*>(res + (size_t)row * D_MODEL)[tid];
    float4 gv = reinterpret_cast<const float4*>(g)[tid];
    float4 bv = reinterpret_cast<const float4*>(bta)[tid];

    float4 o;
    o.x = rv.x + dx * rstd * gv.x + bv.x;
    o.y = rv.y + dy * rstd * gv.y + bv.y;
    o.z = rv.z + dz * rstd * gv.z + bv.z;
    o.w = rv.w + dw * rstd * gv.w + bv.w;
    reinterpret_cast<float4*>(out + (size_t)row * D_MODEL)[tid] = o;
    if (outb)
        reinterpret_cast<ushort4*>(outb + (size_t)row * D_MODEL)[tid] =
            make_ushort4(f2bf(o.x), f2bf(o.y), f2bf(o.z), f2bf(o.w));
}

// ---------------------------------------------------------------------------
extern "C" void kernel_launch(void* const* d_in, const int* in_sizes, int n_in,
                              void* d_out, int out_size, void* d_ws, size_t ws_size,
                              hipStream_t stream)
{
    const float* X    = (const float*)d_in[0];
    const float* Wq1  = (const float*)d_in[1];
    const float* Wk1  = (const float*)d_in[2];
    const float* Wv1  = (const float*)d_in[3];
    const float* Wo1  = (const float*)d_in[4];
    const float* Wq2  = (const float*)d_in[5];
    const float* Wk2  = (const float*)d_in[6];
    const float* Wv2  = (const float*)d_in[7];
    const float* Wo2  = (const float*)d_in[8];
    const float* ln_g = (const float*)d_in[9];
    const float* ln_b = (const float*)d_in[10];
    const float* W1   = (const float*)d_in[11];
    const float* b1   = (const float*)d_in[12];
    const float* W2   = (const float*)d_in[13];
    const float* b2   = (const float*)d_in[14];

    // ws layout (ushort units; total 96 MB, proven-safe <= 100.7 MB):
    //  [0,4Mi)   WtA (4 weight-transpose slots)
    //  [4,8Mi)   Xb ; later W2t
    //  [8,24Mi)  qb,kb,vb,t0b ; FFN hidden hb overlays
    //  [24,28Mi) t2b
    //  [28,36Mi) t1 fp32 ; [36,44Mi) t2 fp32
    //  [44,48Mi) Vtb (V^T per-head [64][64][1024])
    const size_t MI = 1024 * 1024;
    USHORT* ws16 = (USHORT*)d_ws;
    USHORT* WtA = ws16;
    USHORT* Xb  = ws16 + 4 * MI;
    USHORT* qb  = ws16 + 8 * MI;
    USHORT* kb  = ws16 + 12 * MI;
    USHORT* t0b = ws16 + 20 * MI;
    USHORT* hb  = qb;
    USHORT* t2b = ws16 + 24 * MI;
    float* t1 = (float*)(ws16 + 28 * MI);
    float* t2 = t1 + 4 * MI;
    USHORT* Vtb = ws16 + 44 * MI;

    auto gemm = [&](const USHORT* A, const USHORT* Bt, float* Cf, USHORT* Cb,
                    USHORT* Vt, int M, int N, int K, const float* bias, int relu) {
        gemm_bf16_kernel<<<dim3(N / 128, M / 128), 256, 0, stream>>>(
            A, Bt, Cf, Cb, Vt, M, N, K, bias, relu);
    };
    auto tcvt = [&](const float* W, USHORT* Wt, int K, int N) {
        tcvt_kernel<<<dim3(N / 64, K / 64), 256, 0, stream>>>(W, Wt, K, N);
    };

    dim3 agrid(SEQ / 64, BATCH * N_HEADS);

    // ---- prologue: weights(MHA1) + X -> bf16 ----
    tcvt(Wq1, WtA + 0 * MI, D_MODEL, D_MODEL);
    tcvt(Wk1, WtA + 1 * MI, D_MODEL, D_MODEL);
    tcvt(Wv1, WtA + 2 * MI, D_MODEL, D_MODEL);
    tcvt(Wo1, WtA + 3 * MI, D_MODEL, D_MODEL);
    f2b_kernel<<<dim3(4096), 256, 0, stream>>>(X, Xb, TOK * D_MODEL / 4);

    // ---- MHA 1 (causal) ----
    gemm(Xb, WtA + 0 * MI, nullptr, qb, nullptr, TOK, D_MODEL, D_MODEL, nullptr, 0);
    gemm(Xb, WtA + 1 * MI, nullptr, kb, nullptr, TOK, D_MODEL, D_MODEL, nullptr, 0);
    gemm(Xb, WtA + 2 * MI, nullptr, nullptr, Vtb, TOK, D_MODEL, D_MODEL, nullptr, 0);
    attn_mfma_kernel<<<agrid, 256, 0, stream>>>(qb, kb, Vtb, t0b, 1);
    gemm(t0b, WtA + 3 * MI, t1, nullptr, nullptr, TOK, D_MODEL, D_MODEL, nullptr, 0);
    ln_res_kernel<<<dim3(TOK), 256, 0, stream>>>(t1, X, ln_g, ln_b, t2, t2b);

    // ---- MHA 2 (full) ----
    tcvt(Wq2, WtA + 0 * MI, D_MODEL, D_MODEL);
    tcvt(Wk2, WtA + 1 * MI, D_MODEL, D_MODEL);
    tcvt(Wv2, WtA + 2 * MI, D_MODEL, D_MODEL);
    tcvt(Wo2, WtA + 3 * MI, D_MODEL, D_MODEL);
    gemm(t2b, WtA + 0 * MI, nullptr, qb, nullptr, TOK, D_MODEL, D_MODEL, nullptr, 0);
    gemm(t2b, WtA + 1 * MI, nullptr, kb, nullptr, TOK, D_MODEL, D_MODEL, nullptr, 0);
    gemm(t2b, WtA + 2 * MI, nullptr, nullptr, Vtb, TOK, D_MODEL, D_MODEL, nullptr, 0);
    attn_mfma_kernel<<<agrid, 256, 0, stream>>>(qb, kb, Vtb, t0b, 0);
    gemm(t0b, WtA + 3 * MI, t1, nullptr, nullptr, TOK, D_MODEL, D_MODEL, nullptr, 0);
    ln_res_kernel<<<dim3(TOK), 256, 0, stream>>>(t1, t1, ln_g, ln_b, t2, t2b);

    // ---- FFN ----
    tcvt(W1, WtA, D_MODEL, D_FF);
    tcvt(W2, Xb,  D_FF, D_MODEL);
    gemm(t2b, WtA, nullptr, hb, nullptr, TOK, D_FF, D_MODEL, b1, 1);
    gemm(hb, Xb, t1, nullptr, nullptr, TOK, D_MODEL, D_FF, b2, 0);
    ln_res_kernel<<<dim3(TOK), 256, 0, stream>>>(t1, t2, ln_g, ln_b,
                                                 (float*)d_out, nullptr);
}

// Round 5
// 541.530 us; speedup vs baseline: 19.4047x; 1.1071x over previous
//
#include <hip/hip_runtime.h>
#include <hip/hip_bf16.h>

#define D_MODEL 1024
#define N_HEADS 16
#define DH 64
#define D_FF   4096
#define SEQ    1024
#define BATCH  4
#define TOK    (BATCH*SEQ)
#define EPS    1e-5f
#define SCALE  0.125f   // 1/sqrt(64)

typedef unsigned short USHORT;
typedef __attribute__((ext_vector_type(8))) short short8v;
typedef __attribute__((ext_vector_type(4))) float f32x4;

__device__ __forceinline__ USHORT f2bf(float f) {
    unsigned int u; __builtin_memcpy(&u, &f, 4);
    u += 0x7fffu + ((u >> 16) & 1u);          // RNE
    return (USHORT)(u >> 16);
}
__device__ __forceinline__ float bf2f(USHORT s) {
    unsigned int u = ((unsigned int)s) << 16;
    float f; __builtin_memcpy(&f, &u, 4);
    return f;
}

// swizzled frag read: element (row,c) lives at row*64 + ((c>>3)^(row&7))*8 + (c&7)
__device__ __forceinline__ short8v ld_frag(const USHORT* lds, int row, int c8) {
    return *reinterpret_cast<const short8v*>(
        &lds[row * 64 + (((c8) ^ (row & 7)) << 3)]);
}

#define GLDS(gsrc, ldst) \
    __builtin_amdgcn_global_load_lds( \
        (const __attribute__((address_space(1))) void*)(gsrc), \
        (__attribute__((address_space(3))) void*)(ldst), 16, 0, 0)

// ---------------------------------------------------------------------------
// bf16 MFMA GEMM: C[M,N] = A[M,K] @ Bt[N,K]^T
// 128x128 tile, BK=32, 4 waves. Double-buffered LDS: next K-tile's
// global_load_lds issued BEFORE computing current tile (T3-minimum recipe);
// the single end-of-iter __syncthreads (implicit vmcnt(0)) completes it.
// Optional extra epilogue: VtOut = C^T per-head [b*16+h][64 d][1024 S].
// ---------------------------------------------------------------------------
__global__ __launch_bounds__(256) void gemm_bf16_kernel(
    const USHORT* __restrict__ A,    // [M][K] bf16
    const USHORT* __restrict__ Bt,   // [N][K] bf16
    float* __restrict__ Cf, USHORT* __restrict__ Cb, USHORT* __restrict__ VtOut,
    int M, int N, int K, const float* __restrict__ bias, int relu)
{
    __shared__ USHORT As[2][128 * 32];
    __shared__ USHORT Bs[2][128 * 32];

    const int tid = threadIdx.x;
    const int l   = tid & 63;
    const int w   = tid >> 6;
    const int wr  = w >> 1, wc = w & 1;
    const int m0  = blockIdx.y * 128, n0 = blockIdx.x * 128;

    const int u0 = w * 64 + l;
    const int r0 = u0 >> 2, c0 = (u0 & 3) * 8;
    const int u1 = 256 + u0;
    const int r1 = u1 >> 2, c1 = (u1 & 3) * 8;

    const USHORT* a0 = A  + (size_t)(m0 + r0) * K + c0;
    const USHORT* a1 = A  + (size_t)(m0 + r1) * K + c1;
    const USHORT* b0 = Bt + (size_t)(n0 + r0) * K + c0;
    const USHORT* b1 = Bt + (size_t)(n0 + r1) * K + c1;
    const int la0 = (w * 64) * 8;          // LDS unit offsets within a buffer
    const int la1 = (256 + w * 64) * 8;

#define GSTAGE(buf, k0) do {                        \
    GLDS(a0 + (k0), &As[buf][la0]);                 \
    GLDS(a1 + (k0), &As[buf][la1]);                 \
    GLDS(b0 + (k0), &Bs[buf][la0]);                 \
    GLDS(b1 + (k0), &Bs[buf][la1]);                 \
} while (0)

    f32x4 acc[4][4];
#pragma unroll
    for (int i = 0; i < 4; ++i)
#pragma unroll
        for (int j = 0; j < 4; ++j) acc[i][j] = (f32x4){0.f, 0.f, 0.f, 0.f};

    const int lr = l & 15;
    const int lk = (l >> 4) * 8;
    const int nk = K >> 5;

    GSTAGE(0, 0);
    __syncthreads();                       // tile 0 staged (vmcnt drained)

    for (int t = 0; t < nk; ++t) {
        const int cur = t & 1;
        if (t + 1 < nk) GSTAGE(cur ^ 1, (t + 1) << 5);   // prefetch next tile

        short8v af[4], bfr[4];
#pragma unroll
        for (int mi = 0; mi < 4; ++mi)
            af[mi] = *reinterpret_cast<const short8v*>(
                &As[cur][(wr * 64 + mi * 16 + lr) * 32 + lk]);
#pragma unroll
        for (int ni = 0; ni < 4; ++ni)
            bfr[ni] = *reinterpret_cast<const short8v*>(
                &Bs[cur][(wc * 64 + ni * 16 + lr) * 32 + lk]);
#pragma unroll
        for (int mi = 0; mi < 4; ++mi)
#pragma unroll
            for (int ni = 0; ni < 4; ++ni)
                acc[mi][ni] = __builtin_amdgcn_mfma_f32_16x16x32_bf16(
                    af[mi], bfr[ni], acc[mi][ni], 0, 0, 0);
        __syncthreads();   // drains prefetch (vmcnt0) + guards buffer reuse
    }
#undef GSTAGE

    // epilogue: C/D layout col = lane&15, row = (lane>>4)*4 + reg  [m89/m91]
#pragma unroll
    for (int mi = 0; mi < 4; ++mi) {
        const int row = m0 + wr * 64 + mi * 16 + (l >> 4) * 4;
#pragma unroll
        for (int ni = 0; ni < 4; ++ni) {
            const int col = n0 + wc * 64 + ni * 16 + lr;
            const float bv = bias ? bias[col] : 0.f;
#pragma unroll
            for (int j = 0; j < 4; ++j) {
                float v = acc[mi][ni][j] + bv;
                if (relu) v = fmaxf(v, 0.f);
                const size_t idx = (size_t)(row + j) * N + col;
                if (Cf) Cf[idx] = v;
                if (Cb) Cb[idx] = f2bf(v);
            }
            if (VtOut) {   // Vt[b*16+h][d][S]; the 4 regs are 4 consecutive tokens
                const int bb = row >> 10, jr = row & 1023;
                const int hh = col >> 6, dd = col & 63;
                ushort4 pk = make_ushort4(f2bf(acc[mi][ni][0]), f2bf(acc[mi][ni][1]),
                                          f2bf(acc[mi][ni][2]), f2bf(acc[mi][ni][3]));
                *reinterpret_cast<ushort4*>(
                    &VtOut[((size_t)(bb * 16 + hh) * 64 + dd) * 1024 + jr]) = pk;
            }
        }
    }
}

// ---------------------------------------------------------------------------
// Weight convert+transpose: W fp32 [K][N] -> Wt bf16 [N][K]. 64x64 LDS tiles.
// Batched x4 variant (blockIdx.z selects the matrix) to cut launch count.
// ---------------------------------------------------------------------------
struct TcvtB4 {
    const float* s0; const float* s1; const float* s2; const float* s3;
    USHORT* d0; USHORT* d1; USHORT* d2; USHORT* d3;
};

__device__ __forceinline__ void tcvt_body(
    const float* __restrict__ W, USHORT* __restrict__ Wt, int K, int N)
{
    __shared__ USHORT L[64][65];
    const int tid = threadIdx.x;
    const int tx = tid & 15, ty = tid >> 4;
    const int n0 = blockIdx.x * 64, k0 = blockIdx.y * 64;
#pragma unroll
    for (int r = 0; r < 4; ++r) {
        int kr = ty + 16 * r;
        float4 v = *reinterpret_cast<const float4*>(
            &W[(size_t)(k0 + kr) * N + n0 + tx * 4]);
        L[tx * 4 + 0][kr] = f2bf(v.x);
        L[tx * 4 + 1][kr] = f2bf(v.y);
        L[tx * 4 + 2][kr] = f2bf(v.z);
        L[tx * 4 + 3][kr] = f2bf(v.w);
    }
    __syncthreads();
#pragma unroll
    for (int r = 0; r < 4; ++r) {
        int nr = ty + 16 * r;
        ushort4 o = make_ushort4(L[nr][tx * 4 + 0], L[nr][tx * 4 + 1],
                                 L[nr][tx * 4 + 2], L[nr][tx * 4 + 3]);
        *reinterpret_cast<ushort4*>(&Wt[(size_t)(n0 + nr) * K + k0 + tx * 4]) = o;
    }
}

__global__ __launch_bounds__(256) void tcvt_kernel(
    const float* __restrict__ W, USHORT* __restrict__ Wt, int K, int N)
{
    tcvt_body(W, Wt, K, N);
}

__global__ __launch_bounds__(256) void tcvt4_kernel(TcvtB4 p, int K, int N)
{
    const int z = blockIdx.z;
    const float* W = (z == 0) ? p.s0 : (z == 1) ? p.s1 : (z == 2) ? p.s2 : p.s3;
    USHORT*    Wt = (z == 0) ? p.d0 : (z == 1) ? p.d1 : (z == 2) ? p.d2 : p.d3;
    tcvt_body(W, Wt, K, N);
}

// fp32 -> bf16 elementwise (n4 = count/4)
__global__ __launch_bounds__(256) void f2b_kernel(
    const float* __restrict__ in, USHORT* __restrict__ out, int n4)
{
    int i = blockIdx.x * 256 + threadIdx.x;
    if (i < n4) {
        float4 v = reinterpret_cast<const float4*>(in)[i];
        reinterpret_cast<ushort4*>(out)[i] =
            make_ushort4(f2bf(v.x), f2bf(v.y), f2bf(v.z), f2bf(v.w));
    }
}

// ---------------------------------------------------------------------------
// MFMA flash attention, double-buffered K/V staging (same T3-minimum recipe).
// Block = (b,h, 64 q-rows), 4 waves; wave owns a 16-row q-strip.
// ---------------------------------------------------------------------------
__global__ __launch_bounds__(256) void attn_mfma_kernel(
    const USHORT* __restrict__ Q, const USHORT* __restrict__ K,
    const USHORT* __restrict__ Vt, USHORT* __restrict__ O, int causal)
{
    __shared__ USHORT Qs[64 * 64];
    __shared__ USHORT Ks[2][64 * 64];
    __shared__ USHORT Vs[2][64 * 64];
    __shared__ USHORT Ps[4][16 * 64];

    const int tid = threadIdx.x;
    const int l  = tid & 63;
    const int w  = tid >> 6;
    const int lr = l & 15;
    const int lg = l >> 4;
    const int qt = blockIdx.x;
    const int bh = blockIdx.y;
    const int h = bh & 15, b = bh >> 4;
    const int q0 = qt * 64;

    const USHORT* gq  = Q  + (size_t)(b * SEQ + q0) * D_MODEL + h * DH;
    const USHORT* gk0 = K  + (size_t)b * SEQ * D_MODEL + h * DH;
    const USHORT* gv0 = Vt + (size_t)bh * DH * SEQ;

    // staging source offsets (inverse-swizzled): unit u -> row u>>3, block (u&7)^(row&7)
    const int r0s = tid >> 3,         c0s = (tid & 7) ^ (r0s & 7);
    const int r1s = (256 + tid) >> 3, c1s = (tid & 7) ^ (r1s & 7);
    const size_t so0 = (size_t)r0s * 1024 + c0s * 8;   // Q/K/Vt row stride 1024
    const size_t so1 = (size_t)r1s * 1024 + c1s * 8;
    const int db0 = (tid & 192) << 3;          // wave-uniform LDS unit base
    const int db1 = (256 << 3) + db0;

#define STAGE(ldsb, gsrc) do {                 \
    GLDS((gsrc) + so0, (ldsb) + db0);          \
    GLDS((gsrc) + so1, (ldsb) + db1);          \
} while (0)

    STAGE(Qs, gq);
    STAGE(Ks[0], gk0);
    STAGE(Vs[0], gv0);

    f32x4 oacc[4];
    float m_[4], l_[4];
#pragma unroll
    for (int r = 0; r < 4; ++r) {
        m_[r] = -1e30f; l_[r] = 0.f;
    }
#pragma unroll
    for (int d = 0; d < 4; ++d) oacc[d] = (f32x4){0.f, 0.f, 0.f, 0.f};

    __syncthreads();                           // Q + tile 0 staged
    short8v qa0 = ld_frag(Qs, w * 16 + lr, lg);
    short8v qa1 = ld_frag(Qs, w * 16 + lr, 4 + lg);

    const int ntile = causal ? (qt + 1) : (SEQ / 64);
    for (int kt = 0; kt < ntile; ++kt) {
        const int cur = kt & 1;
        if (kt + 1 < ntile) {                  // prefetch next K/V tile
            STAGE(Ks[cur ^ 1], gk0 + (size_t)(kt + 1) * 64 * D_MODEL);
            STAGE(Vs[cur ^ 1], gv0 + (kt + 1) * 64);
        }
        const int j0 = kt * 64;

        f32x4 sa[4];
#pragma unroll
        for (int jb = 0; jb < 4; ++jb) {
            sa[jb] = (f32x4){0.f, 0.f, 0.f, 0.f};
            sa[jb] = __builtin_amdgcn_mfma_f32_16x16x32_bf16(
                qa0, ld_frag(Ks[cur], jb * 16 + lr, lg), sa[jb], 0, 0, 0);
            sa[jb] = __builtin_amdgcn_mfma_f32_16x16x32_bf16(
                qa1, ld_frag(Ks[cur], jb * 16 + lr, 4 + lg), sa[jb], 0, 0, 0);
        }

        // scale + causal mask (diagonal tile only)
#pragma unroll
        for (int jb = 0; jb < 4; ++jb)
#pragma unroll
            for (int r = 0; r < 4; ++r) {
                float s = sa[jb][r] * SCALE;
                if (causal && kt == qt &&
                    (j0 + jb * 16 + lr) > (q0 + w * 16 + lg * 4 + r))
                    s = -1e30f;
                sa[jb][r] = s;
            }

        // online softmax per q-row (state replicated across the 16-lane group)
#pragma unroll
        for (int r = 0; r < 4; ++r) {
            float tm = fmaxf(fmaxf(sa[0][r], sa[1][r]), fmaxf(sa[2][r], sa[3][r]));
            tm = fmaxf(tm, __shfl_xor(tm, 1));
            tm = fmaxf(tm, __shfl_xor(tm, 2));
            tm = fmaxf(tm, __shfl_xor(tm, 4));
            tm = fmaxf(tm, __shfl_xor(tm, 8));
            float mn = fmaxf(m_[r], tm);
            float sc = __expf(m_[r] - mn);
            m_[r] = mn;
            float rs_ = 0.f;
#pragma unroll
            for (int jb = 0; jb < 4; ++jb) {
                float p = __expf(sa[jb][r] - mn);
                sa[jb][r] = p;
                rs_ += p;
            }
            rs_ += __shfl_xor(rs_, 1);
            rs_ += __shfl_xor(rs_, 2);
            rs_ += __shfl_xor(rs_, 4);
            rs_ += __shfl_xor(rs_, 8);
            l_[r] = l_[r] * sc + rs_;
#pragma unroll
            for (int d = 0; d < 4; ++d) oacc[d][r] *= sc;
        }

        // P -> per-wave swizzled LDS (bf16)
        USHORT* PsW = Ps[w];
#pragma unroll
        for (int jb = 0; jb < 4; ++jb) {
            const int c8 = jb * 2 + (lr >> 3), cl = lr & 7;
#pragma unroll
            for (int r = 0; r < 4; ++r) {
                const int row = lg * 4 + r;
                PsW[row * 64 + ((c8 ^ (row & 7)) << 3) + cl] = f2bf(sa[jb][r]);
            }
        }

        // PV
        short8v pa0 = ld_frag(PsW, lr, lg);
        short8v pa1 = ld_frag(PsW, lr, 4 + lg);
#pragma unroll
        for (int d = 0; d < 4; ++d) {
            oacc[d] = __builtin_amdgcn_mfma_f32_16x16x32_bf16(
                pa0, ld_frag(Vs[cur], d * 16 + lr, lg), oacc[d], 0, 0, 0);
            oacc[d] = __builtin_amdgcn_mfma_f32_16x16x32_bf16(
                pa1, ld_frag(Vs[cur], d * 16 + lr, 4 + lg), oacc[d], 0, 0, 0);
        }
        __syncthreads();   // drains prefetch + guards K/V buffer reuse
    }
#undef STAGE

    USHORT* go = O + (size_t)(b * SEQ + q0 + w * 16) * D_MODEL + h * DH;
#pragma unroll
    for (int r = 0; r < 4; ++r) {
        const float inv = 1.f / l_[r];
        const int qrow = lg * 4 + r;
#pragma unroll
        for (int d = 0; d < 4; ++d)
            go[(size_t)qrow * D_MODEL + d * 16 + lr] = f2bf(oacc[d][r] * inv);
    }
}

// ---------------------------------------------------------------------------
// out = res + LayerNorm(x)*g + b ; optional bf16 side-copy
// ---------------------------------------------------------------------------
__global__ __launch_bounds__(256) void ln_res_kernel(
    const float* __restrict__ x, const float* __restrict__ res,
    const float* __restrict__ g, const float* __restrict__ bta,
    float* __restrict__ out, USHORT* __restrict__ outb)
{
    __shared__ float red[256];
    __shared__ float s_mu, s_rstd;

    const int row = blockIdx.x;
    const int tid = threadIdx.x;
    const float4* x4 = reinterpret_cast<const float4*>(x + (size_t)row * D_MODEL);
    float4 v = x4[tid];

    float sum = v.x + v.y + v.z + v.w;
    red[tid] = sum;
    __syncthreads();
    for (int s = 128; s > 0; s >>= 1) {
        if (tid < s) red[tid] += red[tid + s];
        __syncthreads();
    }
    if (tid == 0) s_mu = red[0] * (1.f / D_MODEL);
    __syncthreads();
    const float mu = s_mu;

    float dx = v.x - mu, dy = v.y - mu, dz = v.z - mu, dw = v.w - mu;
    red[tid] = dx * dx + dy * dy + dz * dz + dw * dw;
    __syncthreads();
    for (int s = 128; s > 0; s >>= 1) {
        if (tid < s) red[tid] += red[tid + s];
        __syncthreads();
    }
    if (tid == 0) s_rstd = rsqrtf(red[0] * (1.f / D_MODEL) + EPS);
    __syncthreads();
    const float rstd = s_rstd;

    float4 rv = reinterpret_cast<const float4*>(res + (size_t)row * D_MODEL)[tid];
    float4 gv = reinterpret_cast<const float4*>(g)[tid];
    float4 bv = reinterpret_cast<const float4*>(bta)[tid];

    float4 o;
    o.x = rv.x + dx * rstd * gv.x + bv.x;
    o.y = rv.y + dy * rstd * gv.y + bv.y;
    o.z = rv.z + dz * rstd * gv.z + bv.z;
    o.w = rv.w + dw * rstd * gv.w + bv.w;
    reinterpret_cast<float4*>(out + (size_t)row * D_MODEL)[tid] = o;
    if (outb)
        reinterpret_cast<ushort4*>(outb + (size_t)row * D_MODEL)[tid] =
            make_ushort4(f2bf(o.x), f2bf(o.y), f2bf(o.z), f2bf(o.w));
}

// ---------------------------------------------------------------------------
extern "C" void kernel_launch(void* const* d_in, const int* in_sizes, int n_in,
                              void* d_out, int out_size, void* d_ws, size_t ws_size,
                              hipStream_t stream)
{
    const float* X    = (const float*)d_in[0];
    const float* Wq1  = (const float*)d_in[1];
    const float* Wk1  = (const float*)d_in[2];
    const float* Wv1  = (const float*)d_in[3];
    const float* Wo1  = (const float*)d_in[4];
    const float* Wq2  = (const float*)d_in[5];
    const float* Wk2  = (const float*)d_in[6];
    const float* Wv2  = (const float*)d_in[7];
    const float* Wo2  = (const float*)d_in[8];
    const float* ln_g = (const float*)d_in[9];
    const float* ln_b = (const float*)d_in[10];
    const float* W1   = (const float*)d_in[11];
    const float* b1   = (const float*)d_in[12];
    const float* W2   = (const float*)d_in[13];
    const float* b2   = (const float*)d_in[14];

    // ws layout (ushort units; total 96 MB):
    //  [0,4Mi)   WtA (4 weight-transpose slots)
    //  [4,8Mi)   Xb ; later W2t
    //  [8,24Mi)  qb,kb,(old vb),t0b ; FFN hidden hb overlays
    //  [24,28Mi) t2b
    //  [28,36Mi) t1 fp32 ; [36,44Mi) t2 fp32
    //  [44,48Mi) Vtb (V^T per-head [64][64][1024])
    const size_t MI = 1024 * 1024;
    USHORT* ws16 = (USHORT*)d_ws;
    USHORT* WtA = ws16;
    USHORT* Xb  = ws16 + 4 * MI;
    USHORT* qb  = ws16 + 8 * MI;
    USHORT* kb  = ws16 + 12 * MI;
    USHORT* t0b = ws16 + 20 * MI;
    USHORT* hb  = qb;
    USHORT* t2b = ws16 + 24 * MI;
    float* t1 = (float*)(ws16 + 28 * MI);
    float* t2 = t1 + 4 * MI;
    USHORT* Vtb = ws16 + 44 * MI;

    auto gemm = [&](const USHORT* A, const USHORT* Bt, float* Cf, USHORT* Cb,
                    USHORT* Vt, int M, int N, int K, const float* bias, int relu) {
        gemm_bf16_kernel<<<dim3(N / 128, M / 128), 256, 0, stream>>>(
            A, Bt, Cf, Cb, Vt, M, N, K, bias, relu);
    };
    auto tcvt4 = [&](const float* s0, const float* s1, const float* s2,
                     const float* s3) {
        TcvtB4 p{s0, s1, s2, s3, WtA, WtA + 1 * MI, WtA + 2 * MI, WtA + 3 * MI};
        tcvt4_kernel<<<dim3(16, 16, 4), 256, 0, stream>>>(p, D_MODEL, D_MODEL);
    };

    dim3 agrid(SEQ / 64, BATCH * N_HEADS);

    // ---- prologue: weights(MHA1) + X -> bf16 ----
    tcvt4(Wq1, Wk1, Wv1, Wo1);
    f2b_kernel<<<dim3(4096), 256, 0, stream>>>(X, Xb, TOK * D_MODEL / 4);

    // ---- MHA 1 (causal) ----
    gemm(Xb, WtA + 0 * MI, nullptr, qb, nullptr, TOK, D_MODEL, D_MODEL, nullptr, 0);
    gemm(Xb, WtA + 1 * MI, nullptr, kb, nullptr, TOK, D_MODEL, D_MODEL, nullptr, 0);
    gemm(Xb, WtA + 2 * MI, nullptr, nullptr, Vtb, TOK, D_MODEL, D_MODEL, nullptr, 0);
    attn_mfma_kernel<<<agrid, 256, 0, stream>>>(qb, kb, Vtb, t0b, 1);
    gemm(t0b, WtA + 3 * MI, t1, nullptr, nullptr, TOK, D_MODEL, D_MODEL, nullptr, 0);
    ln_res_kernel<<<dim3(TOK), 256, 0, stream>>>(t1, X, ln_g, ln_b, t2, t2b);

    // ---- MHA 2 (full) ----
    tcvt4(Wq2, Wk2, Wv2, Wo2);
    gemm(t2b, WtA + 0 * MI, nullptr, qb, nullptr, TOK, D_MODEL, D_MODEL, nullptr, 0);
    gemm(t2b, WtA + 1 * MI, nullptr, kb, nullptr, TOK, D_MODEL, D_MODEL, nullptr, 0);
    gemm(t2b, WtA + 2 * MI, nullptr, nullptr, Vtb, TOK, D_MODEL, D_MODEL, nullptr, 0);
    attn_mfma_kernel<<<agrid, 256, 0, stream>>>(qb, kb, Vtb, t0b, 0);
    gemm(t0b, WtA + 3 * MI, t1, nullptr, nullptr, TOK, D_MODEL, D_MODEL, nullptr, 0);
    ln_res_kernel<<<dim3(TOK), 256, 0, stream>>>(t1, t1, ln_g, ln_b, t2, t2b);

    // ---- FFN ----
    tcvt_kernel<<<dim3(D_FF / 64, D_MODEL / 64), 256, 0, stream>>>(
        W1, WtA, D_MODEL, D_FF);
    tcvt_kernel<<<dim3(D_MODEL / 64, D_FF / 64), 256, 0, stream>>>(
        W2, Xb, D_FF, D_MODEL);
    gemm(t2b, WtA, nullptr, hb, nullptr, TOK, D_FF, D_MODEL, b1, 1);
    gemm(hb, Xb, t1, nullptr, nullptr, TOK, D_MODEL, D_FF, b2, 0);
    ln_res_kernel<<<dim3(TOK), 256, 0, stream>>>(t1, t2, ln_g, ln_b,
                                                 (float*)d_out, nullptr);
}

// Round 6
// 434.738 us; speedup vs baseline: 24.1715x; 1.2456x over previous
//
#include <hip/hip_runtime.h>
#include <hip/hip_bf16.h>

#define D_MODEL 1024
#define N_HEADS 16
#define DH 64
#define D_FF   4096
#define SEQ    1024
#define BATCH  4
#define TOK    (BATCH*SEQ)
#define EPS    1e-5f
#define SCALE  0.125f   // 1/sqrt(64)

typedef unsigned short USHORT;
typedef __attribute__((ext_vector_type(8))) short short8v;
typedef __attribute__((ext_vector_type(4))) float f32x4;

__device__ __forceinline__ USHORT f2bf(float f) {
    unsigned int u; __builtin_memcpy(&u, &f, 4);
    u += 0x7fffu + ((u >> 16) & 1u);          // RNE
    return (USHORT)(u >> 16);
}
__device__ __forceinline__ float bf2f(USHORT s) {
    unsigned int u = ((unsigned int)s) << 16;
    float f; __builtin_memcpy(&f, &u, 4);
    return f;
}

// swizzled frag read: element (row,c) lives at row*64 + ((c>>3)^(row&7))*8 + (c&7)
__device__ __forceinline__ short8v ld_frag(const USHORT* lds, int row, int c8) {
    return *reinterpret_cast<const short8v*>(
        &lds[row * 64 + (((c8) ^ (row & 7)) << 3)]);
}

#define GLDS(gsrc, ldst) \
    __builtin_amdgcn_global_load_lds( \
        (const __attribute__((address_space(1))) void*)(gsrc), \
        (__attribute__((address_space(3))) void*)(ldst), 16, 0, 0)

// ---------------------------------------------------------------------------
// bf16 MFMA GEMM: C[M,N] = A[M,K] @ Bt[N,K]^T. 128x128 tile, BK=32, 4 waves,
// double-buffered LDS (T3-minimum: stage next tile before compute, one
// barrier/iter). Bijective XCD swizzle on the linearized grid (m204; all our
// grids have nwg%8==0) so each XCD's L2 keeps a contiguous A row-panel.
// Epilogues: normal (Cf fp32 / Cb bf16, stride N) or fused-QKV routing
// (cols [0,1024)->Cq, [1024,2048)->Ck, [2048,3072)->Vt transposed per-head).
// ---------------------------------------------------------------------------
__global__ __launch_bounds__(256) void gemm_bf16_kernel(
    const USHORT* __restrict__ A,    // [M][K] bf16
    const USHORT* __restrict__ Bt,   // [N][K] bf16
    float* __restrict__ Cf, USHORT* __restrict__ Cb, USHORT* __restrict__ Ck,
    USHORT* __restrict__ VtOut,
    int M, int N, int K, const float* __restrict__ bias, int relu, int qkv)
{
    __shared__ USHORT As[2][128 * 32];
    __shared__ USHORT Bs[2][128 * 32];

    const int tid = threadIdx.x;
    const int l   = tid & 63;
    const int w   = tid >> 6;
    const int wr  = w >> 1, wc = w & 1;

    // XCD-aware bijective swizzle (nwg % 8 == 0 for all launches)
    const int gx  = gridDim.x;
    const int nwg = gx * gridDim.y;
    const int lin = blockIdx.y * gx + blockIdx.x;
    const int swz = (lin & 7) * (nwg >> 3) + (lin >> 3);
    const int m0  = (swz / gx) * 128, n0 = (swz % gx) * 128;

    const int u0 = w * 64 + l;
    const int r0 = u0 >> 2, c0 = (u0 & 3) * 8;
    const int u1 = 256 + u0;
    const int r1 = u1 >> 2, c1 = (u1 & 3) * 8;

    const USHORT* a0 = A  + (size_t)(m0 + r0) * K + c0;
    const USHORT* a1 = A  + (size_t)(m0 + r1) * K + c1;
    const USHORT* b0 = Bt + (size_t)(n0 + r0) * K + c0;
    const USHORT* b1 = Bt + (size_t)(n0 + r1) * K + c1;
    const int la0 = (w * 64) * 8;          // LDS unit offsets within a buffer
    const int la1 = (256 + w * 64) * 8;

#define GSTAGE(buf, k0) do {                        \
    GLDS(a0 + (k0), &As[buf][la0]);                 \
    GLDS(a1 + (k0), &As[buf][la1]);                 \
    GLDS(b0 + (k0), &Bs[buf][la0]);                 \
    GLDS(b1 + (k0), &Bs[buf][la1]);                 \
} while (0)

    f32x4 acc[4][4];
#pragma unroll
    for (int i = 0; i < 4; ++i)
#pragma unroll
        for (int j = 0; j < 4; ++j) acc[i][j] = (f32x4){0.f, 0.f, 0.f, 0.f};

    const int lr = l & 15;
    const int lk = (l >> 4) * 8;
    const int nk = K >> 5;

    GSTAGE(0, 0);
    __syncthreads();                       // tile 0 staged (vmcnt drained)

    for (int t = 0; t < nk; ++t) {
        const int cur = t & 1;
        if (t + 1 < nk) GSTAGE(cur ^ 1, (t + 1) << 5);   // prefetch next tile

        short8v af[4], bfr[4];
#pragma unroll
        for (int mi = 0; mi < 4; ++mi)
            af[mi] = *reinterpret_cast<const short8v*>(
                &As[cur][(wr * 64 + mi * 16 + lr) * 32 + lk]);
#pragma unroll
        for (int ni = 0; ni < 4; ++ni)
            bfr[ni] = *reinterpret_cast<const short8v*>(
                &Bs[cur][(wc * 64 + ni * 16 + lr) * 32 + lk]);
#pragma unroll
        for (int mi = 0; mi < 4; ++mi)
#pragma unroll
            for (int ni = 0; ni < 4; ++ni)
                acc[mi][ni] = __builtin_amdgcn_mfma_f32_16x16x32_bf16(
                    af[mi], bfr[ni], acc[mi][ni], 0, 0, 0);
        __syncthreads();   // drains prefetch (vmcnt0) + guards buffer reuse
    }
#undef GSTAGE

    // epilogue: C/D layout col = lane&15, row = (lane>>4)*4 + reg  [m89/m91]
    if (qkv) {
        // cols [0,1024)->Cq(=Cb), [1024,2048)->Ck, [2048,3072)->Vt transposed
#pragma unroll
        for (int mi = 0; mi < 4; ++mi) {
            const int row = m0 + wr * 64 + mi * 16 + (l >> 4) * 4;
#pragma unroll
            for (int ni = 0; ni < 4; ++ni) {
                const int col = n0 + wc * 64 + ni * 16 + lr;
                if (col < 2048) {
                    USHORT* dst = (col < 1024) ? Cb : Ck;
                    const int c = col & 1023;
#pragma unroll
                    for (int j = 0; j < 4; ++j)
                        dst[(size_t)(row + j) * D_MODEL + c] =
                            f2bf(acc[mi][ni][j]);
                } else {
                    const int c = col - 2048;
                    const int bb = row >> 10, jr = row & 1023;
                    const int hh = c >> 6, dd = c & 63;
                    ushort4 pk = make_ushort4(
                        f2bf(acc[mi][ni][0]), f2bf(acc[mi][ni][1]),
                        f2bf(acc[mi][ni][2]), f2bf(acc[mi][ni][3]));
                    *reinterpret_cast<ushort4*>(
                        &VtOut[((size_t)(bb * 16 + hh) * 64 + dd) * 1024 + jr]) = pk;
                }
            }
        }
    } else {
#pragma unroll
        for (int mi = 0; mi < 4; ++mi) {
            const int row = m0 + wr * 64 + mi * 16 + (l >> 4) * 4;
#pragma unroll
            for (int ni = 0; ni < 4; ++ni) {
                const int col = n0 + wc * 64 + ni * 16 + lr;
                const float bv = bias ? bias[col] : 0.f;
#pragma unroll
                for (int j = 0; j < 4; ++j) {
                    float v = acc[mi][ni][j] + bv;
                    if (relu) v = fmaxf(v, 0.f);
                    const size_t idx = (size_t)(row + j) * N + col;
                    if (Cf) Cf[idx] = v;
                    if (Cb) Cb[idx] = f2bf(v);
                }
            }
        }
    }
}

// ---------------------------------------------------------------------------
// Weight convert+transpose: W fp32 [K][N] -> Wt bf16 [N][K]. 64x64 LDS tiles.
// ---------------------------------------------------------------------------
struct TcvtB4 {
    const float* s0; const float* s1; const float* s2; const float* s3;
    USHORT* d0; USHORT* d1; USHORT* d2; USHORT* d3;
};

__device__ __forceinline__ void tcvt_body(
    const float* __restrict__ W, USHORT* __restrict__ Wt, int K, int N)
{
    __shared__ USHORT L[64][65];
    const int tid = threadIdx.x;
    const int tx = tid & 15, ty = tid >> 4;
    const int n0 = blockIdx.x * 64, k0 = blockIdx.y * 64;
#pragma unroll
    for (int r = 0; r < 4; ++r) {
        int kr = ty + 16 * r;
        float4 v = *reinterpret_cast<const float4*>(
            &W[(size_t)(k0 + kr) * N + n0 + tx * 4]);
        L[tx * 4 + 0][kr] = f2bf(v.x);
        L[tx * 4 + 1][kr] = f2bf(v.y);
        L[tx * 4 + 2][kr] = f2bf(v.z);
        L[tx * 4 + 3][kr] = f2bf(v.w);
    }
    __syncthreads();
#pragma unroll
    for (int r = 0; r < 4; ++r) {
        int nr = ty + 16 * r;
        ushort4 o = make_ushort4(L[nr][tx * 4 + 0], L[nr][tx * 4 + 1],
                                 L[nr][tx * 4 + 2], L[nr][tx * 4 + 3]);
        *reinterpret_cast<ushort4*>(&Wt[(size_t)(n0 + nr) * K + k0 + tx * 4]) = o;
    }
}

__global__ __launch_bounds__(256) void tcvt_kernel(
    const float* __restrict__ W, USHORT* __restrict__ Wt, int K, int N)
{
    tcvt_body(W, Wt, K, N);
}

__global__ __launch_bounds__(256) void tcvt4_kernel(TcvtB4 p, int K, int N)
{
    const int z = blockIdx.z;
    const float* W = (z == 0) ? p.s0 : (z == 1) ? p.s1 : (z == 2) ? p.s2 : p.s3;
    USHORT*    Wt = (z == 0) ? p.d0 : (z == 1) ? p.d1 : (z == 2) ? p.d2 : p.d3;
    tcvt_body(W, Wt, K, N);
}

// fp32 -> bf16 elementwise (n4 = count/4)
__global__ __launch_bounds__(256) void f2b_kernel(
    const float* __restrict__ in, USHORT* __restrict__ out, int n4)
{
    int i = blockIdx.x * 256 + threadIdx.x;
    if (i < n4) {
        float4 v = reinterpret_cast<const float4*>(in)[i];
        reinterpret_cast<ushort4*>(out)[i] =
            make_ushort4(f2bf(v.x), f2bf(v.y), f2bf(v.z), f2bf(v.w));
    }
}

// ---------------------------------------------------------------------------
// MFMA flash attention, double-buffered K/V staging. Block = (b,h, 64 q-rows),
// 4 waves. XCD swizzle clusters same-(b,h) q-tiles on one XCD (K/V L2-local).
// ---------------------------------------------------------------------------
__global__ __launch_bounds__(256) void attn_mfma_kernel(
    const USHORT* __restrict__ Q, const USHORT* __restrict__ K,
    const USHORT* __restrict__ Vt, USHORT* __restrict__ O, int causal)
{
    __shared__ USHORT Qs[64 * 64];
    __shared__ USHORT Ks[2][64 * 64];
    __shared__ USHORT Vs[2][64 * 64];
    __shared__ USHORT Ps[4][16 * 64];

    const int tid = threadIdx.x;
    const int l  = tid & 63;
    const int w  = tid >> 6;
    const int lr = l & 15;
    const int lg = l >> 4;

    // swizzle: 8 consecutive bh-groups per XCD (K/V panels ~2MB < 4MB L2)
    const int lin = blockIdx.y * 16 + blockIdx.x;   // nwg = 1024
    const int swz = (lin & 7) * 128 + (lin >> 3);
    const int qt = swz & 15;
    const int bh = swz >> 4;
    const int h = bh & 15, b = bh >> 4;
    const int q0 = qt * 64;

    const USHORT* gq  = Q  + (size_t)(b * SEQ + q0) * D_MODEL + h * DH;
    const USHORT* gk0 = K  + (size_t)b * SEQ * D_MODEL + h * DH;
    const USHORT* gv0 = Vt + (size_t)bh * DH * SEQ;

    // staging source offsets (inverse-swizzled): unit u -> row u>>3, block (u&7)^(row&7)
    const int r0s = tid >> 3,         c0s = (tid & 7) ^ (r0s & 7);
    const int r1s = (256 + tid) >> 3, c1s = (tid & 7) ^ (r1s & 7);
    const size_t so0 = (size_t)r0s * 1024 + c0s * 8;   // Q/K/Vt row stride 1024
    const size_t so1 = (size_t)r1s * 1024 + c1s * 8;
    const int db0 = (tid & 192) << 3;          // wave-uniform LDS unit base
    const int db1 = (256 << 3) + db0;

#define STAGE(ldsb, gsrc) do {                 \
    GLDS((gsrc) + so0, (ldsb) + db0);          \
    GLDS((gsrc) + so1, (ldsb) + db1);          \
} while (0)

    STAGE(Qs, gq);
    STAGE(Ks[0], gk0);
    STAGE(Vs[0], gv0);

    f32x4 oacc[4];
    float m_[4], l_[4];
#pragma unroll
    for (int r = 0; r < 4; ++r) {
        m_[r] = -1e30f; l_[r] = 0.f;
    }
#pragma unroll
    for (int d = 0; d < 4; ++d) oacc[d] = (f32x4){0.f, 0.f, 0.f, 0.f};

    __syncthreads();                           // Q + tile 0 staged
    short8v qa0 = ld_frag(Qs, w * 16 + lr, lg);
    short8v qa1 = ld_frag(Qs, w * 16 + lr, 4 + lg);

    const int ntile = causal ? (qt + 1) : (SEQ / 64);
    for (int kt = 0; kt < ntile; ++kt) {
        const int cur = kt & 1;
        if (kt + 1 < ntile) {                  // prefetch next K/V tile
            STAGE(Ks[cur ^ 1], gk0 + (size_t)(kt + 1) * 64 * D_MODEL);
            STAGE(Vs[cur ^ 1], gv0 + (kt + 1) * 64);
        }
        const int j0 = kt * 64;

        f32x4 sa[4];
#pragma unroll
        for (int jb = 0; jb < 4; ++jb) {
            sa[jb] = (f32x4){0.f, 0.f, 0.f, 0.f};
            sa[jb] = __builtin_amdgcn_mfma_f32_16x16x32_bf16(
                qa0, ld_frag(Ks[cur], jb * 16 + lr, lg), sa[jb], 0, 0, 0);
            sa[jb] = __builtin_amdgcn_mfma_f32_16x16x32_bf16(
                qa1, ld_frag(Ks[cur], jb * 16 + lr, 4 + lg), sa[jb], 0, 0, 0);
        }

        // scale + causal mask (diagonal tile only)
#pragma unroll
        for (int jb = 0; jb < 4; ++jb)
#pragma unroll
            for (int r = 0; r < 4; ++r) {
                float s = sa[jb][r] * SCALE;
                if (causal && kt == qt &&
                    (j0 + jb * 16 + lr) > (q0 + w * 16 + lg * 4 + r))
                    s = -1e30f;
                sa[jb][r] = s;
            }

        // online softmax per q-row (state replicated across the 16-lane group)
#pragma unroll
        for (int r = 0; r < 4; ++r) {
            float tm = fmaxf(fmaxf(sa[0][r], sa[1][r]), fmaxf(sa[2][r], sa[3][r]));
            tm = fmaxf(tm, __shfl_xor(tm, 1));
            tm = fmaxf(tm, __shfl_xor(tm, 2));
            tm = fmaxf(tm, __shfl_xor(tm, 4));
            tm = fmaxf(tm, __shfl_xor(tm, 8));
            float mn = fmaxf(m_[r], tm);
            float sc = __expf(m_[r] - mn);
            m_[r] = mn;
            float rs_ = 0.f;
#pragma unroll
            for (int jb = 0; jb < 4; ++jb) {
                float p = __expf(sa[jb][r] - mn);
                sa[jb][r] = p;
                rs_ += p;
            }
            rs_ += __shfl_xor(rs_, 1);
            rs_ += __shfl_xor(rs_, 2);
            rs_ += __shfl_xor(rs_, 4);
            rs_ += __shfl_xor(rs_, 8);
            l_[r] = l_[r] * sc + rs_;
#pragma unroll
            for (int d = 0; d < 4; ++d) oacc[d][r] *= sc;
        }

        // P -> per-wave swizzled LDS (bf16)
        USHORT* PsW = Ps[w];
#pragma unroll
        for (int jb = 0; jb < 4; ++jb) {
            const int c8 = jb * 2 + (lr >> 3), cl = lr & 7;
#pragma unroll
            for (int r = 0; r < 4; ++r) {
                const int row = lg * 4 + r;
                PsW[row * 64 + ((c8 ^ (row & 7)) << 3) + cl] = f2bf(sa[jb][r]);
            }
        }

        // PV
        short8v pa0 = ld_frag(PsW, lr, lg);
        short8v pa1 = ld_frag(PsW, lr, 4 + lg);
#pragma unroll
        for (int d = 0; d < 4; ++d) {
            oacc[d] = __builtin_amdgcn_mfma_f32_16x16x32_bf16(
                pa0, ld_frag(Vs[cur], d * 16 + lr, lg), oacc[d], 0, 0, 0);
            oacc[d] = __builtin_amdgcn_mfma_f32_16x16x32_bf16(
                pa1, ld_frag(Vs[cur], d * 16 + lr, 4 + lg), oacc[d], 0, 0, 0);
        }
        __syncthreads();   // drains prefetch + guards K/V buffer reuse
    }
#undef STAGE

    USHORT* go = O + (size_t)(b * SEQ + q0 + w * 16) * D_MODEL + h * DH;
#pragma unroll
    for (int r = 0; r < 4; ++r) {
        const float inv = 1.f / l_[r];
        const int qrow = lg * 4 + r;
#pragma unroll
        for (int d = 0; d < 4; ++d)
            go[(size_t)qrow * D_MODEL + d * 16 + lr] = f2bf(oacc[d][r] * inv);
    }
}

// ---------------------------------------------------------------------------
// out = res + LayerNorm(x)*g + b.  x is bf16; res is fp32 (resf) or bf16
// (resb); outf fp32 always, outb bf16 optional.
// ---------------------------------------------------------------------------
__global__ __launch_bounds__(256) void ln_res_kernel(
    const USHORT* __restrict__ xb, const float* __restrict__ resf,
    const USHORT* __restrict__ resb,
    const float* __restrict__ g, const float* __restrict__ bta,
    float* __restrict__ outf, USHORT* __restrict__ outb)
{
    __shared__ float red[256];
    __shared__ float s_mu, s_rstd;

    const int row = blockIdx.x;
    const int tid = threadIdx.x;
    ushort4 xv = reinterpret_cast<const ushort4*>(xb + (size_t)row * D_MODEL)[tid];
    float vx = bf2f(xv.x), vy = bf2f(xv.y), vz = bf2f(xv.z), vw = bf2f(xv.w);

    red[tid] = vx + vy + vz + vw;
    __syncthreads();
    for (int s = 128; s > 0; s >>= 1) {
        if (tid < s) red[tid] += red[tid + s];
        __syncthreads();
    }
    if (tid == 0) s_mu = red[0] * (1.f / D_MODEL);
    __syncthreads();
    const float mu = s_mu;

    float dx = vx - mu, dy = vy - mu, dz = vz - mu, dw = vw - mu;
    red[tid] = dx * dx + dy * dy + dz * dz + dw * dw;
    __syncthreads();
    for (int s = 128; s > 0; s >>= 1) {
        if (tid < s) red[tid] += red[tid + s];
        __syncthreads();
    }
    if (tid == 0) s_rstd = rsqrtf(red[0] * (1.f / D_MODEL) + EPS);
    __syncthreads();
    const float rstd = s_rstd;

    float4 rv;
    if (resf) {
        rv = reinterpret_cast<const float4*>(resf + (size_t)row * D_MODEL)[tid];
    } else {
        ushort4 rb = reinterpret_cast<const ushort4*>(
            resb + (size_t)row * D_MODEL)[tid];
        rv = make_float4(bf2f(rb.x), bf2f(rb.y), bf2f(rb.z), bf2f(rb.w));
    }
    float4 gv = reinterpret_cast<const float4*>(g)[tid];
    float4 bv = reinterpret_cast<const float4*>(bta)[tid];

    float4 o;
    o.x = rv.x + dx * rstd * gv.x + bv.x;
    o.y = rv.y + dy * rstd * gv.y + bv.y;
    o.z = rv.z + dz * rstd * gv.z + bv.z;
    o.w = rv.w + dw * rstd * gv.w + bv.w;
    reinterpret_cast<float4*>(outf + (size_t)row * D_MODEL)[tid] = o;
    if (outb)
        reinterpret_cast<ushort4*>(outb + (size_t)row * D_MODEL)[tid] =
            make_ushort4(f2bf(o.x), f2bf(o.y), f2bf(o.z), f2bf(o.w));
}

// ---------------------------------------------------------------------------
extern "C" void kernel_launch(void* const* d_in, const int* in_sizes, int n_in,
                              void* d_out, int out_size, void* d_ws, size_t ws_size,
                              hipStream_t stream)
{
    const float* X    = (const float*)d_in[0];
    const float* Wq1  = (const float*)d_in[1];
    const float* Wk1  = (const float*)d_in[2];
    const float* Wv1  = (const float*)d_in[3];
    const float* Wo1  = (const float*)d_in[4];
    const float* Wq2  = (const float*)d_in[5];
    const float* Wk2  = (const float*)d_in[6];
    const float* Wv2  = (const float*)d_in[7];
    const float* Wo2  = (const float*)d_in[8];
    const float* ln_g = (const float*)d_in[9];
    const float* ln_b = (const float*)d_in[10];
    const float* W1   = (const float*)d_in[11];
    const float* b1   = (const float*)d_in[12];
    const float* W2   = (const float*)d_in[13];
    const float* b2   = (const float*)d_in[14];

    // ws layout (ushort units; total 48 Mi = 96 MB):
    //  [0,3Mi)   Wqkv1t ([3072][1024]); [3,4) Wo1t
    //  [4,7Mi)   Wqkv2t;                [7,8) Wo2t
    //  [8,12Mi)  W2t
    //  [12,16Mi) Xb ; after MHA1 projections -> W1t
    //  [16,32Mi) qb,kb,Vtb,t0b (4x4Mi); FFN hidden hb overlays all 16Mi
    //  [32,36Mi) t2b ; [36,40Mi) t1b
    //  [40,48Mi) t2 fp32 (4Mi floats)
    const size_t MI = 1024 * 1024;
    USHORT* ws16 = (USHORT*)d_ws;
    USHORT* Wqkv1t = ws16;
    USHORT* Wo1t   = ws16 + 3 * MI;
    USHORT* Wqkv2t = ws16 + 4 * MI;
    USHORT* Wo2t   = ws16 + 7 * MI;
    USHORT* W2t    = ws16 + 8 * MI;
    USHORT* Xb     = ws16 + 12 * MI;   // later W1t
    USHORT* W1t    = Xb;
    USHORT* qb     = ws16 + 16 * MI;
    USHORT* kb     = ws16 + 20 * MI;
    USHORT* Vtb    = ws16 + 24 * MI;
    USHORT* t0b    = ws16 + 28 * MI;
    USHORT* hb     = qb;               // [TOK][D_FF] bf16 = 16 Mi
    USHORT* t2b    = ws16 + 32 * MI;
    USHORT* t1b    = ws16 + 36 * MI;
    float*  t2     = (float*)(ws16 + 40 * MI);

    auto gemm = [&](const USHORT* A, const USHORT* Bt, float* Cf, USHORT* Cb,
                    int M, int N, int K, const float* bias, int relu) {
        gemm_bf16_kernel<<<dim3(N / 128, M / 128), 256, 0, stream>>>(
            A, Bt, Cf, Cb, nullptr, nullptr, M, N, K, bias, relu, 0);
    };
    auto gemm_qkv = [&](const USHORT* A, const USHORT* Bt) {
        gemm_bf16_kernel<<<dim3(3072 / 128, TOK / 128), 256, 0, stream>>>(
            A, Bt, nullptr, qb, kb, Vtb, TOK, 3072, D_MODEL, nullptr, 0, 1);
    };

    dim3 agrid(SEQ / 64, BATCH * N_HEADS);

    // ---- prologue: all square weights + W2 + X -> bf16 ----
    {
        TcvtB4 p1{Wq1, Wk1, Wv1, Wo1,
                  Wqkv1t, Wqkv1t + 1 * MI, Wqkv1t + 2 * MI, Wo1t};
        tcvt4_kernel<<<dim3(16, 16, 4), 256, 0, stream>>>(p1, D_MODEL, D_MODEL);
        TcvtB4 p2{Wq2, Wk2, Wv2, Wo2,
                  Wqkv2t, Wqkv2t + 1 * MI, Wqkv2t + 2 * MI, Wo2t};
        tcvt4_kernel<<<dim3(16, 16, 4), 256, 0, stream>>>(p2, D_MODEL, D_MODEL);
    }
    tcvt_kernel<<<dim3(D_MODEL / 64, D_FF / 64), 256, 0, stream>>>(
        W2, W2t, D_FF, D_MODEL);
    f2b_kernel<<<dim3(4096), 256, 0, stream>>>(X, Xb, TOK * D_MODEL / 4);

    // ---- MHA 1 (causal) ----
    gemm_qkv(Xb, Wqkv1t);
    attn_mfma_kernel<<<agrid, 256, 0, stream>>>(qb, kb, Vtb, t0b, 1);
    gemm(t0b, Wo1t, nullptr, t1b, TOK, D_MODEL, D_MODEL, nullptr, 0);
    ln_res_kernel<<<dim3(TOK), 256, 0, stream>>>(t1b, X, nullptr,
                                                 ln_g, ln_b, t2, t2b);
    // W1t conversion (Xb slot now dead)
    tcvt_kernel<<<dim3(D_FF / 64, D_MODEL / 64), 256, 0, stream>>>(
        W1, W1t, D_MODEL, D_FF);

    // ---- MHA 2 (full) ----
    gemm_qkv(t2b, Wqkv2t);
    attn_mfma_kernel<<<agrid, 256, 0, stream>>>(qb, kb, Vtb, t0b, 0);
    gemm(t0b, Wo2t, nullptr, t1b, TOK, D_MODEL, D_MODEL, nullptr, 0);
    ln_res_kernel<<<dim3(TOK), 256, 0, stream>>>(t1b, nullptr, t1b,
                                                 ln_g, ln_b, t2, t2b);

    // ---- FFN ----
    gemm(t2b, W1t, nullptr, hb, TOK, D_FF, D_MODEL, b1, 1);
    gemm(hb, W2t, nullptr, t1b, TOK, D_MODEL, D_FF, b2, 0);
    ln_res_kernel<<<dim3(TOK), 256, 0, stream>>>(t1b, t2, nullptr,
                                                 ln_g, ln_b, (float*)d_out, nullptr);
}

// Round 7
// 414.595 us; speedup vs baseline: 25.3458x; 1.0486x over previous
//
#include <hip/hip_runtime.h>
#include <hip/hip_bf16.h>

#define D_MODEL 1024
#define N_HEADS 16
#define DH 64
#define D_FF   4096
#define SEQ    1024
#define BATCH  4
#define TOK    (BATCH*SEQ)
#define EPS    1e-5f
#define SCALE  0.125f   // 1/sqrt(64)

typedef unsigned short USHORT;
typedef __attribute__((ext_vector_type(8))) short short8v;
typedef __attribute__((ext_vector_type(4))) float f32x4;

__device__ __forceinline__ USHORT f2bf(float f) {
    unsigned int u; __builtin_memcpy(&u, &f, 4);
    u += 0x7fffu + ((u >> 16) & 1u);          // RNE
    return (USHORT)(u >> 16);
}
__device__ __forceinline__ float bf2f(USHORT s) {
    unsigned int u = ((unsigned int)s) << 16;
    float f; __builtin_memcpy(&f, &u, 4);
    return f;
}

// row-stride-64 swizzled read (BK=64 tiles + attention): unit ^= row&7
__device__ __forceinline__ short8v ld_frag(const USHORT* lds, int row, int c8) {
    return *reinterpret_cast<const short8v*>(
        &lds[row * 64 + (((c8) ^ (row & 7)) << 3)]);
}
// row-stride-32 swizzled read (BK=32 tiles): unit ^= (row>>1)&3  (2-way = free)
__device__ __forceinline__ short8v ld32(const USHORT* lds, int row, int c8) {
    return *reinterpret_cast<const short8v*>(
        &lds[row * 32 + (((c8) ^ ((row >> 1) & 3)) << 3)]);
}

#define GLDS(gsrc, ldst) \
    __builtin_amdgcn_global_load_lds( \
        (const __attribute__((address_space(1))) void*)(gsrc), \
        (__attribute__((address_space(3))) void*)(ldst), 16, 0, 0)

#define WAITVM(n) asm volatile("s_waitcnt vmcnt(" #n ")" ::: "memory")

// ---------------------------------------------------------------------------
// bf16 MFMA GEMM, BK=32, 3-buffer counted-vmcnt pipeline (T4).
// C[M,N] = A[M,K] @ Bt[N,K]^T. 128x128 tile, 4 waves. XOR-swizzled LDS
// (source-side inverse per m173; reads via ld32). Raw s_barrier; vmcnt(4)
// mid-loop (1 tile in flight), vmcnt(0) only on the last iteration.
// Epilogues: normal (Cf fp32 / Cb bf16) or fused-QKV routing.
// ---------------------------------------------------------------------------
__global__ __launch_bounds__(256) void gemm_k32_kernel(
    const USHORT* __restrict__ A, const USHORT* __restrict__ Bt,
    float* __restrict__ Cf, USHORT* __restrict__ Cb, USHORT* __restrict__ Ck,
    USHORT* __restrict__ VtOut,
    int M, int N, int K, const float* __restrict__ bias, int relu, int qkv)
{
    __shared__ USHORT As[3][128 * 32];
    __shared__ USHORT Bs[3][128 * 32];

    const int tid = threadIdx.x;
    const int l   = tid & 63;
    const int w   = tid >> 6;
    const int wr  = w >> 1, wc = w & 1;
    const int lr  = l & 15, lg = l >> 4;

    // XCD-aware bijective swizzle (all grids have nwg % 8 == 0)
    const int gx  = gridDim.x;
    const int nwg = gx * gridDim.y;
    const int lin = blockIdx.y * gx + blockIdx.x;
    const int swz = (lin & 7) * (nwg >> 3) + (lin >> 3);
    const int m0  = (swz / gx) * 128, n0 = (swz % gx) * 128;

    // staging: 512 16B-units per matrix; thread covers q = p*256 + tid, p=0,1.
    // LDS unit q holds global col-unit (q&3) ^ ((row>>1)&3)  [inverse swizzle]
    const int q0 = tid,        r0 = q0 >> 2, c0 = ((q0 & 3) ^ ((r0 >> 1) & 3)) * 8;
    const int q1 = 256 + tid,  r1 = q1 >> 2, c1 = ((q1 & 3) ^ ((r1 >> 1) & 3)) * 8;

    const USHORT* a0 = A  + (size_t)(m0 + r0) * K + c0;
    const USHORT* a1 = A  + (size_t)(m0 + r1) * K + c1;
    const USHORT* b0 = Bt + (size_t)(n0 + r0) * K + c0;
    const USHORT* b1 = Bt + (size_t)(n0 + r1) * K + c1;
    const int la0 = (w * 64) * 8;            // wave-uniform LDS dest bases
    const int la1 = (256 + w * 64) * 8;

    auto stage = [&](int buf, int k0) {
        GLDS(a0 + k0, &As[buf][la0]);
        GLDS(a1 + k0, &As[buf][la1]);
        GLDS(b0 + k0, &Bs[buf][la0]);
        GLDS(b1 + k0, &Bs[buf][la1]);
    };

    f32x4 acc[4][4];
#pragma unroll
    for (int i = 0; i < 4; ++i)
#pragma unroll
        for (int j = 0; j < 4; ++j) acc[i][j] = (f32x4){0.f, 0.f, 0.f, 0.f};

    const int nk = K >> 5;
    stage(0, 0);
    if (nk > 1) stage(1, 32);

    for (int t = 0; t < nk; ++t) {
        const int cur = t % 3;
        if (t + 1 < nk) { WAITVM(4); } else { WAITVM(0); }   // tile t landed
        __builtin_amdgcn_s_barrier();           // + all waves done with t-1
        if (t + 2 < nk) stage((t + 2) % 3, (t + 2) << 5);

        short8v af[4], bfr[4];
#pragma unroll
        for (int mi = 0; mi < 4; ++mi)
            af[mi] = ld32(As[cur], wr * 64 + mi * 16 + lr, lg);
#pragma unroll
        for (int ni = 0; ni < 4; ++ni)
            bfr[ni] = ld32(Bs[cur], wc * 64 + ni * 16 + lr, lg);
#pragma unroll
        for (int mi = 0; mi < 4; ++mi)
#pragma unroll
            for (int ni = 0; ni < 4; ++ni)
                acc[mi][ni] = __builtin_amdgcn_mfma_f32_16x16x32_bf16(
                    af[mi], bfr[ni], acc[mi][ni], 0, 0, 0);
    }

    // epilogue: C/D layout col = lane&15, row = (lane>>4)*4 + reg  [m89/m91]
    if (qkv) {
#pragma unroll
        for (int mi = 0; mi < 4; ++mi) {
            const int row = m0 + wr * 64 + mi * 16 + (l >> 4) * 4;
#pragma unroll
            for (int ni = 0; ni < 4; ++ni) {
                const int col = n0 + wc * 64 + ni * 16 + lr;
                if (col < 2048) {
                    USHORT* dst = (col < 1024) ? Cb : Ck;
                    const int c = col & 1023;
#pragma unroll
                    for (int j = 0; j < 4; ++j)
                        dst[(size_t)(row + j) * D_MODEL + c] =
                            f2bf(acc[mi][ni][j]);
                } else {
                    const int c = col - 2048;
                    const int bb = row >> 10, jr = row & 1023;
                    const int hh = c >> 6, dd = c & 63;
                    ushort4 pk = make_ushort4(
                        f2bf(acc[mi][ni][0]), f2bf(acc[mi][ni][1]),
                        f2bf(acc[mi][ni][2]), f2bf(acc[mi][ni][3]));
                    *reinterpret_cast<ushort4*>(
                        &VtOut[((size_t)(bb * 16 + hh) * 64 + dd) * 1024 + jr]) = pk;
                }
            }
        }
    } else {
#pragma unroll
        for (int mi = 0; mi < 4; ++mi) {
            const int row = m0 + wr * 64 + mi * 16 + (l >> 4) * 4;
#pragma unroll
            for (int ni = 0; ni < 4; ++ni) {
                const int col = n0 + wc * 64 + ni * 16 + lr;
                const float bv = bias ? bias[col] : 0.f;
#pragma unroll
                for (int j = 0; j < 4; ++j) {
                    float v = acc[mi][ni][j] + bv;
                    if (relu) v = fmaxf(v, 0.f);
                    const size_t idx = (size_t)(row + j) * N + col;
                    if (Cf) Cf[idx] = v;
                    if (Cb) Cb[idx] = f2bf(v);
                }
            }
        }
    }
}

// ---------------------------------------------------------------------------
// bf16 MFMA GEMM, BK=64, 4-buffer counted-vmcnt pipeline (depth 3 covers
// ~900cyc HBM latency). For the grid-starved N=1024 shapes (1 block/CU).
// ---------------------------------------------------------------------------
__global__ __launch_bounds__(256) void gemm_k64_kernel(
    const USHORT* __restrict__ A, const USHORT* __restrict__ Bt,
    float* __restrict__ Cf, USHORT* __restrict__ Cb,
    int M, int N, int K, const float* __restrict__ bias, int relu)
{
    __shared__ USHORT As[4][128 * 64];
    __shared__ USHORT Bs[4][128 * 64];

    const int tid = threadIdx.x;
    const int l   = tid & 63;
    const int w   = tid >> 6;
    const int wr  = w >> 1, wc = w & 1;
    const int lr  = l & 15, lg = l >> 4;

    const int gx  = gridDim.x;
    const int nwg = gx * gridDim.y;
    const int lin = blockIdx.y * gx + blockIdx.x;
    const int swz = (lin & 7) * (nwg >> 3) + (lin >> 3);
    const int m0  = (swz / gx) * 128, n0 = (swz % gx) * 128;

    // staging: 1024 units/matrix; thread covers q = p*256 + tid, p=0..3.
    // LDS unit q holds global col-unit (q&7) ^ (row&7)
    const USHORT* aS[4]; const USHORT* bS[4]; int dOf[4];
#pragma unroll
    for (int p = 0; p < 4; ++p) {
        const int q = p * 256 + tid;
        const int row = q >> 3, cu = q & 7;
        const int cs = ((cu ^ (row & 7)) << 3);
        aS[p] = A  + (size_t)(m0 + row) * K + cs;
        bS[p] = Bt + (size_t)(n0 + row) * K + cs;
        dOf[p] = (p * 256 + w * 64) * 8;
    }

    auto stage = [&](int buf, int k0) {
#pragma unroll
        for (int p = 0; p < 4; ++p) {
            GLDS(aS[p] + k0, &As[buf][dOf[p]]);
            GLDS(bS[p] + k0, &Bs[buf][dOf[p]]);
        }
    };

    f32x4 acc[4][4];
#pragma unroll
    for (int i = 0; i < 4; ++i)
#pragma unroll
        for (int j = 0; j < 4; ++j) acc[i][j] = (f32x4){0.f, 0.f, 0.f, 0.f};

    const int nk = K >> 6;
    stage(0, 0);
    if (nk > 1) stage(1, 64);
    if (nk > 2) stage(2, 128);

    for (int t = 0; t < nk; ++t) {
        const int cur = t & 3;
        if (t + 2 < nk)      { WAITVM(16); }    // allow tiles t+1,t+2 in flight
        else if (t + 1 < nk) { WAITVM(8); }
        else                 { WAITVM(0); }
        __builtin_amdgcn_s_barrier();
        if (t + 3 < nk) stage((t + 3) & 3, (t + 3) << 6);

#pragma unroll
        for (int ks = 0; ks < 2; ++ks) {
            short8v af[4], bfr[4];
#pragma unroll
            for (int mi = 0; mi < 4; ++mi)
                af[mi] = ld_frag(As[cur], wr * 64 + mi * 16 + lr, ks * 4 + lg);
#pragma unroll
            for (int ni = 0; ni < 4; ++ni)
                bfr[ni] = ld_frag(Bs[cur], wc * 64 + ni * 16 + lr, ks * 4 + lg);
#pragma unroll
            for (int mi = 0; mi < 4; ++mi)
#pragma unroll
                for (int ni = 0; ni < 4; ++ni)
                    acc[mi][ni] = __builtin_amdgcn_mfma_f32_16x16x32_bf16(
                        af[mi], bfr[ni], acc[mi][ni], 0, 0, 0);
        }
    }

#pragma unroll
    for (int mi = 0; mi < 4; ++mi) {
        const int row = m0 + wr * 64 + mi * 16 + (l >> 4) * 4;
#pragma unroll
        for (int ni = 0; ni < 4; ++ni) {
            const int col = n0 + wc * 64 + ni * 16 + lr;
            const float bv = bias ? bias[col] : 0.f;
#pragma unroll
            for (int j = 0; j < 4; ++j) {
                float v = acc[mi][ni][j] + bv;
                if (relu) v = fmaxf(v, 0.f);
                const size_t idx = (size_t)(row + j) * N + col;
                if (Cf) Cf[idx] = v;
                if (Cb) Cb[idx] = f2bf(v);
            }
        }
    }
}

// ---------------------------------------------------------------------------
// Weight convert+transpose: W fp32 [K][N] -> Wt bf16 [N][K]. 64x64 LDS tiles.
// ---------------------------------------------------------------------------
struct TcvtB4 {
    const float* s0; const float* s1; const float* s2; const float* s3;
    USHORT* d0; USHORT* d1; USHORT* d2; USHORT* d3;
};

__device__ __forceinline__ void tcvt_body(
    const float* __restrict__ W, USHORT* __restrict__ Wt, int K, int N)
{
    __shared__ USHORT L[64][65];
    const int tid = threadIdx.x;
    const int tx = tid & 15, ty = tid >> 4;
    const int n0 = blockIdx.x * 64, k0 = blockIdx.y * 64;
#pragma unroll
    for (int r = 0; r < 4; ++r) {
        int kr = ty + 16 * r;
        float4 v = *reinterpret_cast<const float4*>(
            &W[(size_t)(k0 + kr) * N + n0 + tx * 4]);
        L[tx * 4 + 0][kr] = f2bf(v.x);
        L[tx * 4 + 1][kr] = f2bf(v.y);
        L[tx * 4 + 2][kr] = f2bf(v.z);
        L[tx * 4 + 3][kr] = f2bf(v.w);
    }
    __syncthreads();
#pragma unroll
    for (int r = 0; r < 4; ++r) {
        int nr = ty + 16 * r;
        ushort4 o = make_ushort4(L[nr][tx * 4 + 0], L[nr][tx * 4 + 1],
                                 L[nr][tx * 4 + 2], L[nr][tx * 4 + 3]);
        *reinterpret_cast<ushort4*>(&Wt[(size_t)(n0 + nr) * K + k0 + tx * 4]) = o;
    }
}

__global__ __launch_bounds__(256) void tcvt_kernel(
    const float* __restrict__ W, USHORT* __restrict__ Wt, int K, int N)
{
    tcvt_body(W, Wt, K, N);
}

__global__ __launch_bounds__(256) void tcvt4_kernel(TcvtB4 p, int K, int N)
{
    const int z = blockIdx.z;
    const float* W = (z == 0) ? p.s0 : (z == 1) ? p.s1 : (z == 2) ? p.s2 : p.s3;
    USHORT*    Wt = (z == 0) ? p.d0 : (z == 1) ? p.d1 : (z == 2) ? p.d2 : p.d3;
    tcvt_body(W, Wt, K, N);
}

// fp32 -> bf16 elementwise (n4 = count/4)
__global__ __launch_bounds__(256) void f2b_kernel(
    const float* __restrict__ in, USHORT* __restrict__ out, int n4)
{
    int i = blockIdx.x * 256 + threadIdx.x;
    if (i < n4) {
        float4 v = reinterpret_cast<const float4*>(in)[i];
        reinterpret_cast<ushort4*>(out)[i] =
            make_ushort4(f2bf(v.x), f2bf(v.y), f2bf(v.z), f2bf(v.w));
    }
}

// ---------------------------------------------------------------------------
// MFMA flash attention, double-buffered K/V staging (unchanged from R6).
// ---------------------------------------------------------------------------
__global__ __launch_bounds__(256) void attn_mfma_kernel(
    const USHORT* __restrict__ Q, const USHORT* __restrict__ K,
    const USHORT* __restrict__ Vt, USHORT* __restrict__ O, int causal)
{
    __shared__ USHORT Qs[64 * 64];
    __shared__ USHORT Ks[2][64 * 64];
    __shared__ USHORT Vs[2][64 * 64];
    __shared__ USHORT Ps[4][16 * 64];

    const int tid = threadIdx.x;
    const int l  = tid & 63;
    const int w  = tid >> 6;
    const int lr = l & 15;
    const int lg = l >> 4;

    const int lin = blockIdx.y * 16 + blockIdx.x;   // nwg = 1024
    const int swz = (lin & 7) * 128 + (lin >> 3);
    const int qt = swz & 15;
    const int bh = swz >> 4;
    const int h = bh & 15, b = bh >> 4;
    const int q0 = qt * 64;

    const USHORT* gq  = Q  + (size_t)(b * SEQ + q0) * D_MODEL + h * DH;
    const USHORT* gk0 = K  + (size_t)b * SEQ * D_MODEL + h * DH;
    const USHORT* gv0 = Vt + (size_t)bh * DH * SEQ;

    const int r0s = tid >> 3,         c0s = (tid & 7) ^ (r0s & 7);
    const int r1s = (256 + tid) >> 3, c1s = (tid & 7) ^ (r1s & 7);
    const size_t so0 = (size_t)r0s * 1024 + c0s * 8;
    const size_t so1 = (size_t)r1s * 1024 + c1s * 8;
    const int db0 = (tid & 192) << 3;
    const int db1 = (256 << 3) + db0;

#define STAGE(ldsb, gsrc) do {                 \
    GLDS((gsrc) + so0, (ldsb) + db0);          \
    GLDS((gsrc) + so1, (ldsb) + db1);          \
} while (0)

    STAGE(Qs, gq);
    STAGE(Ks[0], gk0);
    STAGE(Vs[0], gv0);

    f32x4 oacc[4];
    float m_[4], l_[4];
#pragma unroll
    for (int r = 0; r < 4; ++r) {
        m_[r] = -1e30f; l_[r] = 0.f;
    }
#pragma unroll
    for (int d = 0; d < 4; ++d) oacc[d] = (f32x4){0.f, 0.f, 0.f, 0.f};

    __syncthreads();
    short8v qa0 = ld_frag(Qs, w * 16 + lr, lg);
    short8v qa1 = ld_frag(Qs, w * 16 + lr, 4 + lg);

    const int ntile = causal ? (qt + 1) : (SEQ / 64);
    for (int kt = 0; kt < ntile; ++kt) {
        const int cur = kt & 1;
        if (kt + 1 < ntile) {
            STAGE(Ks[cur ^ 1], gk0 + (size_t)(kt + 1) * 64 * D_MODEL);
            STAGE(Vs[cur ^ 1], gv0 + (kt + 1) * 64);
        }
        const int j0 = kt * 64;

        f32x4 sa[4];
#pragma unroll
        for (int jb = 0; jb < 4; ++jb) {
            sa[jb] = (f32x4){0.f, 0.f, 0.f, 0.f};
            sa[jb] = __builtin_amdgcn_mfma_f32_16x16x32_bf16(
                qa0, ld_frag(Ks[cur], jb * 16 + lr, lg), sa[jb], 0, 0, 0);
            sa[jb] = __builtin_amdgcn_mfma_f32_16x16x32_bf16(
                qa1, ld_frag(Ks[cur], jb * 16 + lr, 4 + lg), sa[jb], 0, 0, 0);
        }

#pragma unroll
        for (int jb = 0; jb < 4; ++jb)
#pragma unroll
            for (int r = 0; r < 4; ++r) {
                float s = sa[jb][r] * SCALE;
                if (causal && kt == qt &&
                    (j0 + jb * 16 + lr) > (q0 + w * 16 + lg * 4 + r))
                    s = -1e30f;
                sa[jb][r] = s;
            }

#pragma unroll
        for (int r = 0; r < 4; ++r) {
            float tm = fmaxf(fmaxf(sa[0][r], sa[1][r]), fmaxf(sa[2][r], sa[3][r]));
            tm = fmaxf(tm, __shfl_xor(tm, 1));
            tm = fmaxf(tm, __shfl_xor(tm, 2));
            tm = fmaxf(tm, __shfl_xor(tm, 4));
            tm = fmaxf(tm, __shfl_xor(tm, 8));
            float mn = fmaxf(m_[r], tm);
            float sc = __expf(m_[r] - mn);
            m_[r] = mn;
            float rs_ = 0.f;
#pragma unroll
            for (int jb = 0; jb < 4; ++jb) {
                float p = __expf(sa[jb][r] - mn);
                sa[jb][r] = p;
                rs_ += p;
            }
            rs_ += __shfl_xor(rs_, 1);
            rs_ += __shfl_xor(rs_, 2);
            rs_ += __shfl_xor(rs_, 4);
            rs_ += __shfl_xor(rs_, 8);
            l_[r] = l_[r] * sc + rs_;
#pragma unroll
            for (int d = 0; d < 4; ++d) oacc[d][r] *= sc;
        }

        USHORT* PsW = Ps[w];
#pragma unroll
        for (int jb = 0; jb < 4; ++jb) {
            const int c8 = jb * 2 + (lr >> 3), cl = lr & 7;
#pragma unroll
            for (int r = 0; r < 4; ++r) {
                const int row = lg * 4 + r;
                PsW[row * 64 + ((c8 ^ (row & 7)) << 3) + cl] = f2bf(sa[jb][r]);
            }
        }

        short8v pa0 = ld_frag(PsW, lr, lg);
        short8v pa1 = ld_frag(PsW, lr, 4 + lg);
#pragma unroll
        for (int d = 0; d < 4; ++d) {
            oacc[d] = __builtin_amdgcn_mfma_f32_16x16x32_bf16(
                pa0, ld_frag(Vs[cur], d * 16 + lr, lg), oacc[d], 0, 0, 0);
            oacc[d] = __builtin_amdgcn_mfma_f32_16x16x32_bf16(
                pa1, ld_frag(Vs[cur], d * 16 + lr, 4 + lg), oacc[d], 0, 0, 0);
        }
        __syncthreads();
    }
#undef STAGE

    USHORT* go = O + (size_t)(b * SEQ + q0 + w * 16) * D_MODEL + h * DH;
#pragma unroll
    for (int r = 0; r < 4; ++r) {
        const float inv = 1.f / l_[r];
        const int qrow = lg * 4 + r;
#pragma unroll
        for (int d = 0; d < 4; ++d)
            go[(size_t)qrow * D_MODEL + d * 16 + lr] = f2bf(oacc[d][r] * inv);
    }
}

// ---------------------------------------------------------------------------
// out = res + LayerNorm(x)*g + b.  x bf16; res fp32 (resf) or bf16 (resb).
// ---------------------------------------------------------------------------
__global__ __launch_bounds__(256) void ln_res_kernel(
    const USHORT* __restrict__ xb, const float* __restrict__ resf,
    const USHORT* __restrict__ resb,
    const float* __restrict__ g, const float* __restrict__ bta,
    float* __restrict__ outf, USHORT* __restrict__ outb)
{
    __shared__ float red[256];
    __shared__ float s_mu, s_rstd;

    const int row = blockIdx.x;
    const int tid = threadIdx.x;
    ushort4 xv = reinterpret_cast<const ushort4*>(xb + (size_t)row * D_MODEL)[tid];
    float vx = bf2f(xv.x), vy = bf2f(xv.y), vz = bf2f(xv.z), vw = bf2f(xv.w);

    red[tid] = vx + vy + vz + vw;
    __syncthreads();
    for (int s = 128; s > 0; s >>= 1) {
        if (tid < s) red[tid] += red[tid + s];
        __syncthreads();
    }
    if (tid == 0) s_mu = red[0] * (1.f / D_MODEL);
    __syncthreads();
    const float mu = s_mu;

    float dx = vx - mu, dy = vy - mu, dz = vz - mu, dw = vw - mu;
    red[tid] = dx * dx + dy * dy + dz * dz + dw * dw;
    __syncthreads();
    for (int s = 128; s > 0; s >>= 1) {
        if (tid < s) red[tid] += red[tid + s];
        __syncthreads();
    }
    if (tid == 0) s_rstd = rsqrtf(red[0] * (1.f / D_MODEL) + EPS);
    __syncthreads();
    const float rstd = s_rstd;

    float4 rv;
    if (resf) {
        rv = reinterpret_cast<const float4*>(resf + (size_t)row * D_MODEL)[tid];
    } else {
        ushort4 rb = reinterpret_cast<const ushort4*>(
            resb + (size_t)row * D_MODEL)[tid];
        rv = make_float4(bf2f(rb.x), bf2f(rb.y), bf2f(rb.z), bf2f(rb.w));
    }
    float4 gv = reinterpret_cast<const float4*>(g)[tid];
    float4 bv = reinterpret_cast<const float4*>(bta)[tid];

    float4 o;
    o.x = rv.x + dx * rstd * gv.x + bv.x;
    o.y = rv.y + dy * rstd * gv.y + bv.y;
    o.z = rv.z + dz * rstd * gv.z + bv.z;
    o.w = rv.w + dw * rstd * gv.w + bv.w;
    reinterpret_cast<float4*>(outf + (size_t)row * D_MODEL)[tid] = o;
    if (outb)
        reinterpret_cast<ushort4*>(outb + (size_t)row * D_MODEL)[tid] =
            make_ushort4(f2bf(o.x), f2bf(o.y), f2bf(o.z), f2bf(o.w));
}

// ---------------------------------------------------------------------------
extern "C" void kernel_launch(void* const* d_in, const int* in_sizes, int n_in,
                              void* d_out, int out_size, void* d_ws, size_t ws_size,
                              hipStream_t stream)
{
    const float* X    = (const float*)d_in[0];
    const float* Wq1  = (const float*)d_in[1];
    const float* Wk1  = (const float*)d_in[2];
    const float* Wv1  = (const float*)d_in[3];
    const float* Wo1  = (const float*)d_in[4];
    const float* Wq2  = (const float*)d_in[5];
    const float* Wk2  = (const float*)d_in[6];
    const float* Wv2  = (const float*)d_in[7];
    const float* Wo2  = (const float*)d_in[8];
    const float* ln_g = (const float*)d_in[9];
    const float* ln_b = (const float*)d_in[10];
    const float* W1   = (const float*)d_in[11];
    const float* b1   = (const float*)d_in[12];
    const float* W2   = (const float*)d_in[13];
    const float* b2   = (const float*)d_in[14];

    // ws layout (ushort units; total 48 Mi = 96 MB):
    //  [0,3Mi)   Wqkv1t; [3,4) Wo1t; [4,7Mi) Wqkv2t; [7,8) Wo2t
    //  [8,12Mi)  W2t
    //  [12,16Mi) Xb ; after MHA1 projections -> W1t
    //  [16,32Mi) qb,kb,Vtb,t0b (4x4Mi); FFN hidden hb overlays all 16Mi
    //  [32,36Mi) t2b ; [36,40Mi) t1b
    //  [40,48Mi) t2 fp32 (4Mi floats)
    const size_t MI = 1024 * 1024;
    USHORT* ws16 = (USHORT*)d_ws;
    USHORT* Wqkv1t = ws16;
    USHORT* Wo1t   = ws16 + 3 * MI;
    USHORT* Wqkv2t = ws16 + 4 * MI;
    USHORT* Wo2t   = ws16 + 7 * MI;
    USHORT* W2t    = ws16 + 8 * MI;
    USHORT* Xb     = ws16 + 12 * MI;
    USHORT* W1t    = Xb;
    USHORT* qb     = ws16 + 16 * MI;
    USHORT* kb     = ws16 + 20 * MI;
    USHORT* Vtb    = ws16 + 24 * MI;
    USHORT* t0b    = ws16 + 28 * MI;
    USHORT* hb     = qb;
    USHORT* t2b    = ws16 + 32 * MI;
    USHORT* t1b    = ws16 + 36 * MI;
    float*  t2     = (float*)(ws16 + 40 * MI);

    auto gemm32 = [&](const USHORT* A, const USHORT* Bt, float* Cf, USHORT* Cb,
                      int M, int N, int K, const float* bias, int relu) {
        gemm_k32_kernel<<<dim3(N / 128, M / 128), 256, 0, stream>>>(
            A, Bt, Cf, Cb, nullptr, nullptr, M, N, K, bias, relu, 0);
    };
    auto gemm_qkv = [&](const USHORT* A, const USHORT* Bt) {
        gemm_k32_kernel<<<dim3(3072 / 128, TOK / 128), 256, 0, stream>>>(
            A, Bt, nullptr, qb, kb, Vtb, TOK, 3072, D_MODEL, nullptr, 0, 1);
    };
    auto gemm64 = [&](const USHORT* A, const USHORT* Bt, float* Cf, USHORT* Cb,
                      int M, int N, int K, const float* bias, int relu) {
        gemm_k64_kernel<<<dim3(N / 128, M / 128), 256, 0, stream>>>(
            A, Bt, Cf, Cb, M, N, K, bias, relu);
    };

    dim3 agrid(SEQ / 64, BATCH * N_HEADS);

    // ---- prologue: all square weights + W2 + X -> bf16 ----
    {
        TcvtB4 p1{Wq1, Wk1, Wv1, Wo1,
                  Wqkv1t, Wqkv1t + 1 * MI, Wqkv1t + 2 * MI, Wo1t};
        tcvt4_kernel<<<dim3(16, 16, 4), 256, 0, stream>>>(p1, D_MODEL, D_MODEL);
        TcvtB4 p2{Wq2, Wk2, Wv2, Wo2,
                  Wqkv2t, Wqkv2t + 1 * MI, Wqkv2t + 2 * MI, Wo2t};
        tcvt4_kernel<<<dim3(16, 16, 4), 256, 0, stream>>>(p2, D_MODEL, D_MODEL);
    }
    tcvt_kernel<<<dim3(D_MODEL / 64, D_FF / 64), 256, 0, stream>>>(
        W2, W2t, D_FF, D_MODEL);
    f2b_kernel<<<dim3(4096), 256, 0, stream>>>(X, Xb, TOK * D_MODEL / 4);

    // ---- MHA 1 (causal) ----
    gemm_qkv(Xb, Wqkv1t);
    attn_mfma_kernel<<<agrid, 256, 0, stream>>>(qb, kb, Vtb, t0b, 1);
    gemm64(t0b, Wo1t, nullptr, t1b, TOK, D_MODEL, D_MODEL, nullptr, 0);
    ln_res_kernel<<<dim3(TOK), 256, 0, stream>>>(t1b, X, nullptr,
                                                 ln_g, ln_b, t2, t2b);
    // W1t conversion (Xb slot now dead)
    tcvt_kernel<<<dim3(D_FF / 64, D_MODEL / 64), 256, 0, stream>>>(
        W1, W1t, D_MODEL, D_FF);

    // ---- MHA 2 (full) ----
    gemm_qkv(t2b, Wqkv2t);
    attn_mfma_kernel<<<agrid, 256, 0, stream>>>(qb, kb, Vtb, t0b, 0);
    gemm64(t0b, Wo2t, nullptr, t1b, TOK, D_MODEL, D_MODEL, nullptr, 0);
    ln_res_kernel<<<dim3(TOK), 256, 0, stream>>>(t1b, nullptr, t1b,
                                                 ln_g, ln_b, t2, t2b);

    // ---- FFN ----
    gemm32(t2b, W1t, nullptr, hb, TOK, D_FF, D_MODEL, b1, 1);
    gemm64(hb, W2t, nullptr, t1b, TOK, D_MODEL, D_FF, b2, 0);
    ln_res_kernel<<<dim3(TOK), 256, 0, stream>>>(t1b, t2, nullptr,
                                                 ln_g, ln_b, (float*)d_out, nullptr);
}

// Round 9
// 404.476 us; speedup vs baseline: 25.9799x; 1.0250x over previous
//
#include <hip/hip_runtime.h>
#include <hip/hip_bf16.h>

#define D_MODEL 1024
#define N_HEADS 16
#define DH 64
#define D_FF   4096
#define SEQ    1024
#define BATCH  4
#define TOK    (BATCH*SEQ)
#define EPS    1e-5f
#define SCALE  0.125f   // 1/sqrt(64)

typedef unsigned short USHORT;
typedef __attribute__((ext_vector_type(8))) short short8v;
typedef __attribute__((ext_vector_type(4))) float f32x4;

__device__ __forceinline__ USHORT f2bf(float f) {
    unsigned int u; __builtin_memcpy(&u, &f, 4);
    u += 0x7fffu + ((u >> 16) & 1u);          // RNE
    return (USHORT)(u >> 16);
}
__device__ __forceinline__ float bf2f(USHORT s) {
    unsigned int u = ((unsigned int)s) << 16;
    float f; __builtin_memcpy(&f, &u, 4);
    return f;
}

// row-stride-64 swizzled read: unit ^= row&7
__device__ __forceinline__ short8v ld_frag(const USHORT* lds, int row, int c8) {
    return *reinterpret_cast<const short8v*>(
        &lds[row * 64 + (((c8) ^ (row & 7)) << 3)]);
}
// row-stride-32 swizzled read (BK=32 tiles): unit ^= (row>>1)&3
__device__ __forceinline__ short8v ld32(const USHORT* lds, int row, int c8) {
    return *reinterpret_cast<const short8v*>(
        &lds[row * 32 + (((c8) ^ ((row >> 1) & 3)) << 3)]);
}
// row-stride-128 swizzled read (attn V/P tiles): unit ^= row&15
__device__ __forceinline__ short8v ld128(const USHORT* lds, int row, int cu) {
    return *reinterpret_cast<const short8v*>(
        &lds[row * 128 + (((cu) ^ (row & 15)) << 3)]);
}

#define GLDS(gsrc, ldst) \
    __builtin_amdgcn_global_load_lds( \
        (const __attribute__((address_space(1))) void*)(gsrc), \
        (__attribute__((address_space(3))) void*)(ldst), 16, 0, 0)

#define WAITVM(n) asm volatile("s_waitcnt vmcnt(" #n ")" ::: "memory")

// ---------------------------------------------------------------------------
// bf16 MFMA GEMM, BK=32, 3-buffer counted-vmcnt pipeline.
// Epilogues: normal (Cf fp32 / Cb bf16) or fused-QKV routing (Q pre-scaled).
// ---------------------------------------------------------------------------
__global__ __launch_bounds__(256) void gemm_k32_kernel(
    const USHORT* __restrict__ A, const USHORT* __restrict__ Bt,
    float* __restrict__ Cf, USHORT* __restrict__ Cb, USHORT* __restrict__ Ck,
    USHORT* __restrict__ VtOut,
    int M, int N, int K, const float* __restrict__ bias, int relu, int qkv)
{
    __shared__ USHORT As[3][128 * 32];
    __shared__ USHORT Bs[3][128 * 32];

    const int tid = threadIdx.x;
    const int l   = tid & 63;
    const int w   = tid >> 6;
    const int wr  = w >> 1, wc = w & 1;
    const int lr  = l & 15, lg = l >> 4;

    const int gx  = gridDim.x;
    const int nwg = gx * gridDim.y;
    const int lin = blockIdx.y * gx + blockIdx.x;
    const int swz = (lin & 7) * (nwg >> 3) + (lin >> 3);
    const int m0  = (swz / gx) * 128, n0 = (swz % gx) * 128;

    const int q0 = tid,        r0 = q0 >> 2, c0 = ((q0 & 3) ^ ((r0 >> 1) & 3)) * 8;
    const int q1 = 256 + tid,  r1 = q1 >> 2, c1 = ((q1 & 3) ^ ((r1 >> 1) & 3)) * 8;

    const USHORT* a0 = A  + (size_t)(m0 + r0) * K + c0;
    const USHORT* a1 = A  + (size_t)(m0 + r1) * K + c1;
    const USHORT* b0 = Bt + (size_t)(n0 + r0) * K + c0;
    const USHORT* b1 = Bt + (size_t)(n0 + r1) * K + c1;
    const int la0 = (w * 64) * 8;
    const int la1 = (256 + w * 64) * 8;

    auto stage = [&](int buf, int k0) {
        GLDS(a0 + k0, &As[buf][la0]);
        GLDS(a1 + k0, &As[buf][la1]);
        GLDS(b0 + k0, &Bs[buf][la0]);
        GLDS(b1 + k0, &Bs[buf][la1]);
    };

    f32x4 acc[4][4];
#pragma unroll
    for (int i = 0; i < 4; ++i)
#pragma unroll
        for (int j = 0; j < 4; ++j) acc[i][j] = (f32x4){0.f, 0.f, 0.f, 0.f};

    const int nk = K >> 5;
    stage(0, 0);
    if (nk > 1) stage(1, 32);

    for (int t = 0; t < nk; ++t) {
        const int cur = t % 3;
        if (t + 1 < nk) { WAITVM(4); } else { WAITVM(0); }
        __builtin_amdgcn_s_barrier();
        if (t + 2 < nk) stage((t + 2) % 3, (t + 2) << 5);

        short8v af[4], bfr[4];
#pragma unroll
        for (int mi = 0; mi < 4; ++mi)
            af[mi] = ld32(As[cur], wr * 64 + mi * 16 + lr, lg);
#pragma unroll
        for (int ni = 0; ni < 4; ++ni)
            bfr[ni] = ld32(Bs[cur], wc * 64 + ni * 16 + lr, lg);
        __builtin_amdgcn_s_setprio(1);
#pragma unroll
        for (int mi = 0; mi < 4; ++mi)
#pragma unroll
            for (int ni = 0; ni < 4; ++ni)
                acc[mi][ni] = __builtin_amdgcn_mfma_f32_16x16x32_bf16(
                    af[mi], bfr[ni], acc[mi][ni], 0, 0, 0);
        __builtin_amdgcn_s_setprio(0);
    }

    // epilogue: C/D layout col = lane&15, row = (lane>>4)*4 + reg
    if (qkv) {
#pragma unroll
        for (int mi = 0; mi < 4; ++mi) {
            const int row = m0 + wr * 64 + mi * 16 + (l >> 4) * 4;
#pragma unroll
            for (int ni = 0; ni < 4; ++ni) {
                const int col = n0 + wc * 64 + ni * 16 + lr;
                if (col < 2048) {
                    USHORT* dst = (col < 1024) ? Cb : Ck;
                    const float scl = (col < 1024) ? SCALE : 1.f;  // pre-scale Q
                    const int c = col & 1023;
#pragma unroll
                    for (int j = 0; j < 4; ++j)
                        dst[(size_t)(row + j) * D_MODEL + c] =
                            f2bf(acc[mi][ni][j] * scl);
                } else {
                    const int c = col - 2048;
                    const int bb = row >> 10, jr = row & 1023;
                    const int hh = c >> 6, dd = c & 63;
                    ushort4 pk = make_ushort4(
                        f2bf(acc[mi][ni][0]), f2bf(acc[mi][ni][1]),
                        f2bf(acc[mi][ni][2]), f2bf(acc[mi][ni][3]));
                    *reinterpret_cast<ushort4*>(
                        &VtOut[((size_t)(bb * 16 + hh) * 64 + dd) * 1024 + jr]) = pk;
                }
            }
        }
    } else {
#pragma unroll
        for (int mi = 0; mi < 4; ++mi) {
            const int row = m0 + wr * 64 + mi * 16 + (l >> 4) * 4;
#pragma unroll
            for (int ni = 0; ni < 4; ++ni) {
                const int col = n0 + wc * 64 + ni * 16 + lr;
                const float bv = bias ? bias[col] : 0.f;
#pragma unroll
                for (int j = 0; j < 4; ++j) {
                    float v = acc[mi][ni][j] + bv;
                    if (relu) v = fmaxf(v, 0.f);
                    const size_t idx = (size_t)(row + j) * N + col;
                    if (Cf) Cf[idx] = v;
                    if (Cb) Cb[idx] = f2bf(v);
                }
            }
        }
    }
}

// ---------------------------------------------------------------------------
// bf16 MFMA GEMM, BK=64, 4-buffer counted-vmcnt pipeline.
// ---------------------------------------------------------------------------
__global__ __launch_bounds__(256) void gemm_k64_kernel(
    const USHORT* __restrict__ A, const USHORT* __restrict__ Bt,
    float* __restrict__ Cf, USHORT* __restrict__ Cb,
    int M, int N, int K, const float* __restrict__ bias, int relu)
{
    __shared__ USHORT As[4][128 * 64];
    __shared__ USHORT Bs[4][128 * 64];

    const int tid = threadIdx.x;
    const int l   = tid & 63;
    const int w   = tid >> 6;
    const int wr  = w >> 1, wc = w & 1;
    const int lr  = l & 15, lg = l >> 4;

    const int gx  = gridDim.x;
    const int nwg = gx * gridDim.y;
    const int lin = blockIdx.y * gx + blockIdx.x;
    const int swz = (lin & 7) * (nwg >> 3) + (lin >> 3);
    const int m0  = (swz / gx) * 128, n0 = (swz % gx) * 128;

    const USHORT* aS[4]; const USHORT* bS[4]; int dOf[4];
#pragma unroll
    for (int p = 0; p < 4; ++p) {
        const int q = p * 256 + tid;
        const int row = q >> 3, cu = q & 7;
        const int cs = ((cu ^ (row & 7)) << 3);
        aS[p] = A  + (size_t)(m0 + row) * K + cs;
        bS[p] = Bt + (size_t)(n0 + row) * K + cs;
        dOf[p] = (p * 256 + w * 64) * 8;
    }

    auto stage = [&](int buf, int k0) {
#pragma unroll
        for (int p = 0; p < 4; ++p) {
            GLDS(aS[p] + k0, &As[buf][dOf[p]]);
            GLDS(bS[p] + k0, &Bs[buf][dOf[p]]);
        }
    };

    f32x4 acc[4][4];
#pragma unroll
    for (int i = 0; i < 4; ++i)
#pragma unroll
        for (int j = 0; j < 4; ++j) acc[i][j] = (f32x4){0.f, 0.f, 0.f, 0.f};

    const int nk = K >> 6;
    stage(0, 0);
    if (nk > 1) stage(1, 64);
    if (nk > 2) stage(2, 128);

    for (int t = 0; t < nk; ++t) {
        const int cur = t & 3;
        if (t + 2 < nk)      { WAITVM(16); }
        else if (t + 1 < nk) { WAITVM(8); }
        else                 { WAITVM(0); }
        __builtin_amdgcn_s_barrier();
        if (t + 3 < nk) stage((t + 3) & 3, (t + 3) << 6);

#pragma unroll
        for (int ks = 0; ks < 2; ++ks) {
            short8v af[4], bfr[4];
#pragma unroll
            for (int mi = 0; mi < 4; ++mi)
                af[mi] = ld_frag(As[cur], wr * 64 + mi * 16 + lr, ks * 4 + lg);
#pragma unroll
            for (int ni = 0; ni < 4; ++ni)
                bfr[ni] = ld_frag(Bs[cur], wc * 64 + ni * 16 + lr, ks * 4 + lg);
            __builtin_amdgcn_s_setprio(1);
#pragma unroll
            for (int mi = 0; mi < 4; ++mi)
#pragma unroll
                for (int ni = 0; ni < 4; ++ni)
                    acc[mi][ni] = __builtin_amdgcn_mfma_f32_16x16x32_bf16(
                        af[mi], bfr[ni], acc[mi][ni], 0, 0, 0);
            __builtin_amdgcn_s_setprio(0);
        }
    }

#pragma unroll
    for (int mi = 0; mi < 4; ++mi) {
        const int row = m0 + wr * 64 + mi * 16 + (l >> 4) * 4;
#pragma unroll
        for (int ni = 0; ni < 4; ++ni) {
            const int col = n0 + wc * 64 + ni * 16 + lr;
            const float bv = bias ? bias[col] : 0.f;
#pragma unroll
            for (int j = 0; j < 4; ++j) {
                float v = acc[mi][ni][j] + bv;
                if (relu) v = fmaxf(v, 0.f);
                const size_t idx = (size_t)(row + j) * N + col;
                if (Cf) Cf[idx] = v;
                if (Cb) Cb[idx] = f2bf(v);
            }
        }
    }
}

// ---------------------------------------------------------------------------
// Weight convert+transpose kernels (unchanged).
// ---------------------------------------------------------------------------
struct TcvtB4 {
    const float* s0; const float* s1; const float* s2; const float* s3;
    USHORT* d0; USHORT* d1; USHORT* d2; USHORT* d3;
};

__device__ __forceinline__ void tcvt_body(
    const float* __restrict__ W, USHORT* __restrict__ Wt, int K, int N)
{
    __shared__ USHORT L[64][65];
    const int tid = threadIdx.x;
    const int tx = tid & 15, ty = tid >> 4;
    const int n0 = blockIdx.x * 64, k0 = blockIdx.y * 64;
#pragma unroll
    for (int r = 0; r < 4; ++r) {
        int kr = ty + 16 * r;
        float4 v = *reinterpret_cast<const float4*>(
            &W[(size_t)(k0 + kr) * N + n0 + tx * 4]);
        L[tx * 4 + 0][kr] = f2bf(v.x);
        L[tx * 4 + 1][kr] = f2bf(v.y);
        L[tx * 4 + 2][kr] = f2bf(v.z);
        L[tx * 4 + 3][kr] = f2bf(v.w);
    }
    __syncthreads();
#pragma unroll
    for (int r = 0; r < 4; ++r) {
        int nr = ty + 16 * r;
        ushort4 o = make_ushort4(L[nr][tx * 4 + 0], L[nr][tx * 4 + 1],
                                 L[nr][tx * 4 + 2], L[nr][tx * 4 + 3]);
        *reinterpret_cast<ushort4*>(&Wt[(size_t)(n0 + nr) * K + k0 + tx * 4]) = o;
    }
}

__global__ __launch_bounds__(256) void tcvt_kernel(
    const float* __restrict__ W, USHORT* __restrict__ Wt, int K, int N)
{
    tcvt_body(W, Wt, K, N);
}

__global__ __launch_bounds__(256) void tcvt4_kernel(TcvtB4 p, int K, int N)
{
    const int z = blockIdx.z;
    const float* W = (z == 0) ? p.s0 : (z == 1) ? p.s1 : (z == 2) ? p.s2 : p.s3;
    USHORT*    Wt = (z == 0) ? p.d0 : (z == 1) ? p.d1 : (z == 2) ? p.d2 : p.d3;
    tcvt_body(W, Wt, K, N);
}

__global__ __launch_bounds__(256) void f2b_kernel(
    const float* __restrict__ in, USHORT* __restrict__ out, int n4)
{
    int i = blockIdx.x * 256 + threadIdx.x;
    if (i < n4) {
        float4 v = reinterpret_cast<const float4*>(in)[i];
        reinterpret_cast<ushort4*>(out)[i] =
            make_ushort4(f2bf(v.x), f2bf(v.y), f2bf(v.z), f2bf(v.w));
    }
}

// ---------------------------------------------------------------------------
// MFMA flash attention, KVBLK=128, dbuf K/V, Q/P LDS union, defer-max (THR=8),
// setprio around MFMA clusters. Q arrives pre-scaled by 1/sqrt(DH).
// LDS map (ushort offsets in smem, 80 KB total):
//   Ks buf0 @0, buf1 @8192        ([128 j][64 d], row&7 swizzle)
//   Vs buf0 @16384, buf1 @24576   ([64 d][128 j], row&15 swizzle)
//   QP @32768 (Q [64][64] until consumed; then P: per-wave 16x128 @ +w*2048)
// NOTE: no pointer arrays from __shared__ (hipcc addrspacecast limitation) —
// buffers selected by inline offset arithmetic.
// ---------------------------------------------------------------------------
__global__ __launch_bounds__(256) void attn_mfma_kernel(
    const USHORT* __restrict__ Q, const USHORT* __restrict__ K,
    const USHORT* __restrict__ Vt, USHORT* __restrict__ O, int causal)
{
    __shared__ USHORT smem[40960];                 // 80 KB

    const int tid = threadIdx.x;
    const int l  = tid & 63;
    const int w  = tid >> 6;
    const int lr = l & 15;
    const int lg = l >> 4;

    const int lin = blockIdx.y * 16 + blockIdx.x;   // nwg = 1024
    const int swz = (lin & 7) * 128 + (lin >> 3);
    const int qt = swz & 15;
    const int bh = swz >> 4;
    const int h = bh & 15, b = bh >> 4;
    const int q0 = qt * 64;

    const USHORT* gq  = Q  + (size_t)(b * SEQ + q0) * D_MODEL + h * DH;
    const USHORT* gk0 = K  + (size_t)b * SEQ * D_MODEL + h * DH;
    const USHORT* gv0 = Vt + (size_t)bh * DH * SEQ;

    auto stageK = [&](int buf, int kt) {           // 128x64, row&7 swizzle
        USHORT* dst = smem + buf * 8192;
        const size_t base = (size_t)kt * 128 * 1024;
#pragma unroll
        for (int p = 0; p < 4; ++p) {
            const int q = p * 256 + tid;
            const int row = q >> 3, cu = q & 7;
            GLDS(gk0 + base + (size_t)row * 1024 + ((cu ^ (row & 7)) << 3),
                 dst + (p * 256 + w * 64) * 8);
        }
    };
    auto stageV = [&](int buf, int kt) {           // 64x128, row&15 swizzle
        USHORT* dst = smem + 16384 + buf * 8192;
        const int j0 = kt * 128;
#pragma unroll
        for (int p = 0; p < 4; ++p) {
            const int q = p * 256 + tid;
            const int row = q >> 4, cu = q & 15;
            GLDS(gv0 + (size_t)row * 1024 + j0 + ((cu ^ (row & 15)) << 3),
                 dst + (p * 256 + w * 64) * 8);
        }
    };

    // stage Q (64x64, row&7 swizzle) + first K/V tile
#pragma unroll
    for (int p = 0; p < 2; ++p) {
        const int q = p * 256 + tid;
        const int row = q >> 3, cu = q & 7;
        GLDS(gq + (size_t)row * 1024 + ((cu ^ (row & 7)) << 3),
             smem + 32768 + (p * 256 + w * 64) * 8);
    }
    stageK(0, 0);
    stageV(0, 0);

    f32x4 oacc[4];
    float m_[4], l_[4];
#pragma unroll
    for (int r = 0; r < 4; ++r) { m_[r] = -1e30f; l_[r] = 0.f; }
#pragma unroll
    for (int d = 0; d < 4; ++d) oacc[d] = (f32x4){0.f, 0.f, 0.f, 0.f};

    __syncthreads();                               // Q + tile 0 staged
    short8v qa0 = ld_frag(smem + 32768, w * 16 + lr, lg);
    short8v qa1 = ld_frag(smem + 32768, w * 16 + lr, 4 + lg);
    __syncthreads();                               // Q consumed -> Ps may reuse
    USHORT* PsW = smem + 32768 + w * 2048;         // per-wave P [16 q][128 j]

    const int ntile = causal ? (qt >> 1) + 1 : (SEQ / 128);
    for (int kt = 0; kt < ntile; ++kt) {
        const int cur = kt & 1;
        if (kt + 1 < ntile) {                      // prefetch next K/V tile
            stageK(cur ^ 1, kt + 1);
            stageV(cur ^ 1, kt + 1);
        }
        const int j0 = kt * 128;
        const USHORT* KsC = smem + cur * 8192;
        const USHORT* VsC = smem + 16384 + cur * 8192;

        // S = Q K^T  (Q pre-scaled)
        f32x4 sa[8];
        __builtin_amdgcn_s_setprio(1);
#pragma unroll
        for (int jb = 0; jb < 8; ++jb) {
            sa[jb] = (f32x4){0.f, 0.f, 0.f, 0.f};
            sa[jb] = __builtin_amdgcn_mfma_f32_16x16x32_bf16(
                qa0, ld_frag(KsC, jb * 16 + lr, lg), sa[jb], 0, 0, 0);
            sa[jb] = __builtin_amdgcn_mfma_f32_16x16x32_bf16(
                qa1, ld_frag(KsC, jb * 16 + lr, 4 + lg), sa[jb], 0, 0, 0);
        }
        __builtin_amdgcn_s_setprio(0);

        // causal mask: only the last tile can cross the diagonal
        if (causal && kt == ntile - 1) {
#pragma unroll
            for (int jb = 0; jb < 8; ++jb)
#pragma unroll
                for (int r = 0; r < 4; ++r)
                    if ((j0 + jb * 16 + lr) > (q0 + w * 16 + lg * 4 + r))
                        sa[jb][r] = -1e30f;
        }

        // online softmax with defer-max (state replicated across 16-lane group)
#pragma unroll
        for (int r = 0; r < 4; ++r) {
            float tm = fmaxf(fmaxf(fmaxf(sa[0][r], sa[1][r]),
                                   fmaxf(sa[2][r], sa[3][r])),
                             fmaxf(fmaxf(sa[4][r], sa[5][r]),
                                   fmaxf(sa[6][r], sa[7][r])));
            tm = fmaxf(tm, __shfl_xor(tm, 1));
            tm = fmaxf(tm, __shfl_xor(tm, 2));
            tm = fmaxf(tm, __shfl_xor(tm, 4));
            tm = fmaxf(tm, __shfl_xor(tm, 8));
            if (tm > m_[r] + 8.f) {                // significant growth only
                float sc = __expf(m_[r] - tm);
                l_[r] *= sc;
#pragma unroll
                for (int d = 0; d < 4; ++d) oacc[d][r] *= sc;
                m_[r] = tm;
            }
            float rs_ = 0.f;
#pragma unroll
            for (int jb = 0; jb < 8; ++jb) {
                float p = __expf(sa[jb][r] - m_[r]);
                sa[jb][r] = p;
                rs_ += p;
            }
            rs_ += __shfl_xor(rs_, 1);
            rs_ += __shfl_xor(rs_, 2);
            rs_ += __shfl_xor(rs_, 4);
            rs_ += __shfl_xor(rs_, 8);
            l_[r] += rs_;
        }

        // P -> per-wave swizzled LDS (bf16), [16 q][128 j], unit ^= row&15
#pragma unroll
        for (int jb = 0; jb < 8; ++jb) {
            const int cu = jb * 2 + (lr >> 3), cl = lr & 7;
#pragma unroll
            for (int r = 0; r < 4; ++r) {
                const int row = lg * 4 + r;
                PsW[row * 128 + ((cu ^ (row & 15)) << 3) + cl] = f2bf(sa[jb][r]);
            }
        }

        // PV: oacc[d] += P(16q x 32j) * V(32j x 16d), 4 j-slots x 4 d-blocks
        __builtin_amdgcn_s_setprio(1);
#pragma unroll
        for (int ks = 0; ks < 4; ++ks) {
            short8v pa = ld128(PsW, lr, ks * 4 + lg);
#pragma unroll
            for (int d = 0; d < 4; ++d)
                oacc[d] = __builtin_amdgcn_mfma_f32_16x16x32_bf16(
                    pa, ld128(VsC, d * 16 + lr, ks * 4 + lg), oacc[d], 0, 0, 0);
        }
        __builtin_amdgcn_s_setprio(0);
        __syncthreads();   // drains prefetch + guards K/V/P buffer reuse
    }

    USHORT* go = O + (size_t)(b * SEQ + q0 + w * 16) * D_MODEL + h * DH;
#pragma unroll
    for (int r = 0; r < 4; ++r) {
        const float inv = 1.f / l_[r];
        const int qrow = lg * 4 + r;
#pragma unroll
        for (int d = 0; d < 4; ++d)
            go[(size_t)qrow * D_MODEL + d * 16 + lr] = f2bf(oacc[d][r] * inv);
    }
}

// ---------------------------------------------------------------------------
// out = res + LayerNorm(x)*g + b.  x bf16; res fp32 (resf) or bf16 (resb).
// ---------------------------------------------------------------------------
__global__ __launch_bounds__(256) void ln_res_kernel(
    const USHORT* __restrict__ xb, const float* __restrict__ resf,
    const USHORT* __restrict__ resb,
    const float* __restrict__ g, const float* __restrict__ bta,
    float* __restrict__ outf, USHORT* __restrict__ outb)
{
    __shared__ float red[256];
    __shared__ float s_mu, s_rstd;

    const int row = blockIdx.x;
    const int tid = threadIdx.x;
    ushort4 xv = reinterpret_cast<const ushort4*>(xb + (size_t)row * D_MODEL)[tid];
    float vx = bf2f(xv.x), vy = bf2f(xv.y), vz = bf2f(xv.z), vw = bf2f(xv.w);

    red[tid] = vx + vy + vz + vw;
    __syncthreads();
    for (int s = 128; s > 0; s >>= 1) {
        if (tid < s) red[tid] += red[tid + s];
        __syncthreads();
    }
    if (tid == 0) s_mu = red[0] * (1.f / D_MODEL);
    __syncthreads();
    const float mu = s_mu;

    float dx = vx - mu, dy = vy - mu, dz = vz - mu, dw = vw - mu;
    red[tid] = dx * dx + dy * dy + dz * dz + dw * dw;
    __syncthreads();
    for (int s = 128; s > 0; s >>= 1) {
        if (tid < s) red[tid] += red[tid + s];
        __syncthreads();
    }
    if (tid == 0) s_rstd = rsqrtf(red[0] * (1.f / D_MODEL) + EPS);
    __syncthreads();
    const float rstd = s_rstd;

    float4 rv;
    if (resf) {
        rv = reinterpret_cast<const float4*>(resf + (size_t)row * D_MODEL)[tid];
    } else {
        ushort4 rb = reinterpret_cast<const ushort4*>(
            resb + (size_t)row * D_MODEL)[tid];
        rv = make_float4(bf2f(rb.x), bf2f(rb.y), bf2f(rb.z), bf2f(rb.w));
    }
    float4 gv = reinterpret_cast<const float4*>(g)[tid];
    float4 bv = reinterpret_cast<const float4*>(bta)[tid];

    float4 o;
    o.x = rv.x + dx * rstd * gv.x + bv.x;
    o.y = rv.y + dy * rstd * gv.y + bv.y;
    o.z = rv.z + dz * rstd * gv.z + bv.z;
    o.w = rv.w + dw * rstd * gv.w + bv.w;
    reinterpret_cast<float4*>(outf + (size_t)row * D_MODEL)[tid] = o;
    if (outb)
        reinterpret_cast<ushort4*>(outb + (size_t)row * D_MODEL)[tid] =
            make_ushort4(f2bf(o.x), f2bf(o.y), f2bf(o.z), f2bf(o.w));
}

// ---------------------------------------------------------------------------
extern "C" void kernel_launch(void* const* d_in, const int* in_sizes, int n_in,
                              void* d_out, int out_size, void* d_ws, size_t ws_size,
                              hipStream_t stream)
{
    const float* X    = (const float*)d_in[0];
    const float* Wq1  = (const float*)d_in[1];
    const float* Wk1  = (const float*)d_in[2];
    const float* Wv1  = (const float*)d_in[3];
    const float* Wo1  = (const float*)d_in[4];
    const float* Wq2  = (const float*)d_in[5];
    const float* Wk2  = (const float*)d_in[6];
    const float* Wv2  = (const float*)d_in[7];
    const float* Wo2  = (const float*)d_in[8];
    const float* ln_g = (const float*)d_in[9];
    const float* ln_b = (const float*)d_in[10];
    const float* W1   = (const float*)d_in[11];
    const float* b1   = (const float*)d_in[12];
    const float* W2   = (const float*)d_in[13];
    const float* b2   = (const float*)d_in[14];

    const size_t MI = 1024 * 1024;
    USHORT* ws16 = (USHORT*)d_ws;
    USHORT* Wqkv1t = ws16;
    USHORT* Wo1t   = ws16 + 3 * MI;
    USHORT* Wqkv2t = ws16 + 4 * MI;
    USHORT* Wo2t   = ws16 + 7 * MI;
    USHORT* W2t    = ws16 + 8 * MI;
    USHORT* Xb     = ws16 + 12 * MI;
    USHORT* W1t    = Xb;
    USHORT* qb     = ws16 + 16 * MI;
    USHORT* kb     = ws16 + 20 * MI;
    USHORT* Vtb    = ws16 + 24 * MI;
    USHORT* t0b    = ws16 + 28 * MI;
    USHORT* hb     = qb;
    USHORT* t2b    = ws16 + 32 * MI;
    USHORT* t1b    = ws16 + 36 * MI;
    float*  t2     = (float*)(ws16 + 40 * MI);

    auto gemm32 = [&](const USHORT* A, const USHORT* Bt, float* Cf, USHORT* Cb,
                      int M, int N, int K, const float* bias, int relu) {
        gemm_k32_kernel<<<dim3(N / 128, M / 128), 256, 0, stream>>>(
            A, Bt, Cf, Cb, nullptr, nullptr, M, N, K, bias, relu, 0);
    };
    auto gemm_qkv = [&](const USHORT* A, const USHORT* Bt) {
        gemm_k32_kernel<<<dim3(3072 / 128, TOK / 128), 256, 0, stream>>>(
            A, Bt, nullptr, qb, kb, Vtb, TOK, 3072, D_MODEL, nullptr, 0, 1);
    };
    auto gemm64 = [&](const USHORT* A, const USHORT* Bt, float* Cf, USHORT* Cb,
                      int M, int N, int K, const float* bias, int relu) {
        gemm_k64_kernel<<<dim3(N / 128, M / 128), 256, 0, stream>>>(
            A, Bt, Cf, Cb, M, N, K, bias, relu);
    };

    dim3 agrid(SEQ / 64, BATCH * N_HEADS);

    // ---- prologue: all square weights + W2 + X -> bf16 ----
    {
        TcvtB4 p1{Wq1, Wk1, Wv1, Wo1,
                  Wqkv1t, Wqkv1t + 1 * MI, Wqkv1t + 2 * MI, Wo1t};
        tcvt4_kernel<<<dim3(16, 16, 4), 256, 0, stream>>>(p1, D_MODEL, D_MODEL);
        TcvtB4 p2{Wq2, Wk2, Wv2, Wo2,
                  Wqkv2t, Wqkv2t + 1 * MI, Wqkv2t + 2 * MI, Wo2t};
        tcvt4_kernel<<<dim3(16, 16, 4), 256, 0, stream>>>(p2, D_MODEL, D_MODEL);
    }
    tcvt_kernel<<<dim3(D_MODEL / 64, D_FF / 64), 256, 0, stream>>>(
        W2, W2t, D_FF, D_MODEL);
    f2b_kernel<<<dim3(4096), 256, 0, stream>>>(X, Xb, TOK * D_MODEL / 4);

    // ---- MHA 1 (causal) ----
    gemm_qkv(Xb, Wqkv1t);
    attn_mfma_kernel<<<agrid, 256, 0, stream>>>(qb, kb, Vtb, t0b, 1);
    gemm64(t0b, Wo1t, nullptr, t1b, TOK, D_MODEL, D_MODEL, nullptr, 0);
    ln_res_kernel<<<dim3(TOK), 256, 0, stream>>>(t1b, X, nullptr,
                                                 ln_g, ln_b, t2, t2b);
    tcvt_kernel<<<dim3(D_FF / 64, D_MODEL / 64), 256, 0, stream>>>(
        W1, W1t, D_MODEL, D_FF);

    // ---- MHA 2 (full) ----
    gemm_qkv(t2b, Wqkv2t);
    attn_mfma_kernel<<<agrid, 256, 0, stream>>>(qb, kb, Vtb, t0b, 0);
    gemm64(t0b, Wo2t, nullptr, t1b, TOK, D_MODEL, D_MODEL, nullptr, 0);
    ln_res_kernel<<<dim3(TOK), 256, 0, stream>>>(t1b, nullptr, t1b,
                                                 ln_g, ln_b, t2, t2b);

    // ---- FFN ----
    gemm32(t2b, W1t, nullptr, hb, TOK, D_FF, D_MODEL, b1, 1);
    gemm64(hb, W2t, nullptr, t1b, TOK, D_MODEL, D_FF, b2, 0);
    ln_res_kernel<<<dim3(TOK), 256, 0, stream>>>(t1b, t2, nullptr,
                                                 ln_g, ln_b, (float*)d_out, nullptr);
}

// Round 10
// 386.671 us; speedup vs baseline: 27.1762x; 1.0460x over previous
//
#include <hip/hip_runtime.h>
#include <hip/hip_bf16.h>

#define D_MODEL 1024
#define N_HEADS 16
#define DH 64
#define D_FF   4096
#define SEQ    1024
#define BATCH  4
#define TOK    (BATCH*SEQ)
#define EPS    1e-5f
#define SCALE  0.125f   // 1/sqrt(64)

typedef unsigned short USHORT;
typedef __attribute__((ext_vector_type(8))) short short8v;
typedef __attribute__((ext_vector_type(4))) float f32x4;

__device__ __forceinline__ USHORT f2bf(float f) {
    unsigned int u; __builtin_memcpy(&u, &f, 4);
    u += 0x7fffu + ((u >> 16) & 1u);          // RNE
    return (USHORT)(u >> 16);
}
__device__ __forceinline__ float bf2f(USHORT s) {
    unsigned int u = ((unsigned int)s) << 16;
    float f; __builtin_memcpy(&f, &u, 4);
    return f;
}

// row-stride-64 swizzled read: unit ^= row&7
__device__ __forceinline__ short8v ld_frag(const USHORT* lds, int row, int c8) {
    return *reinterpret_cast<const short8v*>(
        &lds[row * 64 + (((c8) ^ (row & 7)) << 3)]);
}
// row-stride-32 swizzled read (BK=32 tiles): unit ^= (row>>1)&3
__device__ __forceinline__ short8v ld32(const USHORT* lds, int row, int c8) {
    return *reinterpret_cast<const short8v*>(
        &lds[row * 32 + (((c8) ^ ((row >> 1) & 3)) << 3)]);
}
// row-stride-128 swizzled read (attn V/P tiles): unit ^= row&15
__device__ __forceinline__ short8v ld128(const USHORT* lds, int row, int cu) {
    return *reinterpret_cast<const short8v*>(
        &lds[row * 128 + (((cu) ^ (row & 15)) << 3)]);
}

#define GLDS(gsrc, ldst) \
    __builtin_amdgcn_global_load_lds( \
        (const __attribute__((address_space(1))) void*)(gsrc), \
        (__attribute__((address_space(3))) void*)(ldst), 16, 0, 0)

#define WAITVM(n) asm volatile("s_waitcnt vmcnt(" #n ")" ::: "memory")

// ---------------------------------------------------------------------------
// bf16 MFMA GEMM, BK=32, 3-buffer counted-vmcnt pipeline.
// Epilogues: normal (Cf fp32 / Cb bf16) or fused-QKV routing (Q pre-scaled).
// ---------------------------------------------------------------------------
__global__ __launch_bounds__(256) void gemm_k32_kernel(
    const USHORT* __restrict__ A, const USHORT* __restrict__ Bt,
    float* __restrict__ Cf, USHORT* __restrict__ Cb, USHORT* __restrict__ Ck,
    USHORT* __restrict__ VtOut,
    int M, int N, int K, const float* __restrict__ bias, int relu, int qkv)
{
    __shared__ USHORT As[3][128 * 32];
    __shared__ USHORT Bs[3][128 * 32];

    const int tid = threadIdx.x;
    const int l   = tid & 63;
    const int w   = tid >> 6;
    const int wr  = w >> 1, wc = w & 1;
    const int lr  = l & 15, lg = l >> 4;

    const int gx  = gridDim.x;
    const int nwg = gx * gridDim.y;
    const int lin = blockIdx.y * gx + blockIdx.x;
    const int swz = (lin & 7) * (nwg >> 3) + (lin >> 3);
    const int m0  = (swz / gx) * 128, n0 = (swz % gx) * 128;

    const int q0 = tid,        r0 = q0 >> 2, c0 = ((q0 & 3) ^ ((r0 >> 1) & 3)) * 8;
    const int q1 = 256 + tid,  r1 = q1 >> 2, c1 = ((q1 & 3) ^ ((r1 >> 1) & 3)) * 8;

    const USHORT* a0 = A  + (size_t)(m0 + r0) * K + c0;
    const USHORT* a1 = A  + (size_t)(m0 + r1) * K + c1;
    const USHORT* b0 = Bt + (size_t)(n0 + r0) * K + c0;
    const USHORT* b1 = Bt + (size_t)(n0 + r1) * K + c1;
    const int la0 = (w * 64) * 8;
    const int la1 = (256 + w * 64) * 8;

    auto stage = [&](int buf, int k0) {
        GLDS(a0 + k0, &As[buf][la0]);
        GLDS(a1 + k0, &As[buf][la1]);
        GLDS(b0 + k0, &Bs[buf][la0]);
        GLDS(b1 + k0, &Bs[buf][la1]);
    };

    f32x4 acc[4][4];
#pragma unroll
    for (int i = 0; i < 4; ++i)
#pragma unroll
        for (int j = 0; j < 4; ++j) acc[i][j] = (f32x4){0.f, 0.f, 0.f, 0.f};

    const int nk = K >> 5;
    stage(0, 0);
    if (nk > 1) stage(1, 32);

    for (int t = 0; t < nk; ++t) {
        const int cur = t % 3;
        if (t + 1 < nk) { WAITVM(4); } else { WAITVM(0); }
        __builtin_amdgcn_s_barrier();
        if (t + 2 < nk) stage((t + 2) % 3, (t + 2) << 5);

        short8v af[4], bfr[4];
#pragma unroll
        for (int mi = 0; mi < 4; ++mi)
            af[mi] = ld32(As[cur], wr * 64 + mi * 16 + lr, lg);
#pragma unroll
        for (int ni = 0; ni < 4; ++ni)
            bfr[ni] = ld32(Bs[cur], wc * 64 + ni * 16 + lr, lg);
        __builtin_amdgcn_s_setprio(1);
#pragma unroll
        for (int mi = 0; mi < 4; ++mi)
#pragma unroll
            for (int ni = 0; ni < 4; ++ni)
                acc[mi][ni] = __builtin_amdgcn_mfma_f32_16x16x32_bf16(
                    af[mi], bfr[ni], acc[mi][ni], 0, 0, 0);
        __builtin_amdgcn_s_setprio(0);
    }

    // epilogue: C/D layout col = lane&15, row = (lane>>4)*4 + reg
    if (qkv) {
#pragma unroll
        for (int mi = 0; mi < 4; ++mi) {
            const int row = m0 + wr * 64 + mi * 16 + (l >> 4) * 4;
#pragma unroll
            for (int ni = 0; ni < 4; ++ni) {
                const int col = n0 + wc * 64 + ni * 16 + lr;
                if (col < 2048) {
                    USHORT* dst = (col < 1024) ? Cb : Ck;
                    const float scl = (col < 1024) ? SCALE : 1.f;  // pre-scale Q
                    const int c = col & 1023;
#pragma unroll
                    for (int j = 0; j < 4; ++j)
                        dst[(size_t)(row + j) * D_MODEL + c] =
                            f2bf(acc[mi][ni][j] * scl);
                } else {
                    const int c = col - 2048;
                    const int bb = row >> 10, jr = row & 1023;
                    const int hh = c >> 6, dd = c & 63;
                    ushort4 pk = make_ushort4(
                        f2bf(acc[mi][ni][0]), f2bf(acc[mi][ni][1]),
                        f2bf(acc[mi][ni][2]), f2bf(acc[mi][ni][3]));
                    *reinterpret_cast<ushort4*>(
                        &VtOut[((size_t)(bb * 16 + hh) * 64 + dd) * 1024 + jr]) = pk;
                }
            }
        }
    } else {
#pragma unroll
        for (int mi = 0; mi < 4; ++mi) {
            const int row = m0 + wr * 64 + mi * 16 + (l >> 4) * 4;
#pragma unroll
            for (int ni = 0; ni < 4; ++ni) {
                const int col = n0 + wc * 64 + ni * 16 + lr;
                const float bv = bias ? bias[col] : 0.f;
#pragma unroll
                for (int j = 0; j < 4; ++j) {
                    float v = acc[mi][ni][j] + bv;
                    if (relu) v = fmaxf(v, 0.f);
                    const size_t idx = (size_t)(row + j) * N + col;
                    if (Cf) Cf[idx] = v;
                    if (Cb) Cb[idx] = f2bf(v);
                }
            }
        }
    }
}

// ---------------------------------------------------------------------------
// bf16 MFMA GEMM for the grid-starved N=1024 shapes: 64x128 tile, BK=64,
// 3-buffer counted-vmcnt pipeline, 4 waves (2x2, each 32x64).
// LDS = 3 x (8KB A + 16KB B) = 72 KB -> 2 blocks/CU; grid = (N/128)x(M/64)
// = 512 blocks = 2 blocks/CU -> inter-block latency overlap (m114).
// ---------------------------------------------------------------------------
__global__ __launch_bounds__(256) void gemm_k64b_kernel(
    const USHORT* __restrict__ A, const USHORT* __restrict__ Bt,
    float* __restrict__ Cf, USHORT* __restrict__ Cb,
    int M, int N, int K, const float* __restrict__ bias, int relu)
{
    __shared__ USHORT As[3][64 * 64];     // [64 m][64 k], row&7 swizzle
    __shared__ USHORT Bs[3][128 * 64];    // [128 n][64 k], row&7 swizzle

    const int tid = threadIdx.x;
    const int l   = tid & 63;
    const int w   = tid >> 6;
    const int wr  = w >> 1, wc = w & 1;   // wave tile: 32(m) x 64(n)
    const int lr  = l & 15, lg = l >> 4;

    const int gx  = gridDim.x;
    const int nwg = gx * gridDim.y;
    const int lin = blockIdx.y * gx + blockIdx.x;
    const int swz = (lin & 7) * (nwg >> 3) + (lin >> 3);
    const int m0  = (swz / gx) * 64, n0 = (swz % gx) * 128;

    // A staging: 512 units (2 per thread); B staging: 1024 units (4 per thread)
    const int ar0 = tid >> 3,         ac0 = ((tid & 7) ^ (ar0 & 7)) << 3;
    const int ar1 = (256 + tid) >> 3, ac1 = (((256 + tid) & 7) ^ (ar1 & 7)) << 3;
    const USHORT* aS0 = A + (size_t)(m0 + ar0) * K + ac0;
    const USHORT* aS1 = A + (size_t)(m0 + ar1) * K + ac1;
    const int adOf0 = (w * 64) * 8;
    const int adOf1 = (256 + w * 64) * 8;

    const USHORT* bS[4]; int bdOf[4];
#pragma unroll
    for (int p = 0; p < 4; ++p) {
        const int q = p * 256 + tid;
        const int row = q >> 3, cu = q & 7;
        bS[p] = Bt + (size_t)(n0 + row) * K + ((cu ^ (row & 7)) << 3);
        bdOf[p] = (p * 256 + w * 64) * 8;
    }

    auto stage = [&](int buf, int k0) {   // 6 GLDS per thread per tile
        GLDS(aS0 + k0, &As[buf][adOf0]);
        GLDS(aS1 + k0, &As[buf][adOf1]);
#pragma unroll
        for (int p = 0; p < 4; ++p)
            GLDS(bS[p] + k0, &Bs[buf][bdOf[p]]);
    };

    f32x4 acc[2][4];
#pragma unroll
    for (int i = 0; i < 2; ++i)
#pragma unroll
        for (int j = 0; j < 4; ++j) acc[i][j] = (f32x4){0.f, 0.f, 0.f, 0.f};

    const int nk = K >> 6;
    stage(0, 0);
    if (nk > 1) stage(1, 64);

    for (int t = 0; t < nk; ++t) {
        const int cur = t % 3;
        if (t + 1 < nk) { WAITVM(6); } else { WAITVM(0); }   // tile t landed
        __builtin_amdgcn_s_barrier();
        if (t + 2 < nk) stage((t + 2) % 3, (t + 2) << 6);

#pragma unroll
        for (int ks = 0; ks < 2; ++ks) {
            short8v af[2], bfr[4];
#pragma unroll
            for (int mi = 0; mi < 2; ++mi)
                af[mi] = ld_frag(As[cur], wr * 32 + mi * 16 + lr, ks * 4 + lg);
#pragma unroll
            for (int ni = 0; ni < 4; ++ni)
                bfr[ni] = ld_frag(Bs[cur], wc * 64 + ni * 16 + lr, ks * 4 + lg);
            __builtin_amdgcn_s_setprio(1);
#pragma unroll
            for (int mi = 0; mi < 2; ++mi)
#pragma unroll
                for (int ni = 0; ni < 4; ++ni)
                    acc[mi][ni] = __builtin_amdgcn_mfma_f32_16x16x32_bf16(
                        af[mi], bfr[ni], acc[mi][ni], 0, 0, 0);
            __builtin_amdgcn_s_setprio(0);
        }
    }

#pragma unroll
    for (int mi = 0; mi < 2; ++mi) {
        const int row = m0 + wr * 32 + mi * 16 + (l >> 4) * 4;
#pragma unroll
        for (int ni = 0; ni < 4; ++ni) {
            const int col = n0 + wc * 64 + ni * 16 + lr;
            const float bv = bias ? bias[col] : 0.f;
#pragma unroll
            for (int j = 0; j < 4; ++j) {
                float v = acc[mi][ni][j] + bv;
                if (relu) v = fmaxf(v, 0.f);
                const size_t idx = (size_t)(row + j) * N + col;
                if (Cf) Cf[idx] = v;
                if (Cb) Cb[idx] = f2bf(v);
            }
        }
    }
}

// ---------------------------------------------------------------------------
// Weight convert+transpose kernels (unchanged).
// ---------------------------------------------------------------------------
struct TcvtB4 {
    const float* s0; const float* s1; const float* s2; const float* s3;
    USHORT* d0; USHORT* d1; USHORT* d2; USHORT* d3;
};

__device__ __forceinline__ void tcvt_body(
    const float* __restrict__ W, USHORT* __restrict__ Wt, int K, int N)
{
    __shared__ USHORT L[64][65];
    const int tid = threadIdx.x;
    const int tx = tid & 15, ty = tid >> 4;
    const int n0 = blockIdx.x * 64, k0 = blockIdx.y * 64;
#pragma unroll
    for (int r = 0; r < 4; ++r) {
        int kr = ty + 16 * r;
        float4 v = *reinterpret_cast<const float4*>(
            &W[(size_t)(k0 + kr) * N + n0 + tx * 4]);
        L[tx * 4 + 0][kr] = f2bf(v.x);
        L[tx * 4 + 1][kr] = f2bf(v.y);
        L[tx * 4 + 2][kr] = f2bf(v.z);
        L[tx * 4 + 3][kr] = f2bf(v.w);
    }
    __syncthreads();
#pragma unroll
    for (int r = 0; r < 4; ++r) {
        int nr = ty + 16 * r;
        ushort4 o = make_ushort4(L[nr][tx * 4 + 0], L[nr][tx * 4 + 1],
                                 L[nr][tx * 4 + 2], L[nr][tx * 4 + 3]);
        *reinterpret_cast<ushort4*>(&Wt[(size_t)(n0 + nr) * K + k0 + tx * 4]) = o;
    }
}

__global__ __launch_bounds__(256) void tcvt_kernel(
    const float* __restrict__ W, USHORT* __restrict__ Wt, int K, int N)
{
    tcvt_body(W, Wt, K, N);
}

__global__ __launch_bounds__(256) void tcvt4_kernel(TcvtB4 p, int K, int N)
{
    const int z = blockIdx.z;
    const float* W = (z == 0) ? p.s0 : (z == 1) ? p.s1 : (z == 2) ? p.s2 : p.s3;
    USHORT*    Wt = (z == 0) ? p.d0 : (z == 1) ? p.d1 : (z == 2) ? p.d2 : p.d3;
    tcvt_body(W, Wt, K, N);
}

__global__ __launch_bounds__(256) void f2b_kernel(
    const float* __restrict__ in, USHORT* __restrict__ out, int n4)
{
    int i = blockIdx.x * 256 + threadIdx.x;
    if (i < n4) {
        float4 v = reinterpret_cast<const float4*>(in)[i];
        reinterpret_cast<ushort4*>(out)[i] =
            make_ushort4(f2bf(v.x), f2bf(v.y), f2bf(v.z), f2bf(v.w));
    }
}

// ---------------------------------------------------------------------------
// MFMA flash attention, KVBLK=128, dbuf K/V, Q/P LDS union, defer-max (THR=8),
// setprio around MFMA clusters. Q arrives pre-scaled by 1/sqrt(DH).
// (unchanged from R9)
// ---------------------------------------------------------------------------
__global__ __launch_bounds__(256) void attn_mfma_kernel(
    const USHORT* __restrict__ Q, const USHORT* __restrict__ K,
    const USHORT* __restrict__ Vt, USHORT* __restrict__ O, int causal)
{
    __shared__ USHORT smem[40960];                 // 80 KB

    const int tid = threadIdx.x;
    const int l  = tid & 63;
    const int w  = tid >> 6;
    const int lr = l & 15;
    const int lg = l >> 4;

    const int lin = blockIdx.y * 16 + blockIdx.x;   // nwg = 1024
    const int swz = (lin & 7) * 128 + (lin >> 3);
    const int qt = swz & 15;
    const int bh = swz >> 4;
    const int h = bh & 15, b = bh >> 4;
    const int q0 = qt * 64;

    const USHORT* gq  = Q  + (size_t)(b * SEQ + q0) * D_MODEL + h * DH;
    const USHORT* gk0 = K  + (size_t)b * SEQ * D_MODEL + h * DH;
    const USHORT* gv0 = Vt + (size_t)bh * DH * SEQ;

    auto stageK = [&](int buf, int kt) {           // 128x64, row&7 swizzle
        USHORT* dst = smem + buf * 8192;
        const size_t base = (size_t)kt * 128 * 1024;
#pragma unroll
        for (int p = 0; p < 4; ++p) {
            const int q = p * 256 + tid;
            const int row = q >> 3, cu = q & 7;
            GLDS(gk0 + base + (size_t)row * 1024 + ((cu ^ (row & 7)) << 3),
                 dst + (p * 256 + w * 64) * 8);
        }
    };
    auto stageV = [&](int buf, int kt) {           // 64x128, row&15 swizzle
        USHORT* dst = smem + 16384 + buf * 8192;
        const int j0 = kt * 128;
#pragma unroll
        for (int p = 0; p < 4; ++p) {
            const int q = p * 256 + tid;
            const int row = q >> 4, cu = q & 15;
            GLDS(gv0 + (size_t)row * 1024 + j0 + ((cu ^ (row & 15)) << 3),
                 dst + (p * 256 + w * 64) * 8);
        }
    };

    // stage Q (64x64, row&7 swizzle) + first K/V tile
#pragma unroll
    for (int p = 0; p < 2; ++p) {
        const int q = p * 256 + tid;
        const int row = q >> 3, cu = q & 7;
        GLDS(gq + (size_t)row * 1024 + ((cu ^ (row & 7)) << 3),
             smem + 32768 + (p * 256 + w * 64) * 8);
    }
    stageK(0, 0);
    stageV(0, 0);

    f32x4 oacc[4];
    float m_[4], l_[4];
#pragma unroll
    for (int r = 0; r < 4; ++r) { m_[r] = -1e30f; l_[r] = 0.f; }
#pragma unroll
    for (int d = 0; d < 4; ++d) oacc[d] = (f32x4){0.f, 0.f, 0.f, 0.f};

    __syncthreads();                               // Q + tile 0 staged
    short8v qa0 = ld_frag(smem + 32768, w * 16 + lr, lg);
    short8v qa1 = ld_frag(smem + 32768, w * 16 + lr, 4 + lg);
    __syncthreads();                               // Q consumed -> Ps may reuse
    USHORT* PsW = smem + 32768 + w * 2048;         // per-wave P [16 q][128 j]

    const int ntile = causal ? (qt >> 1) + 1 : (SEQ / 128);
    for (int kt = 0; kt < ntile; ++kt) {
        const int cur = kt & 1;
        if (kt + 1 < ntile) {                      // prefetch next K/V tile
            stageK(cur ^ 1, kt + 1);
            stageV(cur ^ 1, kt + 1);
        }
        const int j0 = kt * 128;
        const USHORT* KsC = smem + cur * 8192;
        const USHORT* VsC = smem + 16384 + cur * 8192;

        // S = Q K^T  (Q pre-scaled)
        f32x4 sa[8];
        __builtin_amdgcn_s_setprio(1);
#pragma unroll
        for (int jb = 0; jb < 8; ++jb) {
            sa[jb] = (f32x4){0.f, 0.f, 0.f, 0.f};
            sa[jb] = __builtin_amdgcn_mfma_f32_16x16x32_bf16(
                qa0, ld_frag(KsC, jb * 16 + lr, lg), sa[jb], 0, 0, 0);
            sa[jb] = __builtin_amdgcn_mfma_f32_16x16x32_bf16(
                qa1, ld_frag(KsC, jb * 16 + lr, 4 + lg), sa[jb], 0, 0, 0);
        }
        __builtin_amdgcn_s_setprio(0);

        // causal mask: only the last tile can cross the diagonal
        if (causal && kt == ntile - 1) {
#pragma unroll
            for (int jb = 0; jb < 8; ++jb)
#pragma unroll
                for (int r = 0; r < 4; ++r)
                    if ((j0 + jb * 16 + lr) > (q0 + w * 16 + lg * 4 + r))
                        sa[jb][r] = -1e30f;
        }

        // online softmax with defer-max (state replicated across 16-lane group)
#pragma unroll
        for (int r = 0; r < 4; ++r) {
            float tm = fmaxf(fmaxf(fmaxf(sa[0][r], sa[1][r]),
                                   fmaxf(sa[2][r], sa[3][r])),
                             fmaxf(fmaxf(sa[4][r], sa[5][r]),
                                   fmaxf(sa[6][r], sa[7][r])));
            tm = fmaxf(tm, __shfl_xor(tm, 1));
            tm = fmaxf(tm, __shfl_xor(tm, 2));
            tm = fmaxf(tm, __shfl_xor(tm, 4));
            tm = fmaxf(tm, __shfl_xor(tm, 8));
            if (tm > m_[r] + 8.f) {                // significant growth only
                float sc = __expf(m_[r] - tm);
                l_[r] *= sc;
#pragma unroll
                for (int d = 0; d < 4; ++d) oacc[d][r] *= sc;
                m_[r] = tm;
            }
            float rs_ = 0.f;
#pragma unroll
            for (int jb = 0; jb < 8; ++jb) {
                float p = __expf(sa[jb][r] - m_[r]);
                sa[jb][r] = p;
                rs_ += p;
            }
            rs_ += __shfl_xor(rs_, 1);
            rs_ += __shfl_xor(rs_, 2);
            rs_ += __shfl_xor(rs_, 4);
            rs_ += __shfl_xor(rs_, 8);
            l_[r] += rs_;
        }

        // P -> per-wave swizzled LDS (bf16), [16 q][128 j], unit ^= row&15
#pragma unroll
        for (int jb = 0; jb < 8; ++jb) {
            const int cu = jb * 2 + (lr >> 3), cl = lr & 7;
#pragma unroll
            for (int r = 0; r < 4; ++r) {
                const int row = lg * 4 + r;
                PsW[row * 128 + ((cu ^ (row & 15)) << 3) + cl] = f2bf(sa[jb][r]);
            }
        }

        // PV: oacc[d] += P(16q x 32j) * V(32j x 16d), 4 j-slots x 4 d-blocks
        __builtin_amdgcn_s_setprio(1);
#pragma unroll
        for (int ks = 0; ks < 4; ++ks) {
            short8v pa = ld128(PsW, lr, ks * 4 + lg);
#pragma unroll
            for (int d = 0; d < 4; ++d)
                oacc[d] = __builtin_amdgcn_mfma_f32_16x16x32_bf16(
                    pa, ld128(VsC, d * 16 + lr, ks * 4 + lg), oacc[d], 0, 0, 0);
        }
        __builtin_amdgcn_s_setprio(0);
        __syncthreads();   // drains prefetch + guards K/V/P buffer reuse
    }

    USHORT* go = O + (size_t)(b * SEQ + q0 + w * 16) * D_MODEL + h * DH;
#pragma unroll
    for (int r = 0; r < 4; ++r) {
        const float inv = 1.f / l_[r];
        const int qrow = lg * 4 + r;
#pragma unroll
        for (int d = 0; d < 4; ++d)
            go[(size_t)qrow * D_MODEL + d * 16 + lr] = f2bf(oacc[d][r] * inv);
    }
}

// ---------------------------------------------------------------------------
// out = res + LayerNorm(x)*g + b.  x bf16; res fp32 (resf) or bf16 (resb).
// ---------------------------------------------------------------------------
__global__ __launch_bounds__(256) void ln_res_kernel(
    const USHORT* __restrict__ xb, const float* __restrict__ resf,
    const USHORT* __restrict__ resb,
    const float* __restrict__ g, const float* __restrict__ bta,
    float* __restrict__ outf, USHORT* __restrict__ outb)
{
    __shared__ float red[256];
    __shared__ float s_mu, s_rstd;

    const int row = blockIdx.x;
    const int tid = threadIdx.x;
    ushort4 xv = reinterpret_cast<const ushort4*>(xb + (size_t)row * D_MODEL)[tid];
    float vx = bf2f(xv.x), vy = bf2f(xv.y), vz = bf2f(xv.z), vw = bf2f(xv.w);

    red[tid] = vx + vy + vz + vw;
    __syncthreads();
    for (int s = 128; s > 0; s >>= 1) {
        if (tid < s) red[tid] += red[tid + s];
        __syncthreads();
    }
    if (tid == 0) s_mu = red[0] * (1.f / D_MODEL);
    __syncthreads();
    const float mu = s_mu;

    float dx = vx - mu, dy = vy - mu, dz = vz - mu, dw = vw - mu;
    red[tid] = dx * dx + dy * dy + dz * dz + dw * dw;
    __syncthreads();
    for (int s = 128; s > 0; s >>= 1) {
        if (tid < s) red[tid] += red[tid + s];
        __syncthreads();
    }
    if (tid == 0) s_rstd = rsqrtf(red[0] * (1.f / D_MODEL) + EPS);
    __syncthreads();
    const float rstd = s_rstd;

    float4 rv;
    if (resf) {
        rv = reinterpret_cast<const float4*>(resf + (size_t)row * D_MODEL)[tid];
    } else {
        ushort4 rb = reinterpret_cast<const ushort4*>(
            resb + (size_t)row * D_MODEL)[tid];
        rv = make_float4(bf2f(rb.x), bf2f(rb.y), bf2f(rb.z), bf2f(rb.w));
    }
    float4 gv = reinterpret_cast<const float4*>(g)[tid];
    float4 bv = reinterpret_cast<const float4*>(bta)[tid];

    float4 o;
    o.x = rv.x + dx * rstd * gv.x + bv.x;
    o.y = rv.y + dy * rstd * gv.y + bv.y;
    o.z = rv.z + dz * rstd * gv.z + bv.z;
    o.w = rv.w + dw * rstd * gv.w + bv.w;
    reinterpret_cast<float4*>(outf + (size_t)row * D_MODEL)[tid] = o;
    if (outb)
        reinterpret_cast<ushort4*>(outb + (size_t)row * D_MODEL)[tid] =
            make_ushort4(f2bf(o.x), f2bf(o.y), f2bf(o.z), f2bf(o.w));
}

// ---------------------------------------------------------------------------
extern "C" void kernel_launch(void* const* d_in, const int* in_sizes, int n_in,
                              void* d_out, int out_size, void* d_ws, size_t ws_size,
                              hipStream_t stream)
{
    const float* X    = (const float*)d_in[0];
    const float* Wq1  = (const float*)d_in[1];
    const float* Wk1  = (const float*)d_in[2];
    const float* Wv1  = (const float*)d_in[3];
    const float* Wo1  = (const float*)d_in[4];
    const float* Wq2  = (const float*)d_in[5];
    const float* Wk2  = (const float*)d_in[6];
    const float* Wv2  = (const float*)d_in[7];
    const float* Wo2  = (const float*)d_in[8];
    const float* ln_g = (const float*)d_in[9];
    const float* ln_b = (const float*)d_in[10];
    const float* W1   = (const float*)d_in[11];
    const float* b1   = (const float*)d_in[12];
    const float* W2   = (const float*)d_in[13];
    const float* b2   = (const float*)d_in[14];

    const size_t MI = 1024 * 1024;
    USHORT* ws16 = (USHORT*)d_ws;
    USHORT* Wqkv1t = ws16;
    USHORT* Wo1t   = ws16 + 3 * MI;
    USHORT* Wqkv2t = ws16 + 4 * MI;
    USHORT* Wo2t   = ws16 + 7 * MI;
    USHORT* W2t    = ws16 + 8 * MI;
    USHORT* Xb     = ws16 + 12 * MI;
    USHORT* W1t    = Xb;
    USHORT* qb     = ws16 + 16 * MI;
    USHORT* kb     = ws16 + 20 * MI;
    USHORT* Vtb    = ws16 + 24 * MI;
    USHORT* t0b    = ws16 + 28 * MI;
    USHORT* hb     = qb;
    USHORT* t2b    = ws16 + 32 * MI;
    USHORT* t1b    = ws16 + 36 * MI;
    float*  t2     = (float*)(ws16 + 40 * MI);

    auto gemm32 = [&](const USHORT* A, const USHORT* Bt, float* Cf, USHORT* Cb,
                      int M, int N, int K, const float* bias, int relu) {
        gemm_k32_kernel<<<dim3(N / 128, M / 128), 256, 0, stream>>>(
            A, Bt, Cf, Cb, nullptr, nullptr, M, N, K, bias, relu, 0);
    };
    auto gemm_qkv = [&](const USHORT* A, const USHORT* Bt) {
        gemm_k32_kernel<<<dim3(3072 / 128, TOK / 128), 256, 0, stream>>>(
            A, Bt, nullptr, qb, kb, Vtb, TOK, 3072, D_MODEL, nullptr, 0, 1);
    };
    auto gemm64b = [&](const USHORT* A, const USHORT* Bt, float* Cf, USHORT* Cb,
                       int M, int N, int K, const float* bias, int relu) {
        gemm_k64b_kernel<<<dim3(N / 128, M / 64), 256, 0, stream>>>(
            A, Bt, Cf, Cb, M, N, K, bias, relu);
    };

    dim3 agrid(SEQ / 64, BATCH * N_HEADS);

    // ---- prologue: all square weights + W2 + X -> bf16 ----
    {
        TcvtB4 p1{Wq1, Wk1, Wv1, Wo1,
                  Wqkv1t, Wqkv1t + 1 * MI, Wqkv1t + 2 * MI, Wo1t};
        tcvt4_kernel<<<dim3(16, 16, 4), 256, 0, stream>>>(p1, D_MODEL, D_MODEL);
        TcvtB4 p2{Wq2, Wk2, Wv2, Wo2,
                  Wqkv2t, Wqkv2t + 1 * MI, Wqkv2t + 2 * MI, Wo2t};
        tcvt4_kernel<<<dim3(16, 16, 4), 256, 0, stream>>>(p2, D_MODEL, D_MODEL);
    }
    tcvt_kernel<<<dim3(D_MODEL / 64, D_FF / 64), 256, 0, stream>>>(
        W2, W2t, D_FF, D_MODEL);
    f2b_kernel<<<dim3(4096), 256, 0, stream>>>(X, Xb, TOK * D_MODEL / 4);

    // ---- MHA 1 (causal) ----
    gemm_qkv(Xb, Wqkv1t);
    attn_mfma_kernel<<<agrid, 256, 0, stream>>>(qb, kb, Vtb, t0b, 1);
    gemm64b(t0b, Wo1t, nullptr, t1b, TOK, D_MODEL, D_MODEL, nullptr, 0);
    ln_res_kernel<<<dim3(TOK), 256, 0, stream>>>(t1b, X, nullptr,
                                                 ln_g, ln_b, t2, t2b);
    tcvt_kernel<<<dim3(D_FF / 64, D_MODEL / 64), 256, 0, stream>>>(
        W1, W1t, D_MODEL, D_FF);

    // ---- MHA 2 (full) ----
    gemm_qkv(t2b, Wqkv2t);
    attn_mfma_kernel<<<agrid, 256, 0, stream>>>(qb, kb, Vtb, t0b, 0);
    gemm64b(t0b, Wo2t, nullptr, t1b, TOK, D_MODEL, D_MODEL, nullptr, 0);
    ln_res_kernel<<<dim3(TOK), 256, 0, stream>>>(t1b, nullptr, t1b,
                                                 ln_g, ln_b, t2, t2b);

    // ---- FFN ----
    gemm32(t2b, W1t, nullptr, hb, TOK, D_FF, D_MODEL, b1, 1);
    gemm64b(hb, W2t, nullptr, t1b, TOK, D_MODEL, D_FF, b2, 0);
    ln_res_kernel<<<dim3(TOK), 256, 0, stream>>>(t1b, t2, nullptr,
                                                 ln_g, ln_b, (float*)d_out, nullptr);
}

// Round 11
// 382.422 us; speedup vs baseline: 27.4782x; 1.0111x over previous
//
#include <hip/hip_runtime.h>
#include <hip/hip_bf16.h>

#define D_MODEL 1024
#define N_HEADS 16
#define DH 64
#define D_FF   4096
#define SEQ    1024
#define BATCH  4
#define TOK    (BATCH*SEQ)
#define EPS    1e-5f
#define SCALE  0.125f   // 1/sqrt(64)

typedef unsigned short USHORT;
typedef __attribute__((ext_vector_type(8))) short short8v;
typedef __attribute__((ext_vector_type(4))) float f32x4;

__device__ __forceinline__ USHORT f2bf(float f) {
    unsigned int u; __builtin_memcpy(&u, &f, 4);
    u += 0x7fffu + ((u >> 16) & 1u);          // RNE
    return (USHORT)(u >> 16);
}
__device__ __forceinline__ float bf2f(USHORT s) {
    unsigned int u = ((unsigned int)s) << 16;
    float f; __builtin_memcpy(&f, &u, 4);
    return f;
}

// row-stride-64 swizzled read: unit ^= row&7
__device__ __forceinline__ short8v ld_frag(const USHORT* lds, int row, int c8) {
    return *reinterpret_cast<const short8v*>(
        &lds[row * 64 + (((c8) ^ (row & 7)) << 3)]);
}
// row-stride-128 swizzled read (attn V/P tiles): unit ^= row&15
__device__ __forceinline__ short8v ld128(const USHORT* lds, int row, int cu) {
    return *reinterpret_cast<const short8v*>(
        &lds[row * 128 + (((cu) ^ (row & 15)) << 3)]);
}

#define GLDS(gsrc, ldst) \
    __builtin_amdgcn_global_load_lds( \
        (const __attribute__((address_space(1))) void*)(gsrc), \
        (__attribute__((address_space(3))) void*)(ldst), 16, 0, 0)

#define WAITVM(n) asm volatile("s_waitcnt vmcnt(" #n ")" ::: "memory")

// ---------------------------------------------------------------------------
// bf16 MFMA GEMM, 256x256 tile, BK=64, 512 threads = 8 waves (2M x 4N; each
// wave 128x64 output). 2-buffer counted-vmcnt pipeline: issue next tile's 8
// global_load_lds BEFORE WAITVM(8)+barrier (loads span the whole MFMA phase;
// never drain to 0 mid-loop). LDS 2 x (32KB A + 32KB B) = 128 KB, row&7 XOR
// swizzle (source-side inverse). Halves staged bytes/FLOP vs the 128^2 tile
// (BM*BN/(BM+BN): 64 -> 128). Epilogues: normal or fused-QKV routing.
// ---------------------------------------------------------------------------
__global__ __launch_bounds__(512) void gemm_k256_kernel(
    const USHORT* __restrict__ A, const USHORT* __restrict__ Bt,
    float* __restrict__ Cf, USHORT* __restrict__ Cb, USHORT* __restrict__ Ck,
    USHORT* __restrict__ VtOut,
    int M, int N, int K, const float* __restrict__ bias, int relu, int qkv)
{
    __shared__ USHORT As[2][256 * 64];
    __shared__ USHORT Bs[2][256 * 64];

    const int tid = threadIdx.x;
    const int l   = tid & 63;
    const int w   = tid >> 6;              // 0..7
    const int wr  = w >> 2, wc = w & 3;    // 2 x 4 wave grid
    const int lr  = l & 15, lg = l >> 4;

    const int gx  = gridDim.x;
    const int nwg = gx * gridDim.y;
    const int lin = blockIdx.y * gx + blockIdx.x;
    const int swz = (lin & 7) * (nwg >> 3) + (lin >> 3);
    const int m0  = (swz / gx) * 256, n0 = (swz % gx) * 256;

    // staging: 2048 16B-units per matrix; thread covers q = p*512 + tid, p=0..3
    const USHORT* aS[4]; const USHORT* bS[4]; int dOf[4];
#pragma unroll
    for (int p = 0; p < 4; ++p) {
        const int q = p * 512 + tid;
        const int row = q >> 3, cu = q & 7;
        const int cs = ((cu ^ (row & 7)) << 3);
        aS[p] = A  + (size_t)(m0 + row) * K + cs;
        bS[p] = Bt + (size_t)(n0 + row) * K + cs;
        dOf[p] = (p * 512 + w * 64) * 8;
    }

    auto stage = [&](int buf, int k0) {    // 8 GLDS per thread per tile
#pragma unroll
        for (int p = 0; p < 4; ++p) {
            GLDS(aS[p] + k0, &As[buf][dOf[p]]);
            GLDS(bS[p] + k0, &Bs[buf][dOf[p]]);
        }
    };

    f32x4 acc[8][4];
#pragma unroll
    for (int i = 0; i < 8; ++i)
#pragma unroll
        for (int j = 0; j < 4; ++j) acc[i][j] = (f32x4){0.f, 0.f, 0.f, 0.f};

    const int nk = K >> 6;
    stage(0, 0);

    for (int t = 0; t < nk; ++t) {
        const int cur = t & 1;
        if (t + 1 < nk) {
            stage(cur ^ 1, (t + 1) << 6);  // issue early: full MFMA phase to land
            WAITVM(8);                     // tile t complete; t+1 stays in flight
        } else {
            WAITVM(0);
        }
        __builtin_amdgcn_s_barrier();      // all waves' tile-t loads done

#pragma unroll
        for (int ks = 0; ks < 2; ++ks) {
            short8v bfr[4];
#pragma unroll
            for (int ni = 0; ni < 4; ++ni)
                bfr[ni] = ld_frag(Bs[cur], wc * 64 + ni * 16 + lr, ks * 4 + lg);
            __builtin_amdgcn_s_setprio(1);
#pragma unroll
            for (int mi = 0; mi < 8; ++mi) {
                short8v af = ld_frag(As[cur], wr * 128 + mi * 16 + lr, ks * 4 + lg);
#pragma unroll
                for (int ni = 0; ni < 4; ++ni)
                    acc[mi][ni] = __builtin_amdgcn_mfma_f32_16x16x32_bf16(
                        af, bfr[ni], acc[mi][ni], 0, 0, 0);
            }
            __builtin_amdgcn_s_setprio(0);
        }
        __builtin_amdgcn_s_barrier();      // all waves done reading buf cur
    }

    // epilogue: C/D layout col = lane&15, row = (lane>>4)*4 + reg
    if (qkv) {
#pragma unroll
        for (int mi = 0; mi < 8; ++mi) {
            const int row = m0 + wr * 128 + mi * 16 + (l >> 4) * 4;
#pragma unroll
            for (int ni = 0; ni < 4; ++ni) {
                const int col = n0 + wc * 64 + ni * 16 + lr;
                if (col < 2048) {
                    USHORT* dst = (col < 1024) ? Cb : Ck;
                    const float scl = (col < 1024) ? SCALE : 1.f;  // pre-scale Q
                    const int c = col & 1023;
#pragma unroll
                    for (int j = 0; j < 4; ++j)
                        dst[(size_t)(row + j) * D_MODEL + c] =
                            f2bf(acc[mi][ni][j] * scl);
                } else {
                    const int c = col - 2048;
                    const int bb = row >> 10, jr = row & 1023;
                    const int hh = c >> 6, dd = c & 63;
                    ushort4 pk = make_ushort4(
                        f2bf(acc[mi][ni][0]), f2bf(acc[mi][ni][1]),
                        f2bf(acc[mi][ni][2]), f2bf(acc[mi][ni][3]));
                    *reinterpret_cast<ushort4*>(
                        &VtOut[((size_t)(bb * 16 + hh) * 64 + dd) * 1024 + jr]) = pk;
                }
            }
        }
    } else {
#pragma unroll
        for (int mi = 0; mi < 8; ++mi) {
            const int row = m0 + wr * 128 + mi * 16 + (l >> 4) * 4;
#pragma unroll
            for (int ni = 0; ni < 4; ++ni) {
                const int col = n0 + wc * 64 + ni * 16 + lr;
                const float bv = bias ? bias[col] : 0.f;
#pragma unroll
                for (int j = 0; j < 4; ++j) {
                    float v = acc[mi][ni][j] + bv;
                    if (relu) v = fmaxf(v, 0.f);
                    const size_t idx = (size_t)(row + j) * N + col;
                    if (Cf) Cf[idx] = v;
                    if (Cb) Cb[idx] = f2bf(v);
                }
            }
        }
    }
}

// ---------------------------------------------------------------------------
// bf16 MFMA GEMM for the grid-starved N=1024 shapes: 64x128 tile, BK=64,
// 3-buffer counted-vmcnt pipeline, 4 waves (2x2, each 32x64). (unchanged)
// ---------------------------------------------------------------------------
__global__ __launch_bounds__(256) void gemm_k64b_kernel(
    const USHORT* __restrict__ A, const USHORT* __restrict__ Bt,
    float* __restrict__ Cf, USHORT* __restrict__ Cb,
    int M, int N, int K, const float* __restrict__ bias, int relu)
{
    __shared__ USHORT As[3][64 * 64];     // [64 m][64 k], row&7 swizzle
    __shared__ USHORT Bs[3][128 * 64];    // [128 n][64 k], row&7 swizzle

    const int tid = threadIdx.x;
    const int l   = tid & 63;
    const int w   = tid >> 6;
    const int wr  = w >> 1, wc = w & 1;   // wave tile: 32(m) x 64(n)
    const int lr  = l & 15, lg = l >> 4;

    const int gx  = gridDim.x;
    const int nwg = gx * gridDim.y;
    const int lin = blockIdx.y * gx + blockIdx.x;
    const int swz = (lin & 7) * (nwg >> 3) + (lin >> 3);
    const int m0  = (swz / gx) * 64, n0 = (swz % gx) * 128;

    const int ar0 = tid >> 3,         ac0 = ((tid & 7) ^ (ar0 & 7)) << 3;
    const int ar1 = (256 + tid) >> 3, ac1 = (((256 + tid) & 7) ^ (ar1 & 7)) << 3;
    const USHORT* aS0 = A + (size_t)(m0 + ar0) * K + ac0;
    const USHORT* aS1 = A + (size_t)(m0 + ar1) * K + ac1;
    const int adOf0 = (w * 64) * 8;
    const int adOf1 = (256 + w * 64) * 8;

    const USHORT* bS[4]; int bdOf[4];
#pragma unroll
    for (int p = 0; p < 4; ++p) {
        const int q = p * 256 + tid;
        const int row = q >> 3, cu = q & 7;
        bS[p] = Bt + (size_t)(n0 + row) * K + ((cu ^ (row & 7)) << 3);
        bdOf[p] = (p * 256 + w * 64) * 8;
    }

    auto stage = [&](int buf, int k0) {   // 6 GLDS per thread per tile
        GLDS(aS0 + k0, &As[buf][adOf0]);
        GLDS(aS1 + k0, &As[buf][adOf1]);
#pragma unroll
        for (int p = 0; p < 4; ++p)
            GLDS(bS[p] + k0, &Bs[buf][bdOf[p]]);
    };

    f32x4 acc[2][4];
#pragma unroll
    for (int i = 0; i < 2; ++i)
#pragma unroll
        for (int j = 0; j < 4; ++j) acc[i][j] = (f32x4){0.f, 0.f, 0.f, 0.f};

    const int nk = K >> 6;
    stage(0, 0);
    if (nk > 1) stage(1, 64);

    for (int t = 0; t < nk; ++t) {
        const int cur = t % 3;
        if (t + 1 < nk) { WAITVM(6); } else { WAITVM(0); }   // tile t landed
        __builtin_amdgcn_s_barrier();
        if (t + 2 < nk) stage((t + 2) % 3, (t + 2) << 6);

#pragma unroll
        for (int ks = 0; ks < 2; ++ks) {
            short8v af[2], bfr[4];
#pragma unroll
            for (int mi = 0; mi < 2; ++mi)
                af[mi] = ld_frag(As[cur], wr * 32 + mi * 16 + lr, ks * 4 + lg);
#pragma unroll
            for (int ni = 0; ni < 4; ++ni)
                bfr[ni] = ld_frag(Bs[cur], wc * 64 + ni * 16 + lr, ks * 4 + lg);
            __builtin_amdgcn_s_setprio(1);
#pragma unroll
            for (int mi = 0; mi < 2; ++mi)
#pragma unroll
                for (int ni = 0; ni < 4; ++ni)
                    acc[mi][ni] = __builtin_amdgcn_mfma_f32_16x16x32_bf16(
                        af[mi], bfr[ni], acc[mi][ni], 0, 0, 0);
            __builtin_amdgcn_s_setprio(0);
        }
    }

#pragma unroll
    for (int mi = 0; mi < 2; ++mi) {
        const int row = m0 + wr * 32 + mi * 16 + (l >> 4) * 4;
#pragma unroll
        for (int ni = 0; ni < 4; ++ni) {
            const int col = n0 + wc * 64 + ni * 16 + lr;
            const float bv = bias ? bias[col] : 0.f;
#pragma unroll
            for (int j = 0; j < 4; ++j) {
                float v = acc[mi][ni][j] + bv;
                if (relu) v = fmaxf(v, 0.f);
                const size_t idx = (size_t)(row + j) * N + col;
                if (Cf) Cf[idx] = v;
                if (Cb) Cb[idx] = f2bf(v);
            }
        }
    }
}

// ---------------------------------------------------------------------------
// Weight convert+transpose kernels (unchanged).
// ---------------------------------------------------------------------------
struct TcvtB4 {
    const float* s0; const float* s1; const float* s2; const float* s3;
    USHORT* d0; USHORT* d1; USHORT* d2; USHORT* d3;
};

__device__ __forceinline__ void tcvt_body(
    const float* __restrict__ W, USHORT* __restrict__ Wt, int K, int N)
{
    __shared__ USHORT L[64][65];
    const int tid = threadIdx.x;
    const int tx = tid & 15, ty = tid >> 4;
    const int n0 = blockIdx.x * 64, k0 = blockIdx.y * 64;
#pragma unroll
    for (int r = 0; r < 4; ++r) {
        int kr = ty + 16 * r;
        float4 v = *reinterpret_cast<const float4*>(
            &W[(size_t)(k0 + kr) * N + n0 + tx * 4]);
        L[tx * 4 + 0][kr] = f2bf(v.x);
        L[tx * 4 + 1][kr] = f2bf(v.y);
        L[tx * 4 + 2][kr] = f2bf(v.z);
        L[tx * 4 + 3][kr] = f2bf(v.w);
    }
    __syncthreads();
#pragma unroll
    for (int r = 0; r < 4; ++r) {
        int nr = ty + 16 * r;
        ushort4 o = make_ushort4(L[nr][tx * 4 + 0], L[nr][tx * 4 + 1],
                                 L[nr][tx * 4 + 2], L[nr][tx * 4 + 3]);
        *reinterpret_cast<ushort4*>(&Wt[(size_t)(n0 + nr) * K + k0 + tx * 4]) = o;
    }
}

__global__ __launch_bounds__(256) void tcvt_kernel(
    const float* __restrict__ W, USHORT* __restrict__ Wt, int K, int N)
{
    tcvt_body(W, Wt, K, N);
}

__global__ __launch_bounds__(256) void tcvt4_kernel(TcvtB4 p, int K, int N)
{
    const int z = blockIdx.z;
    const float* W = (z == 0) ? p.s0 : (z == 1) ? p.s1 : (z == 2) ? p.s2 : p.s3;
    USHORT*    Wt = (z == 0) ? p.d0 : (z == 1) ? p.d1 : (z == 2) ? p.d2 : p.d3;
    tcvt_body(W, Wt, K, N);
}

__global__ __launch_bounds__(256) void f2b_kernel(
    const float* __restrict__ in, USHORT* __restrict__ out, int n4)
{
    int i = blockIdx.x * 256 + threadIdx.x;
    if (i < n4) {
        float4 v = reinterpret_cast<const float4*>(in)[i];
        reinterpret_cast<ushort4*>(out)[i] =
            make_ushort4(f2bf(v.x), f2bf(v.y), f2bf(v.z), f2bf(v.w));
    }
}

// ---------------------------------------------------------------------------
// MFMA flash attention, KVBLK=128, dbuf K/V, Q/P LDS union, defer-max (THR=8),
// setprio around MFMA clusters. Q arrives pre-scaled by 1/sqrt(DH). (unchanged)
// ---------------------------------------------------------------------------
__global__ __launch_bounds__(256) void attn_mfma_kernel(
    const USHORT* __restrict__ Q, const USHORT* __restrict__ K,
    const USHORT* __restrict__ Vt, USHORT* __restrict__ O, int causal)
{
    __shared__ USHORT smem[40960];                 // 80 KB

    const int tid = threadIdx.x;
    const int l  = tid & 63;
    const int w  = tid >> 6;
    const int lr = l & 15;
    const int lg = l >> 4;

    const int lin = blockIdx.y * 16 + blockIdx.x;   // nwg = 1024
    const int swz = (lin & 7) * 128 + (lin >> 3);
    const int qt = swz & 15;
    const int bh = swz >> 4;
    const int h = bh & 15, b = bh >> 4;
    const int q0 = qt * 64;

    const USHORT* gq  = Q  + (size_t)(b * SEQ + q0) * D_MODEL + h * DH;
    const USHORT* gk0 = K  + (size_t)b * SEQ * D_MODEL + h * DH;
    const USHORT* gv0 = Vt + (size_t)bh * DH * SEQ;

    auto stageK = [&](int buf, int kt) {           // 128x64, row&7 swizzle
        USHORT* dst = smem + buf * 8192;
        const size_t base = (size_t)kt * 128 * 1024;
#pragma unroll
        for (int p = 0; p < 4; ++p) {
            const int q = p * 256 + tid;
            const int row = q >> 3, cu = q & 7;
            GLDS(gk0 + base + (size_t)row * 1024 + ((cu ^ (row & 7)) << 3),
                 dst + (p * 256 + w * 64) * 8);
        }
    };
    auto stageV = [&](int buf, int kt) {           // 64x128, row&15 swizzle
        USHORT* dst = smem + 16384 + buf * 8192;
        const int j0 = kt * 128;
#pragma unroll
        for (int p = 0; p < 4; ++p) {
            const int q = p * 256 + tid;
            const int row = q >> 4, cu = q & 15;
            GLDS(gv0 + (size_t)row * 1024 + j0 + ((cu ^ (row & 15)) << 3),
                 dst + (p * 256 + w * 64) * 8);
        }
    };

    // stage Q (64x64, row&7 swizzle) + first K/V tile
#pragma unroll
    for (int p = 0; p < 2; ++p) {
        const int q = p * 256 + tid;
        const int row = q >> 3, cu = q & 7;
        GLDS(gq + (size_t)row * 1024 + ((cu ^ (row & 7)) << 3),
             smem + 32768 + (p * 256 + w * 64) * 8);
    }
    stageK(0, 0);
    stageV(0, 0);

    f32x4 oacc[4];
    float m_[4], l_[4];
#pragma unroll
    for (int r = 0; r < 4; ++r) { m_[r] = -1e30f; l_[r] = 0.f; }
#pragma unroll
    for (int d = 0; d < 4; ++d) oacc[d] = (f32x4){0.f, 0.f, 0.f, 0.f};

    __syncthreads();                               // Q + tile 0 staged
    short8v qa0 = ld_frag(smem + 32768, w * 16 + lr, lg);
    short8v qa1 = ld_frag(smem + 32768, w * 16 + lr, 4 + lg);
    __syncthreads();                               // Q consumed -> Ps may reuse
    USHORT* PsW = smem + 32768 + w * 2048;         // per-wave P [16 q][128 j]

    const int ntile = causal ? (qt >> 1) + 1 : (SEQ / 128);
    for (int kt = 0; kt < ntile; ++kt) {
        const int cur = kt & 1;
        if (kt + 1 < ntile) {                      // prefetch next K/V tile
            stageK(cur ^ 1, kt + 1);
            stageV(cur ^ 1, kt + 1);
        }
        const int j0 = kt * 128;
        const USHORT* KsC = smem + cur * 8192;
        const USHORT* VsC = smem + 16384 + cur * 8192;

        // S = Q K^T  (Q pre-scaled)
        f32x4 sa[8];
        __builtin_amdgcn_s_setprio(1);
#pragma unroll
        for (int jb = 0; jb < 8; ++jb) {
            sa[jb] = (f32x4){0.f, 0.f, 0.f, 0.f};
            sa[jb] = __builtin_amdgcn_mfma_f32_16x16x32_bf16(
                qa0, ld_frag(KsC, jb * 16 + lr, lg), sa[jb], 0, 0, 0);
            sa[jb] = __builtin_amdgcn_mfma_f32_16x16x32_bf16(
                qa1, ld_frag(KsC, jb * 16 + lr, 4 + lg), sa[jb], 0, 0, 0);
        }
        __builtin_amdgcn_s_setprio(0);

        // causal mask: only the last tile can cross the diagonal
        if (causal && kt == ntile - 1) {
#pragma unroll
            for (int jb = 0; jb < 8; ++jb)
#pragma unroll
                for (int r = 0; r < 4; ++r)
                    if ((j0 + jb * 16 + lr) > (q0 + w * 16 + lg * 4 + r))
                        sa[jb][r] = -1e30f;
        }

        // online softmax with defer-max (state replicated across 16-lane group)
#pragma unroll
        for (int r = 0; r < 4; ++r) {
            float tm = fmaxf(fmaxf(fmaxf(sa[0][r], sa[1][r]),
                                   fmaxf(sa[2][r], sa[3][r])),
                             fmaxf(fmaxf(sa[4][r], sa[5][r]),
                                   fmaxf(sa[6][r], sa[7][r])));
            tm = fmaxf(tm, __shfl_xor(tm, 1));
            tm = fmaxf(tm, __shfl_xor(tm, 2));
            tm = fmaxf(tm, __shfl_xor(tm, 4));
            tm = fmaxf(tm, __shfl_xor(tm, 8));
            if (tm > m_[r] + 8.f) {                // significant growth only
                float sc = __expf(m_[r] - tm);
                l_[r] *= sc;
#pragma unroll
                for (int d = 0; d < 4; ++d) oacc[d][r] *= sc;
                m_[r] = tm;
            }
            float rs_ = 0.f;
#pragma unroll
            for (int jb = 0; jb < 8; ++jb) {
                float p = __expf(sa[jb][r] - m_[r]);
                sa[jb][r] = p;
                rs_ += p;
            }
            rs_ += __shfl_xor(rs_, 1);
            rs_ += __shfl_xor(rs_, 2);
            rs_ += __shfl_xor(rs_, 4);
            rs_ += __shfl_xor(rs_, 8);
            l_[r] += rs_;
        }

        // P -> per-wave swizzled LDS (bf16), [16 q][128 j], unit ^= row&15
#pragma unroll
        for (int jb = 0; jb < 8; ++jb) {
            const int cu = jb * 2 + (lr >> 3), cl = lr & 7;
#pragma unroll
            for (int r = 0; r < 4; ++r) {
                const int row = lg * 4 + r;
                PsW[row * 128 + ((cu ^ (row & 15)) << 3) + cl] = f2bf(sa[jb][r]);
            }
        }

        // PV: oacc[d] += P(16q x 32j) * V(32j x 16d), 4 j-slots x 4 d-blocks
        __builtin_amdgcn_s_setprio(1);
#pragma unroll
        for (int ks = 0; ks < 4; ++ks) {
            short8v pa = ld128(PsW, lr, ks * 4 + lg);
#pragma unroll
            for (int d = 0; d < 4; ++d)
                oacc[d] = __builtin_amdgcn_mfma_f32_16x16x32_bf16(
                    pa, ld128(VsC, d * 16 + lr, ks * 4 + lg), oacc[d], 0, 0, 0);
        }
        __builtin_amdgcn_s_setprio(0);
        __syncthreads();   // drains prefetch + guards K/V/P buffer reuse
    }

    USHORT* go = O + (size_t)(b * SEQ + q0 + w * 16) * D_MODEL + h * DH;
#pragma unroll
    for (int r = 0; r < 4; ++r) {
        const float inv = 1.f / l_[r];
        const int qrow = lg * 4 + r;
#pragma unroll
        for (int d = 0; d < 4; ++d)
            go[(size_t)qrow * D_MODEL + d * 16 + lr] = f2bf(oacc[d][r] * inv);
    }
}

// ---------------------------------------------------------------------------
// out = res + LayerNorm(x)*g + b.  x bf16; res fp32 (resf) or bf16 (resb).
// ---------------------------------------------------------------------------
__global__ __launch_bounds__(256) void ln_res_kernel(
    const USHORT* __restrict__ xb, const float* __restrict__ resf,
    const USHORT* __restrict__ resb,
    const float* __restrict__ g, const float* __restrict__ bta,
    float* __restrict__ outf, USHORT* __restrict__ outb)
{
    __shared__ float red[256];
    __shared__ float s_mu, s_rstd;

    const int row = blockIdx.x;
    const int tid = threadIdx.x;
    ushort4 xv = reinterpret_cast<const ushort4*>(xb + (size_t)row * D_MODEL)[tid];
    float vx = bf2f(xv.x), vy = bf2f(xv.y), vz = bf2f(xv.z), vw = bf2f(xv.w);

    red[tid] = vx + vy + vz + vw;
    __syncthreads();
    for (int s = 128; s > 0; s >>= 1) {
        if (tid < s) red[tid] += red[tid + s];
        __syncthreads();
    }
    if (tid == 0) s_mu = red[0] * (1.f / D_MODEL);
    __syncthreads();
    const float mu = s_mu;

    float dx = vx - mu, dy = vy - mu, dz = vz - mu, dw = vw - mu;
    red[tid] = dx * dx + dy * dy + dz * dz + dw * dw;
    __syncthreads();
    for (int s = 128; s > 0; s >>= 1) {
        if (tid < s) red[tid] += red[tid + s];
        __syncthreads();
    }
    if (tid == 0) s_rstd = rsqrtf(red[0] * (1.f / D_MODEL) + EPS);
    __syncthreads();
    const float rstd = s_rstd;

    float4 rv;
    if (resf) {
        rv = reinterpret_cast<const float4*>(resf + (size_t)row * D_MODEL)[tid];
    } else {
        ushort4 rb = reinterpret_cast<const ushort4*>(
            resb + (size_t)row * D_MODEL)[tid];
        rv = make_float4(bf2f(rb.x), bf2f(rb.y), bf2f(rb.z), bf2f(rb.w));
    }
    float4 gv = reinterpret_cast<const float4*>(g)[tid];
    float4 bv = reinterpret_cast<const float4*>(bta)[tid];

    float4 o;
    o.x = rv.x + dx * rstd * gv.x + bv.x;
    o.y = rv.y + dy * rstd * gv.y + bv.y;
    o.z = rv.z + dz * rstd * gv.z + bv.z;
    o.w = rv.w + dw * rstd * gv.w + bv.w;
    reinterpret_cast<float4*>(outf + (size_t)row * D_MODEL)[tid] = o;
    if (outb)
        reinterpret_cast<ushort4*>(outb + (size_t)row * D_MODEL)[tid] =
            make_ushort4(f2bf(o.x), f2bf(o.y), f2bf(o.z), f2bf(o.w));
}

// ---------------------------------------------------------------------------
extern "C" void kernel_launch(void* const* d_in, const int* in_sizes, int n_in,
                              void* d_out, int out_size, void* d_ws, size_t ws_size,
                              hipStream_t stream)
{
    const float* X    = (const float*)d_in[0];
    const float* Wq1  = (const float*)d_in[1];
    const float* Wk1  = (const float*)d_in[2];
    const float* Wv1  = (const float*)d_in[3];
    const float* Wo1  = (const float*)d_in[4];
    const float* Wq2  = (const float*)d_in[5];
    const float* Wk2  = (const float*)d_in[6];
    const float* Wv2  = (const float*)d_in[7];
    const float* Wo2  = (const float*)d_in[8];
    const float* ln_g = (const float*)d_in[9];
    const float* ln_b = (const float*)d_in[10];
    const float* W1   = (const float*)d_in[11];
    const float* b1   = (const float*)d_in[12];
    const float* W2   = (const float*)d_in[13];
    const float* b2   = (const float*)d_in[14];

    const size_t MI = 1024 * 1024;
    USHORT* ws16 = (USHORT*)d_ws;
    USHORT* Wqkv1t = ws16;
    USHORT* Wo1t   = ws16 + 3 * MI;
    USHORT* Wqkv2t = ws16 + 4 * MI;
    USHORT* Wo2t   = ws16 + 7 * MI;
    USHORT* W2t    = ws16 + 8 * MI;
    USHORT* Xb     = ws16 + 12 * MI;
    USHORT* W1t    = Xb;
    USHORT* qb     = ws16 + 16 * MI;
    USHORT* kb     = ws16 + 20 * MI;
    USHORT* Vtb    = ws16 + 24 * MI;
    USHORT* t0b    = ws16 + 28 * MI;
    USHORT* hb     = qb;
    USHORT* t2b    = ws16 + 32 * MI;
    USHORT* t1b    = ws16 + 36 * MI;
    float*  t2     = (float*)(ws16 + 40 * MI);

    auto gemm256 = [&](const USHORT* A, const USHORT* Bt, float* Cf, USHORT* Cb,
                       int M, int N, int K, const float* bias, int relu) {
        gemm_k256_kernel<<<dim3(N / 256, M / 256), 512, 0, stream>>>(
            A, Bt, Cf, Cb, nullptr, nullptr, M, N, K, bias, relu, 0);
    };
    auto gemm_qkv = [&](const USHORT* A, const USHORT* Bt) {
        gemm_k256_kernel<<<dim3(3072 / 256, TOK / 256), 512, 0, stream>>>(
            A, Bt, nullptr, qb, kb, Vtb, TOK, 3072, D_MODEL, nullptr, 0, 1);
    };
    auto gemm64b = [&](const USHORT* A, const USHORT* Bt, float* Cf, USHORT* Cb,
                       int M, int N, int K, const float* bias, int relu) {
        gemm_k64b_kernel<<<dim3(N / 128, M / 64), 256, 0, stream>>>(
            A, Bt, Cf, Cb, M, N, K, bias, relu);
    };

    dim3 agrid(SEQ / 64, BATCH * N_HEADS);

    // ---- prologue: all square weights + W2 + X -> bf16 ----
    {
        TcvtB4 p1{Wq1, Wk1, Wv1, Wo1,
                  Wqkv1t, Wqkv1t + 1 * MI, Wqkv1t + 2 * MI, Wo1t};
        tcvt4_kernel<<<dim3(16, 16, 4), 256, 0, stream>>>(p1, D_MODEL, D_MODEL);
        TcvtB4 p2{Wq2, Wk2, Wv2, Wo2,
                  Wqkv2t, Wqkv2t + 1 * MI, Wqkv2t + 2 * MI, Wo2t};
        tcvt4_kernel<<<dim3(16, 16, 4), 256, 0, stream>>>(p2, D_MODEL, D_MODEL);
    }
    tcvt_kernel<<<dim3(D_MODEL / 64, D_FF / 64), 256, 0, stream>>>(
        W2, W2t, D_FF, D_MODEL);
    f2b_kernel<<<dim3(4096), 256, 0, stream>>>(X, Xb, TOK * D_MODEL / 4);

    // ---- MHA 1 (causal) ----
    gemm_qkv(Xb, Wqkv1t);
    attn_mfma_kernel<<<agrid, 256, 0, stream>>>(qb, kb, Vtb, t0b, 1);
    gemm64b(t0b, Wo1t, nullptr, t1b, TOK, D_MODEL, D_MODEL, nullptr, 0);
    ln_res_kernel<<<dim3(TOK), 256, 0, stream>>>(t1b, X, nullptr,
                                                 ln_g, ln_b, t2, t2b);
    tcvt_kernel<<<dim3(D_FF / 64, D_MODEL / 64), 256, 0, stream>>>(
        W1, W1t, D_MODEL, D_FF);

    // ---- MHA 2 (full) ----
    gemm_qkv(t2b, Wqkv2t);
    attn_mfma_kernel<<<agrid, 256, 0, stream>>>(qb, kb, Vtb, t0b, 0);
    gemm64b(t0b, Wo2t, nullptr, t1b, TOK, D_MODEL, D_MODEL, nullptr, 0);
    ln_res_kernel<<<dim3(TOK), 256, 0, stream>>>(t1b, nullptr, t1b,
                                                 ln_g, ln_b, t2, t2b);

    // ---- FFN ----
    gemm256(t2b, W1t, nullptr, hb, TOK, D_FF, D_MODEL, b1, 1);
    gemm64b(hb, W2t, nullptr, t1b, TOK, D_MODEL, D_FF, b2, 0);
    ln_res_kernel<<<dim3(TOK), 256, 0, stream>>>(t1b, t2, nullptr,
                                                 ln_g, ln_b, (float*)d_out, nullptr);
}

// Round 12
// 371.185 us; speedup vs baseline: 28.3100x; 1.0303x over previous
//
#include <hip/hip_runtime.h>
#include <hip/hip_bf16.h>

#define D_MODEL 1024
#define N_HEADS 16
#define DH 64
#define D_FF   4096
#define SEQ    1024
#define BATCH  4
#define TOK    (BATCH*SEQ)
#define EPS    1e-5f
#define SCALE  0.125f           // 1/sqrt(64)
#define QSCL   0.18033688f      // SCALE * log2(e): QK^T lands in log2 domain

typedef unsigned short USHORT;
typedef __attribute__((ext_vector_type(8))) short short8v;
typedef __attribute__((ext_vector_type(4))) float f32x4;

__device__ __forceinline__ USHORT f2bf(float f) {
    unsigned int u; __builtin_memcpy(&u, &f, 4);
    u += 0x7fffu + ((u >> 16) & 1u);          // RNE
    return (USHORT)(u >> 16);
}
__device__ __forceinline__ float bf2f(USHORT s) {
    unsigned int u = ((unsigned int)s) << 16;
    float f; __builtin_memcpy(&f, &u, 4);
    return f;
}

// row-stride-64 swizzled read: unit ^= row&7
__device__ __forceinline__ short8v ld_frag(const USHORT* lds, int row, int c8) {
    return *reinterpret_cast<const short8v*>(
        &lds[row * 64 + (((c8) ^ (row & 7)) << 3)]);
}
// row-stride-128 swizzled read (attn V/P tiles): unit ^= row&15
__device__ __forceinline__ short8v ld128(const USHORT* lds, int row, int cu) {
    return *reinterpret_cast<const short8v*>(
        &lds[row * 128 + (((cu) ^ (row & 15)) << 3)]);
}

#define GLDS(gsrc, ldst) \
    __builtin_amdgcn_global_load_lds( \
        (const __attribute__((address_space(1))) void*)(gsrc), \
        (__attribute__((address_space(3))) void*)(ldst), 16, 0, 0)

#define WAITVM(n) asm volatile("s_waitcnt vmcnt(" #n ")" ::: "memory")

// ---------------------------------------------------------------------------
// bf16 MFMA GEMM, 256x256 tile, BK=64, 512 threads = 8 waves (2M x 4N).
// 2-buffer counted-vmcnt pipeline (issue-early, WAITVM(8), never 0 mid-loop).
// Epilogues: normal or fused-QKV routing (Q pre-scaled into log2-e domain).
// ---------------------------------------------------------------------------
__global__ __launch_bounds__(512) void gemm_k256_kernel(
    const USHORT* __restrict__ A, const USHORT* __restrict__ Bt,
    float* __restrict__ Cf, USHORT* __restrict__ Cb, USHORT* __restrict__ Ck,
    USHORT* __restrict__ VtOut,
    int M, int N, int K, const float* __restrict__ bias, int relu, int qkv)
{
    __shared__ USHORT As[2][256 * 64];
    __shared__ USHORT Bs[2][256 * 64];

    const int tid = threadIdx.x;
    const int l   = tid & 63;
    const int w   = tid >> 6;              // 0..7
    const int wr  = w >> 2, wc = w & 3;    // 2 x 4 wave grid
    const int lr  = l & 15, lg = l >> 4;

    const int gx  = gridDim.x;
    const int nwg = gx * gridDim.y;
    const int lin = blockIdx.y * gx + blockIdx.x;
    const int swz = (lin & 7) * (nwg >> 3) + (lin >> 3);
    const int m0  = (swz / gx) * 256, n0 = (swz % gx) * 256;

    const USHORT* aS[4]; const USHORT* bS[4]; int dOf[4];
#pragma unroll
    for (int p = 0; p < 4; ++p) {
        const int q = p * 512 + tid;
        const int row = q >> 3, cu = q & 7;
        const int cs = ((cu ^ (row & 7)) << 3);
        aS[p] = A  + (size_t)(m0 + row) * K + cs;
        bS[p] = Bt + (size_t)(n0 + row) * K + cs;
        dOf[p] = (p * 512 + w * 64) * 8;
    }

    auto stage = [&](int buf, int k0) {
#pragma unroll
        for (int p = 0; p < 4; ++p) {
            GLDS(aS[p] + k0, &As[buf][dOf[p]]);
            GLDS(bS[p] + k0, &Bs[buf][dOf[p]]);
        }
    };

    f32x4 acc[8][4];
#pragma unroll
    for (int i = 0; i < 8; ++i)
#pragma unroll
        for (int j = 0; j < 4; ++j) acc[i][j] = (f32x4){0.f, 0.f, 0.f, 0.f};

    const int nk = K >> 6;
    stage(0, 0);

    for (int t = 0; t < nk; ++t) {
        const int cur = t & 1;
        if (t + 1 < nk) {
            stage(cur ^ 1, (t + 1) << 6);
            WAITVM(8);
        } else {
            WAITVM(0);
        }
        __builtin_amdgcn_s_barrier();

#pragma unroll
        for (int ks = 0; ks < 2; ++ks) {
            short8v bfr[4];
#pragma unroll
            for (int ni = 0; ni < 4; ++ni)
                bfr[ni] = ld_frag(Bs[cur], wc * 64 + ni * 16 + lr, ks * 4 + lg);
            __builtin_amdgcn_s_setprio(1);
#pragma unroll
            for (int mi = 0; mi < 8; ++mi) {
                short8v af = ld_frag(As[cur], wr * 128 + mi * 16 + lr, ks * 4 + lg);
#pragma unroll
                for (int ni = 0; ni < 4; ++ni)
                    acc[mi][ni] = __builtin_amdgcn_mfma_f32_16x16x32_bf16(
                        af, bfr[ni], acc[mi][ni], 0, 0, 0);
            }
            __builtin_amdgcn_s_setprio(0);
        }
        __builtin_amdgcn_s_barrier();
    }

    // epilogue: C/D layout col = lane&15, row = (lane>>4)*4 + reg
    if (qkv) {
#pragma unroll
        for (int mi = 0; mi < 8; ++mi) {
            const int row = m0 + wr * 128 + mi * 16 + (l >> 4) * 4;
#pragma unroll
            for (int ni = 0; ni < 4; ++ni) {
                const int col = n0 + wc * 64 + ni * 16 + lr;
                if (col < 2048) {
                    USHORT* dst = (col < 1024) ? Cb : Ck;
                    const float scl = (col < 1024) ? QSCL : 1.f;  // log2-e domain
                    const int c = col & 1023;
#pragma unroll
                    for (int j = 0; j < 4; ++j)
                        dst[(size_t)(row + j) * D_MODEL + c] =
                            f2bf(acc[mi][ni][j] * scl);
                } else {
                    const int c = col - 2048;
                    const int bb = row >> 10, jr = row & 1023;
                    const int hh = c >> 6, dd = c & 63;
                    ushort4 pk = make_ushort4(
                        f2bf(acc[mi][ni][0]), f2bf(acc[mi][ni][1]),
                        f2bf(acc[mi][ni][2]), f2bf(acc[mi][ni][3]));
                    *reinterpret_cast<ushort4*>(
                        &VtOut[((size_t)(bb * 16 + hh) * 64 + dd) * 1024 + jr]) = pk;
                }
            }
        }
    } else {
#pragma unroll
        for (int mi = 0; mi < 8; ++mi) {
            const int row = m0 + wr * 128 + mi * 16 + (l >> 4) * 4;
#pragma unroll
            for (int ni = 0; ni < 4; ++ni) {
                const int col = n0 + wc * 64 + ni * 16 + lr;
                const float bv = bias ? bias[col] : 0.f;
#pragma unroll
                for (int j = 0; j < 4; ++j) {
                    float v = acc[mi][ni][j] + bv;
                    if (relu) v = fmaxf(v, 0.f);
                    const size_t idx = (size_t)(row + j) * N + col;
                    if (Cf) Cf[idx] = v;
                    if (Cb) Cb[idx] = f2bf(v);
                }
            }
        }
    }
}

// ---------------------------------------------------------------------------
// bf16 MFMA GEMM for the grid-starved N=1024 shapes: 64x128 tile, BK=64,
// 3-buffer counted-vmcnt pipeline, 4 waves (2x2, each 32x64). (unchanged)
// ---------------------------------------------------------------------------
__global__ __launch_bounds__(256) void gemm_k64b_kernel(
    const USHORT* __restrict__ A, const USHORT* __restrict__ Bt,
    float* __restrict__ Cf, USHORT* __restrict__ Cb,
    int M, int N, int K, const float* __restrict__ bias, int relu)
{
    __shared__ USHORT As[3][64 * 64];
    __shared__ USHORT Bs[3][128 * 64];

    const int tid = threadIdx.x;
    const int l   = tid & 63;
    const int w   = tid >> 6;
    const int wr  = w >> 1, wc = w & 1;
    const int lr  = l & 15, lg = l >> 4;

    const int gx  = gridDim.x;
    const int nwg = gx * gridDim.y;
    const int lin = blockIdx.y * gx + blockIdx.x;
    const int swz = (lin & 7) * (nwg >> 3) + (lin >> 3);
    const int m0  = (swz / gx) * 64, n0 = (swz % gx) * 128;

    const int ar0 = tid >> 3,         ac0 = ((tid & 7) ^ (ar0 & 7)) << 3;
    const int ar1 = (256 + tid) >> 3, ac1 = (((256 + tid) & 7) ^ (ar1 & 7)) << 3;
    const USHORT* aS0 = A + (size_t)(m0 + ar0) * K + ac0;
    const USHORT* aS1 = A + (size_t)(m0 + ar1) * K + ac1;
    const int adOf0 = (w * 64) * 8;
    const int adOf1 = (256 + w * 64) * 8;

    const USHORT* bS[4]; int bdOf[4];
#pragma unroll
    for (int p = 0; p < 4; ++p) {
        const int q = p * 256 + tid;
        const int row = q >> 3, cu = q & 7;
        bS[p] = Bt + (size_t)(n0 + row) * K + ((cu ^ (row & 7)) << 3);
        bdOf[p] = (p * 256 + w * 64) * 8;
    }

    auto stage = [&](int buf, int k0) {
        GLDS(aS0 + k0, &As[buf][adOf0]);
        GLDS(aS1 + k0, &As[buf][adOf1]);
#pragma unroll
        for (int p = 0; p < 4; ++p)
            GLDS(bS[p] + k0, &Bs[buf][bdOf[p]]);
    };

    f32x4 acc[2][4];
#pragma unroll
    for (int i = 0; i < 2; ++i)
#pragma unroll
        for (int j = 0; j < 4; ++j) acc[i][j] = (f32x4){0.f, 0.f, 0.f, 0.f};

    const int nk = K >> 6;
    stage(0, 0);
    if (nk > 1) stage(1, 64);

    for (int t = 0; t < nk; ++t) {
        const int cur = t % 3;
        if (t + 1 < nk) { WAITVM(6); } else { WAITVM(0); }
        __builtin_amdgcn_s_barrier();
        if (t + 2 < nk) stage((t + 2) % 3, (t + 2) << 6);

#pragma unroll
        for (int ks = 0; ks < 2; ++ks) {
            short8v af[2], bfr[4];
#pragma unroll
            for (int mi = 0; mi < 2; ++mi)
                af[mi] = ld_frag(As[cur], wr * 32 + mi * 16 + lr, ks * 4 + lg);
#pragma unroll
            for (int ni = 0; ni < 4; ++ni)
                bfr[ni] = ld_frag(Bs[cur], wc * 64 + ni * 16 + lr, ks * 4 + lg);
            __builtin_amdgcn_s_setprio(1);
#pragma unroll
            for (int mi = 0; mi < 2; ++mi)
#pragma unroll
                for (int ni = 0; ni < 4; ++ni)
                    acc[mi][ni] = __builtin_amdgcn_mfma_f32_16x16x32_bf16(
                        af[mi], bfr[ni], acc[mi][ni], 0, 0, 0);
            __builtin_amdgcn_s_setprio(0);
        }
    }

#pragma unroll
    for (int mi = 0; mi < 2; ++mi) {
        const int row = m0 + wr * 32 + mi * 16 + (l >> 4) * 4;
#pragma unroll
        for (int ni = 0; ni < 4; ++ni) {
            const int col = n0 + wc * 64 + ni * 16 + lr;
            const float bv = bias ? bias[col] : 0.f;
#pragma unroll
            for (int j = 0; j < 4; ++j) {
                float v = acc[mi][ni][j] + bv;
                if (relu) v = fmaxf(v, 0.f);
                const size_t idx = (size_t)(row + j) * N + col;
                if (Cf) Cf[idx] = v;
                if (Cb) Cb[idx] = f2bf(v);
            }
        }
    }
}

// ---------------------------------------------------------------------------
// Weight convert+transpose kernels (unchanged).
// ---------------------------------------------------------------------------
struct TcvtB4 {
    const float* s0; const float* s1; const float* s2; const float* s3;
    USHORT* d0; USHORT* d1; USHORT* d2; USHORT* d3;
};

__device__ __forceinline__ void tcvt_body(
    const float* __restrict__ W, USHORT* __restrict__ Wt, int K, int N)
{
    __shared__ USHORT L[64][65];
    const int tid = threadIdx.x;
    const int tx = tid & 15, ty = tid >> 4;
    const int n0 = blockIdx.x * 64, k0 = blockIdx.y * 64;
#pragma unroll
    for (int r = 0; r < 4; ++r) {
        int kr = ty + 16 * r;
        float4 v = *reinterpret_cast<const float4*>(
            &W[(size_t)(k0 + kr) * N + n0 + tx * 4]);
        L[tx * 4 + 0][kr] = f2bf(v.x);
        L[tx * 4 + 1][kr] = f2bf(v.y);
        L[tx * 4 + 2][kr] = f2bf(v.z);
        L[tx * 4 + 3][kr] = f2bf(v.w);
    }
    __syncthreads();
#pragma unroll
    for (int r = 0; r < 4; ++r) {
        int nr = ty + 16 * r;
        ushort4 o = make_ushort4(L[nr][tx * 4 + 0], L[nr][tx * 4 + 1],
                                 L[nr][tx * 4 + 2], L[nr][tx * 4 + 3]);
        *reinterpret_cast<ushort4*>(&Wt[(size_t)(n0 + nr) * K + k0 + tx * 4]) = o;
    }
}

__global__ __launch_bounds__(256) void tcvt_kernel(
    const float* __restrict__ W, USHORT* __restrict__ Wt, int K, int N)
{
    tcvt_body(W, Wt, K, N);
}

__global__ __launch_bounds__(256) void tcvt4_kernel(TcvtB4 p, int K, int N)
{
    const int z = blockIdx.z;
    const float* W = (z == 0) ? p.s0 : (z == 1) ? p.s1 : (z == 2) ? p.s2 : p.s3;
    USHORT*    Wt = (z == 0) ? p.d0 : (z == 1) ? p.d1 : (z == 2) ? p.d2 : p.d3;
    tcvt_body(W, Wt, K, N);
}

__global__ __launch_bounds__(256) void f2b_kernel(
    const float* __restrict__ in, USHORT* __restrict__ out, int n4)
{
    int i = blockIdx.x * 256 + threadIdx.x;
    if (i < n4) {
        float4 v = reinterpret_cast<const float4*>(in)[i];
        reinterpret_cast<ushort4*>(out)[i] =
            make_ushort4(f2bf(v.x), f2bf(v.y), f2bf(v.z), f2bf(v.w));
    }
}

// ---------------------------------------------------------------------------
// MFMA flash attention, KVBLK=128, dbuf K/V, Q/P LDS union.
// Softmax in log2 domain (Q pre-scaled by SCALE*log2e): p = exp2(s - m).
// LAZY reductions: per-tile max-reduce gated by a wave __ballot (fires only
// when some lane in the 16-lane group sees growth > 8, i.e. ~first tile);
// l kept LANE-PARTIAL per tile (rescale is uniform), one group-sum at the
// epilogue. Common-case per-tile cross-lane ops: 32 shfl -> 1 ballot.
// ---------------------------------------------------------------------------
__global__ __launch_bounds__(256) void attn_mfma_kernel(
    const USHORT* __restrict__ Q, const USHORT* __restrict__ K,
    const USHORT* __restrict__ Vt, USHORT* __restrict__ O, int causal)
{
    __shared__ USHORT smem[40960];                 // 80 KB

    const int tid = threadIdx.x;
    const int l  = tid & 63;
    const int w  = tid >> 6;
    const int lr = l & 15;
    const int lg = l >> 4;

    const int lin = blockIdx.y * 16 + blockIdx.x;   // nwg = 1024
    const int swz = (lin & 7) * 128 + (lin >> 3);
    const int qt = swz & 15;
    const int bh = swz >> 4;
    const int h = bh & 15, b = bh >> 4;
    const int q0 = qt * 64;

    const USHORT* gq  = Q  + (size_t)(b * SEQ + q0) * D_MODEL + h * DH;
    const USHORT* gk0 = K  + (size_t)b * SEQ * D_MODEL + h * DH;
    const USHORT* gv0 = Vt + (size_t)bh * DH * SEQ;

    auto stageK = [&](int buf, int kt) {           // 128x64, row&7 swizzle
        USHORT* dst = smem + buf * 8192;
        const size_t base = (size_t)kt * 128 * 1024;
#pragma unroll
        for (int p = 0; p < 4; ++p) {
            const int q = p * 256 + tid;
            const int row = q >> 3, cu = q & 7;
            GLDS(gk0 + base + (size_t)row * 1024 + ((cu ^ (row & 7)) << 3),
                 dst + (p * 256 + w * 64) * 8);
        }
    };
    auto stageV = [&](int buf, int kt) {           // 64x128, row&15 swizzle
        USHORT* dst = smem + 16384 + buf * 8192;
        const int j0 = kt * 128;
#pragma unroll
        for (int p = 0; p < 4; ++p) {
            const int q = p * 256 + tid;
            const int row = q >> 4, cu = q & 15;
            GLDS(gv0 + (size_t)row * 1024 + j0 + ((cu ^ (row & 15)) << 3),
                 dst + (p * 256 + w * 64) * 8);
        }
    };

    // stage Q (64x64, row&7 swizzle) + first K/V tile
#pragma unroll
    for (int p = 0; p < 2; ++p) {
        const int q = p * 256 + tid;
        const int row = q >> 3, cu = q & 7;
        GLDS(gq + (size_t)row * 1024 + ((cu ^ (row & 7)) << 3),
             smem + 32768 + (p * 256 + w * 64) * 8);
    }
    stageK(0, 0);
    stageV(0, 0);

    f32x4 oacc[4];
    float m_[4], l_[4];                            // l_ is LANE-PARTIAL
#pragma unroll
    for (int r = 0; r < 4; ++r) { m_[r] = -1e30f; l_[r] = 0.f; }
#pragma unroll
    for (int d = 0; d < 4; ++d) oacc[d] = (f32x4){0.f, 0.f, 0.f, 0.f};

    __syncthreads();                               // Q + tile 0 staged
    short8v qa0 = ld_frag(smem + 32768, w * 16 + lr, lg);
    short8v qa1 = ld_frag(smem + 32768, w * 16 + lr, 4 + lg);
    __syncthreads();                               // Q consumed -> Ps may reuse
    USHORT* PsW = smem + 32768 + w * 2048;         // per-wave P [16 q][128 j]

    const int ntile = causal ? (qt >> 1) + 1 : (SEQ / 128);
    for (int kt = 0; kt < ntile; ++kt) {
        const int cur = kt & 1;
        if (kt + 1 < ntile) {                      // prefetch next K/V tile
            stageK(cur ^ 1, kt + 1);
            stageV(cur ^ 1, kt + 1);
        }
        const int j0 = kt * 128;
        const USHORT* KsC = smem + cur * 8192;
        const USHORT* VsC = smem + 16384 + cur * 8192;

        // S = Q K^T  (log2 domain)
        f32x4 sa[8];
        __builtin_amdgcn_s_setprio(1);
#pragma unroll
        for (int jb = 0; jb < 8; ++jb) {
            sa[jb] = (f32x4){0.f, 0.f, 0.f, 0.f};
            sa[jb] = __builtin_amdgcn_mfma_f32_16x16x32_bf16(
                qa0, ld_frag(KsC, jb * 16 + lr, lg), sa[jb], 0, 0, 0);
            sa[jb] = __builtin_amdgcn_mfma_f32_16x16x32_bf16(
                qa1, ld_frag(KsC, jb * 16 + lr, 4 + lg), sa[jb], 0, 0, 0);
        }
        __builtin_amdgcn_s_setprio(0);

        // causal mask: only the last tile can cross the diagonal
        if (causal && kt == ntile - 1) {
#pragma unroll
            for (int jb = 0; jb < 8; ++jb)
#pragma unroll
                for (int r = 0; r < 4; ++r)
                    if ((j0 + jb * 16 + lr) > (q0 + w * 16 + lg * 4 + r))
                        sa[jb][r] = -1e30f;
        }

        // thread-local max per row (8 values each)
        float tmloc[4];
#pragma unroll
        for (int r = 0; r < 4; ++r)
            tmloc[r] = fmaxf(fmaxf(fmaxf(sa[0][r], sa[1][r]),
                                   fmaxf(sa[2][r], sa[3][r])),
                             fmaxf(fmaxf(sa[4][r], sa[5][r]),
                                   fmaxf(sa[6][r], sa[7][r])));

        // lazy group max-reduce: only when someone in the 16-lane group grew
        const bool anyf = (tmloc[0] > m_[0] + 8.f) | (tmloc[1] > m_[1] + 8.f) |
                          (tmloc[2] > m_[2] + 8.f) | (tmloc[3] > m_[3] + 8.f);
        const unsigned long long bal = __ballot(anyf);
        if ((bal >> (lg * 16)) & 0xFFFFull) {
#pragma unroll
            for (int r = 0; r < 4; ++r) {
                float tm = tmloc[r];
                tm = fmaxf(tm, __shfl_xor(tm, 1));
                tm = fmaxf(tm, __shfl_xor(tm, 2));
                tm = fmaxf(tm, __shfl_xor(tm, 4));
                tm = fmaxf(tm, __shfl_xor(tm, 8));
                if (tm > m_[r] + 8.f) {
                    float sc = exp2f(m_[r] - tm);
                    l_[r] *= sc;
#pragma unroll
                    for (int d = 0; d < 4; ++d) oacc[d][r] *= sc;
                    m_[r] = tm;
                }
            }
        }

        // exp (log2 domain) + lane-partial sum
#pragma unroll
        for (int r = 0; r < 4; ++r) {
            float rs_ = 0.f;
#pragma unroll
            for (int jb = 0; jb < 8; ++jb) {
                float p = exp2f(sa[jb][r] - m_[r]);
                sa[jb][r] = p;
                rs_ += p;
            }
            l_[r] += rs_;                          // no per-tile group sum
        }

        // P -> per-wave swizzled LDS (bf16), [16 q][128 j], unit ^= row&15
#pragma unroll
        for (int jb = 0; jb < 8; ++jb) {
            const int cu = jb * 2 + (lr >> 3), cl = lr & 7;
#pragma unroll
            for (int r = 0; r < 4; ++r) {
                const int row = lg * 4 + r;
                PsW[row * 128 + ((cu ^ (row & 15)) << 3) + cl] = f2bf(sa[jb][r]);
            }
        }

        // PV: oacc[d] += P(16q x 32j) * V(32j x 16d), 4 j-slots x 4 d-blocks
        __builtin_amdgcn_s_setprio(1);
#pragma unroll
        for (int ks = 0; ks < 4; ++ks) {
            short8v pa = ld128(PsW, lr, ks * 4 + lg);
#pragma unroll
            for (int d = 0; d < 4; ++d)
                oacc[d] = __builtin_amdgcn_mfma_f32_16x16x32_bf16(
                    pa, ld128(VsC, d * 16 + lr, ks * 4 + lg), oacc[d], 0, 0, 0);
        }
        __builtin_amdgcn_s_setprio(0);
        __syncthreads();   // drains prefetch + guards K/V/P buffer reuse
    }

    // epilogue: one group-sum of the lane-partial l, then normalize
    USHORT* go = O + (size_t)(b * SEQ + q0 + w * 16) * D_MODEL + h * DH;
#pragma unroll
    for (int r = 0; r < 4; ++r) {
        float lv = l_[r];
        lv += __shfl_xor(lv, 1);
        lv += __shfl_xor(lv, 2);
        lv += __shfl_xor(lv, 4);
        lv += __shfl_xor(lv, 8);
        const float inv = 1.f / lv;
        const int qrow = lg * 4 + r;
#pragma unroll
        for (int d = 0; d < 4; ++d)
            go[(size_t)qrow * D_MODEL + d * 16 + lr] = f2bf(oacc[d][r] * inv);
    }
}

// ---------------------------------------------------------------------------
// out = res + LayerNorm(x)*g + b.  x bf16; res fp32 (resf) or bf16 (resb).
// ---------------------------------------------------------------------------
__global__ __launch_bounds__(256) void ln_res_kernel(
    const USHORT* __restrict__ xb, const float* __restrict__ resf,
    const USHORT* __restrict__ resb,
    const float* __restrict__ g, const float* __restrict__ bta,
    float* __restrict__ outf, USHORT* __restrict__ outb)
{
    __shared__ float red[256];
    __shared__ float s_mu, s_rstd;

    const int row = blockIdx.x;
    const int tid = threadIdx.x;
    ushort4 xv = reinterpret_cast<const ushort4*>(xb + (size_t)row * D_MODEL)[tid];
    float vx = bf2f(xv.x), vy = bf2f(xv.y), vz = bf2f(xv.z), vw = bf2f(xv.w);

    red[tid] = vx + vy + vz + vw;
    __syncthreads();
    for (int s = 128; s > 0; s >>= 1) {
        if (tid < s) red[tid] += red[tid + s];
        __syncthreads();
    }
    if (tid == 0) s_mu = red[0] * (1.f / D_MODEL);
    __syncthreads();
    const float mu = s_mu;

    float dx = vx - mu, dy = vy - mu, dz = vz - mu, dw = vw - mu;
    red[tid] = dx * dx + dy * dy + dz * dz + dw * dw;
    __syncthreads();
    for (int s = 128; s > 0; s >>= 1) {
        if (tid < s) red[tid] += red[tid + s];
        __syncthreads();
    }
    if (tid == 0) s_rstd = rsqrtf(red[0] * (1.f / D_MODEL) + EPS);
    __syncthreads();
    const float rstd = s_rstd;

    float4 rv;
    if (resf) {
        rv = reinterpret_cast<const float4*>(resf + (size_t)row * D_MODEL)[tid];
    } else {
        ushort4 rb = reinterpret_cast<const ushort4*>(
            resb + (size_t)row * D_MODEL)[tid];
        rv = make_float4(bf2f(rb.x), bf2f(rb.y), bf2f(rb.z), bf2f(rb.w));
    }
    float4 gv = reinterpret_cast<const float4*>(g)[tid];
    float4 bv = reinterpret_cast<const float4*>(bta)[tid];

    float4 o;
    o.x = rv.x + dx * rstd * gv.x + bv.x;
    o.y = rv.y + dy * rstd * gv.y + bv.y;
    o.z = rv.z + dz * rstd * gv.z + bv.z;
    o.w = rv.w + dw * rstd * gv.w + bv.w;
    reinterpret_cast<float4*>(outf + (size_t)row * D_MODEL)[tid] = o;
    if (outb)
        reinterpret_cast<ushort4*>(outb + (size_t)row * D_MODEL)[tid] =
            make_ushort4(f2bf(o.x), f2bf(o.y), f2bf(o.z), f2bf(o.w));
}

// ---------------------------------------------------------------------------
extern "C" void kernel_launch(void* const* d_in, const int* in_sizes, int n_in,
                              void* d_out, int out_size, void* d_ws, size_t ws_size,
                              hipStream_t stream)
{
    const float* X    = (const float*)d_in[0];
    const float* Wq1  = (const float*)d_in[1];
    const float* Wk1  = (const float*)d_in[2];
    const float* Wv1  = (const float*)d_in[3];
    const float* Wo1  = (const float*)d_in[4];
    const float* Wq2  = (const float*)d_in[5];
    const float* Wk2  = (const float*)d_in[6];
    const float* Wv2  = (const float*)d_in[7];
    const float* Wo2  = (const float*)d_in[8];
    const float* ln_g = (const float*)d_in[9];
    const float* ln_b = (const float*)d_in[10];
    const float* W1   = (const float*)d_in[11];
    const float* b1   = (const float*)d_in[12];
    const float* W2   = (const float*)d_in[13];
    const float* b2   = (const float*)d_in[14];

    const size_t MI = 1024 * 1024;
    USHORT* ws16 = (USHORT*)d_ws;
    USHORT* Wqkv1t = ws16;
    USHORT* Wo1t   = ws16 + 3 * MI;
    USHORT* Wqkv2t = ws16 + 4 * MI;
    USHORT* Wo2t   = ws16 + 7 * MI;
    USHORT* W2t    = ws16 + 8 * MI;
    USHORT* Xb     = ws16 + 12 * MI;
    USHORT* W1t    = Xb;
    USHORT* qb     = ws16 + 16 * MI;
    USHORT* kb     = ws16 + 20 * MI;
    USHORT* Vtb    = ws16 + 24 * MI;
    USHORT* t0b    = ws16 + 28 * MI;
    USHORT* hb     = qb;
    USHORT* t2b    = ws16 + 32 * MI;
    USHORT* t1b    = ws16 + 36 * MI;
    float*  t2     = (float*)(ws16 + 40 * MI);

    auto gemm256 = [&](const USHORT* A, const USHORT* Bt, float* Cf, USHORT* Cb,
                       int M, int N, int K, const float* bias, int relu) {
        gemm_k256_kernel<<<dim3(N / 256, M / 256), 512, 0, stream>>>(
            A, Bt, Cf, Cb, nullptr, nullptr, M, N, K, bias, relu, 0);
    };
    auto gemm_qkv = [&](const USHORT* A, const USHORT* Bt) {
        gemm_k256_kernel<<<dim3(3072 / 256, TOK / 256), 512, 0, stream>>>(
            A, Bt, nullptr, qb, kb, Vtb, TOK, 3072, D_MODEL, nullptr, 0, 1);
    };
    auto gemm64b = [&](const USHORT* A, const USHORT* Bt, float* Cf, USHORT* Cb,
                       int M, int N, int K, const float* bias, int relu) {
        gemm_k64b_kernel<<<dim3(N / 128, M / 64), 256, 0, stream>>>(
            A, Bt, Cf, Cb, M, N, K, bias, relu);
    };

    dim3 agrid(SEQ / 64, BATCH * N_HEADS);

    // ---- prologue: all square weights + W2 + X -> bf16 ----
    {
        TcvtB4 p1{Wq1, Wk1, Wv1, Wo1,
                  Wqkv1t, Wqkv1t + 1 * MI, Wqkv1t + 2 * MI, Wo1t};
        tcvt4_kernel<<<dim3(16, 16, 4), 256, 0, stream>>>(p1, D_MODEL, D_MODEL);
        TcvtB4 p2{Wq2, Wk2, Wv2, Wo2,
                  Wqkv2t, Wqkv2t + 1 * MI, Wqkv2t + 2 * MI, Wo2t};
        tcvt4_kernel<<<dim3(16, 16, 4), 256, 0, stream>>>(p2, D_MODEL, D_MODEL);
    }
    tcvt_kernel<<<dim3(D_MODEL / 64, D_FF / 64), 256, 0, stream>>>(
        W2, W2t, D_FF, D_MODEL);
    f2b_kernel<<<dim3(4096), 256, 0, stream>>>(X, Xb, TOK * D_MODEL / 4);

    // ---- MHA 1 (causal) ----
    gemm_qkv(Xb, Wqkv1t);
    attn_mfma_kernel<<<agrid, 256, 0, stream>>>(qb, kb, Vtb, t0b, 1);
    gemm64b(t0b, Wo1t, nullptr, t1b, TOK, D_MODEL, D_MODEL, nullptr, 0);
    ln_res_kernel<<<dim3(TOK), 256, 0, stream>>>(t1b, X, nullptr,
                                                 ln_g, ln_b, t2, t2b);
    tcvt_kernel<<<dim3(D_FF / 64, D_MODEL / 64), 256, 0, stream>>>(
        W1, W1t, D_MODEL, D_FF);

    // ---- MHA 2 (full) ----
    gemm_qkv(t2b, Wqkv2t);
    attn_mfma_kernel<<<agrid, 256, 0, stream>>>(qb, kb, Vtb, t0b, 0);
    gemm64b(t0b, Wo2t, nullptr, t1b, TOK, D_MODEL, D_MODEL, nullptr, 0);
    ln_res_kernel<<<dim3(TOK), 256, 0, stream>>>(t1b, nullptr, t1b,
                                                 ln_g, ln_b, t2, t2b);

    // ---- FFN ----
    gemm256(t2b, W1t, nullptr, hb, TOK, D_FF, D_MODEL, b1, 1);
    gemm64b(hb, W2t, nullptr, t1b, TOK, D_MODEL, D_FF, b2, 0);
    ln_res_kernel<<<dim3(TOK), 256, 0, stream>>>(t1b, t2, nullptr,
                                                 ln_g, ln_b, (float*)d_out, nullptr);
}